// Round 6
// baseline (3350.073 us; speedup 1.0000x reference)
//
#include <hip/hip_runtime.h>
#include <math.h>

#define DMODEL 512
#define NHEADS 8
#define NEXP 4
#define SEQ 1024
#define BATCH 4
#define NTOK 4096  // BATCH * SEQ
#define NCHUNK 16  // SEQ / 64

typedef float v2f __attribute__((ext_vector_type(2)));
typedef float v4f __attribute__((ext_vector_type(4)));
typedef short bf16x8 __attribute__((ext_vector_type(8)));
typedef float f32x4 __attribute__((ext_vector_type(4)));
typedef unsigned short u16;

__device__ __forceinline__ float dev_sigmoid(float x) { return 1.0f / (1.0f + expf(-x)); }
__device__ __forceinline__ float dev_silu(float x) { return x / (1.0f + expf(-x)); }
__device__ __forceinline__ float dev_softplus(float x) {
  return x > 0.0f ? x + log1pf(expf(-x)) : log1pf(expf(x));
}
// fp32 -> bf16 bits, round-to-nearest-even
__device__ __forceinline__ u16 f2b(float f) {
  unsigned int u = __float_as_uint(f);
  unsigned int r = (u + 0x7fffu + ((u >> 16) & 1u)) >> 16;
  return (u16)r;
}

// ---------------- zero kernel ----------------
__global__ __launch_bounds__(256) void zero_kernel(float4* __restrict__ p) {
  p[(size_t)blockIdx.x * 256 + threadIdx.x] = make_float4(0.f, 0.f, 0.f, 0.f);
}

// ---------------- cast h (fp32) -> bf16 bits ----------------
__global__ __launch_bounds__(256) void cast_h_kernel(const float4* __restrict__ in,
                                                     ushort4* __restrict__ outp) {
  const size_t i = (size_t)blockIdx.x * 256 + threadIdx.x;
  float4 v = in[i];
  ushort4 o;
  o.x = f2b(v.x); o.y = f2b(v.y); o.z = f2b(v.z); o.w = f2b(v.w);
  outp[i] = o;
}

// ---------------- transpose-cast weight: W[512][512] fp32 -> Wt[n][k] bf16 -------------
__global__ __launch_bounds__(256) void castT_kernel(const float* __restrict__ in,
                                                    u16* __restrict__ outp) {
  __shared__ float tile[32][33];
  const int bx = blockIdx.x * 32;  // k base
  const int by = blockIdx.y * 32;  // n base
  const int c = threadIdx.x & 31, r0 = threadIdx.x >> 5;
#pragma unroll
  for (int r = r0; r < 32; r += 8) tile[r][c] = in[(size_t)(bx + r) * DMODEL + by + c];
  __syncthreads();
#pragma unroll
  for (int r = r0; r < 32; r += 8)
    outp[(size_t)(by + r) * DMODEL + bx + c] = f2b(tile[c][r]);
}

// ---------------- router + beta/g small projections: one wave per token ----------------
__global__ __launch_bounds__(64) void router_kernel(
    const float* __restrict__ h, const float* __restrict__ Wb,
    const float* __restrict__ Wa, const float* __restrict__ Wgate,
    const float* __restrict__ A_log, const float* __restrict__ dt_bias,
    float* __restrict__ beta_o, float* __restrict__ g_o, float* __restrict__ w_o) {
  const int t = blockIdx.x;
  const int lane = threadIdx.x;
  float hv[8];
#pragma unroll
  for (int j = 0; j < 8; ++j) hv[j] = h[(size_t)t * DMODEL + j * 64 + lane];
  float db[8], da[8], dg[4];
#pragma unroll
  for (int c = 0; c < 8; ++c) {
    float s1 = 0.f, s2 = 0.f;
#pragma unroll
    for (int j = 0; j < 8; ++j) {
      int row = j * 64 + lane;
      s1 += hv[j] * Wb[row * NHEADS + c];
      s2 += hv[j] * Wa[row * NHEADS + c];
    }
#pragma unroll
    for (int off = 1; off < 64; off <<= 1) {
      s1 += __shfl_xor(s1, off);
      s2 += __shfl_xor(s2, off);
    }
    db[c] = s1; da[c] = s2;
  }
#pragma unroll
  for (int c = 0; c < 4; ++c) {
    float s = 0.f;
#pragma unroll
    for (int j = 0; j < 8; ++j) s += hv[j] * Wgate[(j * 64 + lane) * NEXP + c];
#pragma unroll
    for (int off = 1; off < 64; off <<= 1) s += __shfl_xor(s, off);
    dg[c] = s;
  }
  if (lane == 0) {
#pragma unroll
    for (int c = 0; c < 8; ++c) {
      beta_o[t * NHEADS + c] = dev_sigmoid(db[c]);
      g_o[t * NHEADS + c] = -expf(A_log[c]) * dev_softplus(da[c] + dt_bias[c]);
    }
    float mx = fmaxf(fmaxf(dg[0], dg[1]), fmaxf(dg[2], dg[3]));
    float p[4]; float sum = 0.f;
#pragma unroll
    for (int c = 0; c < 4; ++c) { p[c] = expf(dg[c] - mx); sum += p[c]; }
#pragma unroll
    for (int c = 0; c < 4; ++c) p[c] /= sum;
    float v1 = -1e30f; int i1 = 0;
#pragma unroll
    for (int c = 0; c < 4; ++c) { if (p[c] > v1) { v1 = p[c]; i1 = c; } }
    float v2 = -1e30f; int i2 = -1;
#pragma unroll
    for (int c = 0; c < 4; ++c) { if (c != i1 && p[c] > v2) { v2 = p[c]; i2 = c; } }
    float s2v = v1 + v2;
#pragma unroll
    for (int c = 0; c < 4; ++c) {
      float wv = 0.f;
      if (c == i1) wv = v1 / s2v;
      else if (c == i2) wv = v2 / s2v;
      w_o[t * NEXP + c] = wv;
    }
  }
}

// ---------------- routed-token compaction (fallback path) ----------------
__global__ __launch_bounds__(64) void compact_kernel(
    const float* __restrict__ wbuf, int* __restrict__ tidx, int* __restrict__ tcnt) {
  const int e = blockIdx.x, b = blockIdx.y;
  const int lane = threadIdx.x;
  int* out = tidx + (e * BATCH + b) * SEQ;
  int cnt = 0;
  for (int g0 = 0; g0 < SEQ; g0 += 64) {
    const int l = g0 + lane;
    const float w = wbuf[(b * SEQ + l) * NEXP + e];
    const unsigned long long m = __ballot(w > 0.f);
    const int pos = __popcll(m & ((1ull << lane) - 1ull));
    if (w > 0.f) out[cnt + pos] = l;
    cnt += __popcll(m);
  }
  if (lane == 0) tcnt[e * BATCH + b] = cnt;
}

// ---------------- bf16 MFMA GEMM (proven R5) ----------------
#define LDA 56
template <int MODE>
__global__ __launch_bounds__(128) void gemm_mfma(
    const u16* __restrict__ A, const u16* __restrict__ Bt,
    float* __restrict__ C) {
  constexpr int K = DMODEL, N = DMODEL;
  __shared__ __align__(16) short As[128 * LDA];
  __shared__ __align__(16) short Bs[64 * LDA];
  const int tid = threadIdx.x;
  const int wave = tid >> 6, lane = tid & 63;
  const int quad = lane >> 4, l16 = lane & 15;
  const int m0 = blockIdx.x * 128, n0 = blockIdx.y * 64;
  const int bn = tid >> 1, bk = (tid & 1) * 16;
  const u16* Abase = A + (size_t)(m0 + tid) * K;
  const u16* Bbase = Bt + (size_t)(n0 + bn) * K + bk;

  f32x4 acc[4][4];
#pragma unroll
  for (int i = 0; i < 4; ++i)
#pragma unroll
    for (int j = 0; j < 4; ++j) acc[i][j] = (f32x4){0.f, 0.f, 0.f, 0.f};

  int4 pa0, pa1, pa2, pa3, pb0, pb1;
  {
    const u16* p = Abase;
    pa0 = *(const int4*)p; pa1 = *(const int4*)(p + 8);
    pa2 = *(const int4*)(p + 16); pa3 = *(const int4*)(p + 24);
    const u16* q = Bbase;
    pb0 = *(const int4*)q; pb1 = *(const int4*)(q + 8);
  }
  for (int kk = 0; kk < K; kk += 32) {
    __syncthreads();
    *(int4*)&As[tid * LDA + 0] = pa0;
    *(int4*)&As[tid * LDA + 8] = pa1;
    *(int4*)&As[tid * LDA + 16] = pa2;
    *(int4*)&As[tid * LDA + 24] = pa3;
    *(int4*)&Bs[bn * LDA + bk] = pb0;
    *(int4*)&Bs[bn * LDA + bk + 8] = pb1;
    __syncthreads();
    if (kk + 32 < K) {
      const u16* p = Abase + kk + 32;
      pa0 = *(const int4*)p; pa1 = *(const int4*)(p + 8);
      pa2 = *(const int4*)(p + 16); pa3 = *(const int4*)(p + 24);
      const u16* q = Bbase + kk + 32;
      pb0 = *(const int4*)q; pb1 = *(const int4*)(q + 8);
    }
    bf16x8 af[4], bfg[4];
#pragma unroll
    for (int mi = 0; mi < 4; ++mi)
      af[mi] = *(const bf16x8*)&As[(wave * 64 + mi * 16 + l16) * LDA + quad * 8];
#pragma unroll
    for (int ni = 0; ni < 4; ++ni)
      bfg[ni] = *(const bf16x8*)&Bs[(ni * 16 + l16) * LDA + quad * 8];
#pragma unroll
    for (int mi = 0; mi < 4; ++mi)
#pragma unroll
      for (int ni = 0; ni < 4; ++ni)
        acc[mi][ni] = __builtin_amdgcn_mfma_f32_16x16x32_bf16(af[mi], bfg[ni],
                                                              acc[mi][ni], 0, 0, 0);
  }
#pragma unroll
  for (int mi = 0; mi < 4; ++mi) {
#pragma unroll
    for (int r = 0; r < 4; ++r) {
      const int row = m0 + wave * 64 + mi * 16 + quad * 4 + r;
      float s[4];
#pragma unroll
      for (int ni = 0; ni < 4; ++ni) {
        float x = acc[mi][ni][r];
        s[ni] = (MODE == 0) ? x : dev_silu(x);
      }
      if (MODE == 2) {
        float ss = s[0] * s[0] + s[1] * s[1] + s[2] * s[2] + s[3] * s[3];
        ss += __shfl_xor(ss, 1);
        ss += __shfl_xor(ss, 2);
        ss += __shfl_xor(ss, 4);
        ss += __shfl_xor(ss, 8);
        const float rn = 1.0f / sqrtf(ss + 1e-6f);
#pragma unroll
        for (int ni = 0; ni < 4; ++ni) s[ni] *= rn;
      }
#pragma unroll
      for (int ni = 0; ni < 4; ++ni)
        C[(size_t)row * N + n0 + ni * 16 + l16] = s[ni];
    }
  }
}

// ================= CHUNKED GATED DELTA RULE =================
// Per (e,b,h), chunk of C=64 tokens, inclusive decay cumsum c_t (masked g):
//   T[t][s] = beta_t exp(c_t-c_s)(k_t.k_s), s<t
//   (I+T) [U0 | W] = [beta V | beta exp(c) K]   (forward substitution)
//   u = U0 - W S0;  S' = exp(c63) S0 + Kp^T u,  Kp[t] = exp(c63-c_t) k_t
//   o_t = scale( exp(c_t) q_t^T S0 + sum_{s<=t} exp(c_t-c_s)(q_t.k_s) u_s )

// ---- phase 1: parallel over (e,b,h,chunk): T, solve, store U0/W, cumsum ----
__global__ __launch_bounds__(256) void chunk_phase1(
    const float* __restrict__ kb, const float* __restrict__ vb,
    const float* __restrict__ betab, const float* __restrict__ gbuf,
    const float* __restrict__ wbuf, float* __restrict__ U0buf,
    float* __restrict__ Wbuf, float* __restrict__ cbuf) {
  const int c = blockIdx.x;
  const int eb = blockIdx.y;
  const int h = blockIdx.z;
  const int e = eb / BATCH, b = eb % BATCH;
  const int chunkid = (eb * NHEADS + h) * NCHUNK + c;
  const int tid = threadIdx.x;

  __shared__ float Kd[64][68];  // [d][t]
  __shared__ float Ks[64][68];  // [t][d]
  __shared__ float Vs[64][68];  // [t][dv]
  __shared__ float Tm[64][68];  // [t][s]
  __shared__ float cc[64], bb[64], exs[64];

  if (tid < 64) {
    const int gt = b * SEQ + c * 64 + tid;
    const float w = wbuf[gt * NEXP + e];
    float gv = 0.f, bv = 0.f;
    if (w > 0.f) { gv = gbuf[gt * NHEADS + h]; bv = betab[gt * NHEADS + h]; }
    float cum = gv;
#pragma unroll
    for (int off = 1; off < 64; off <<= 1) {
      float o = __shfl_up(cum, off);
      if (tid >= off) cum += o;
    }
    cc[tid] = cum; exs[tid] = expf(cum); bb[tid] = bv;
    cbuf[(size_t)chunkid * 64 + tid] = cum;
  }
  {
    const int t = tid >> 2;
    const int c0 = (tid & 3) * 16;
    const int gt = b * SEQ + c * 64 + t;
    const float* krow = kb + (size_t)gt * DMODEL + h * 64;
    const float* vrow = vb + (size_t)gt * DMODEL + h * 64;
#pragma unroll
    for (int j = 0; j < 4; ++j) {
      const int d = c0 + j * 4;
      float4 kv = *(const float4*)(krow + d);
      float4 vv = *(const float4*)(vrow + d);
      *(float4*)&Ks[t][d] = kv;
      *(float4*)&Vs[t][d] = vv;
      Kd[d + 0][t] = kv.x; Kd[d + 1][t] = kv.y; Kd[d + 2][t] = kv.z; Kd[d + 3][t] = kv.w;
    }
  }
  __syncthreads();
  {
    const int tt = (tid >> 4) * 4, ss = (tid & 15) * 4;
    float a[4][4] = {};
#pragma unroll
    for (int d = 0; d < 64; ++d) {
      const v4f ka = *(const v4f*)&Kd[d][tt];
      const v4f kv = *(const v4f*)&Kd[d][ss];
#pragma unroll
      for (int i = 0; i < 4; ++i)
#pragma unroll
        for (int j = 0; j < 4; ++j) a[i][j] = fmaf(ka[i], kv[j], a[i][j]);
    }
#pragma unroll
    for (int i = 0; i < 4; ++i)
#pragma unroll
      for (int j = 0; j < 4; ++j) {
        const float dd = fminf(cc[tt + i] - cc[ss + j], 0.f);
        Tm[tt + i][ss + j] = bb[tt + i] * expf(dd) * a[i][j];
      }
  }
  __syncthreads();
  if (tid < 128) {
    const int col = tid;
    const bool isV = col < 64;
    const float* Rs = isV ? &Vs[0][col] : &Ks[0][col - 64];
    float u[64];
#pragma unroll
    for (int t = 0; t < 64; ++t) {
      const float sc = isV ? bb[t] : bb[t] * exs[t];
      float val = sc * Rs[t * 68];
#pragma unroll
      for (int r = 0; r < t; ++r) val = fmaf(-Tm[t][r], u[r], val);
      u[t] = val;
    }
    float* dst = isV ? (U0buf + (size_t)chunkid * 4096 + col)
                     : (Wbuf + (size_t)chunkid * 4096 + (col - 64));
#pragma unroll
    for (int t = 0; t < 64; ++t) dst[(size_t)t * 64] = u[t];
  }
}

// ---- phase 2: serial chunk chain per (e,b,h) x dv-half; U in-place, S snapshots ----
__global__ __launch_bounds__(256) void chunk_phase2(
    const float* __restrict__ kb, const float* __restrict__ cbuf,
    float* __restrict__ U0buf /* becomes U */, const float* __restrict__ Wbuf,
    float* __restrict__ Sbuf) {
  const int dvh = blockIdx.x;
  const int eb = blockIdx.y;
  const int h = blockIdx.z;
  const int b = eb % BATCH;
  const int ebh = eb * NHEADS + h;
  const int tid = threadIdx.x;

  __shared__ float Wt[64][68];   // [dk][t]
  __shared__ float Ksl[64][68];  // [t][dk]
  __shared__ float Sl[64][36];   // [dk][dvl]
  __shared__ float Ul[64][36];   // [t][dvl]
  __shared__ float ext2[64];
  __shared__ float gam;

  for (int i = tid; i < 64 * 36; i += 256) (&Sl[0][0])[i] = 0.f;

  const int tx = tid & 15, ty = tid >> 4;
  const int t0 = ty * 4, dv0 = tx * 2;

  for (int c = 0; c < NCHUNK; ++c) {
    const int chunkid = ebh * NCHUNK + c;
    const size_t base = (size_t)chunkid * 4096;
    if (tid < 64) {
      const float cv = cbuf[(size_t)chunkid * 64 + tid];
      const float c63 = __shfl(cv, 63);
      ext2[tid] = expf(c63 - cv);
      if (tid == 0) gam = expf(c63);
    }
    {
      const int t = tid >> 2;
      const int c0 = (tid & 3) * 16;
      const int gt = b * SEQ + c * 64 + t;
      const float* wrow = Wbuf + base + (size_t)t * 64;
      const float* krow = kb + (size_t)gt * DMODEL + h * 64;
#pragma unroll
      for (int j = 0; j < 4; ++j) {
        const int d = c0 + j * 4;
        float4 wv = *(const float4*)(wrow + d);
        float4 kv = *(const float4*)(krow + d);
        Wt[d + 0][t] = wv.x; Wt[d + 1][t] = wv.y; Wt[d + 2][t] = wv.z; Wt[d + 3][t] = wv.w;
        *(float4*)&Ksl[t][d] = kv;
      }
    }
    __syncthreads();
    // snapshot chunk-start state
    for (int i = tid; i < 2048; i += 256) {
      const int dk = i >> 5, dvl = i & 31;
      Sbuf[base + dk * 64 + dvh * 32 + dvl] = Sl[dk][dvl];
    }
    // U = U0 - W * S
    float acc[4][2] = {};
#pragma unroll
    for (int k = 0; k < 64; ++k) {
      const v4f a = *(const v4f*)&Wt[k][t0];
      const v2f bv = *(const v2f*)&Sl[k][dv0];
#pragma unroll
      for (int i = 0; i < 4; ++i)
#pragma unroll
        for (int j = 0; j < 2; ++j) acc[i][j] = fmaf(a[i], bv[j], acc[i][j]);
    }
#pragma unroll
    for (int i = 0; i < 4; ++i)
#pragma unroll
      for (int j = 0; j < 2; ++j) {
        const size_t gi = base + (size_t)(t0 + i) * 64 + dvh * 32 + dv0 + j;
        const float uv = U0buf[gi] - acc[i][j];
        U0buf[gi] = uv;
        Ul[t0 + i][dv0 + j] = uv;
      }
    __syncthreads();
    // S = gam*S + Kp^T U  (tile over dk = t0)
    float acc2[4][2] = {};
#pragma unroll
    for (int k = 0; k < 64; ++k) {
      const v4f a = *(const v4f*)&Ksl[k][t0];
      const float ex = ext2[k];
      const v2f uv = *(const v2f*)&Ul[k][dv0];
      const v2f us = (v2f){uv[0] * ex, uv[1] * ex};
#pragma unroll
      for (int i = 0; i < 4; ++i)
#pragma unroll
        for (int j = 0; j < 2; ++j) acc2[i][j] = fmaf(a[i], us[j], acc2[i][j]);
    }
    const float g = gam;
#pragma unroll
    for (int i = 0; i < 4; ++i)
#pragma unroll
      for (int j = 0; j < 2; ++j)
        Sl[t0 + i][dv0 + j] = g * Sl[t0 + i][dv0 + j] + acc2[i][j];
    __syncthreads();
  }
}

// ---- phase 3: parallel over (e,b,h,chunk,dv-half): outputs + masked combine ----
__global__ __launch_bounds__(256) void chunk_phase3(
    const float* __restrict__ qb, const float* __restrict__ kb,
    const float* __restrict__ cbuf, const float* __restrict__ U0buf /*U*/,
    const float* __restrict__ Sbuf, const float* __restrict__ wbuf,
    float* __restrict__ coreb) {
  const int c = blockIdx.x;
  const int y = blockIdx.y;
  const int h = blockIdx.z;
  const int eb = y >> 1, dvh = y & 1;
  const int e = eb / BATCH, b = eb % BATCH;
  const int chunkid = (eb * NHEADS + h) * NCHUNK + c;
  const size_t base = (size_t)chunkid * 4096;
  const int tid = threadIdx.x;

  __shared__ float Qd[64][68];   // [d][t]
  __shared__ float Kd3[64][68];  // [d][t]
  __shared__ float Pt[64][68];   // [s][t]
  __shared__ float Sh[64][36];   // [dk][dvl]
  __shared__ float Uh[64][36];   // [s][dvl]
  __shared__ float cc3[64];

  if (tid < 64) cc3[tid] = cbuf[(size_t)chunkid * 64 + tid];
  {
    const int t = tid >> 2, c0 = (tid & 3) * 16;
    const int gt = b * SEQ + c * 64 + t;
    const float* qrow = qb + (size_t)gt * DMODEL + h * 64;
    const float* krow = kb + (size_t)gt * DMODEL + h * 64;
#pragma unroll
    for (int j = 0; j < 4; ++j) {
      const int d = c0 + j * 4;
      float4 qv = *(const float4*)(qrow + d);
      float4 kv = *(const float4*)(krow + d);
      Qd[d + 0][t] = qv.x; Qd[d + 1][t] = qv.y; Qd[d + 2][t] = qv.z; Qd[d + 3][t] = qv.w;
      Kd3[d + 0][t] = kv.x; Kd3[d + 1][t] = kv.y; Kd3[d + 2][t] = kv.z; Kd3[d + 3][t] = kv.w;
    }
  }
  for (int i = tid; i < 2048; i += 256) {
    const int r = i >> 5, q_ = i & 31;
    Sh[r][q_] = Sbuf[base + r * 64 + dvh * 32 + q_];
    Uh[r][q_] = U0buf[base + r * 64 + dvh * 32 + q_];
  }
  __syncthreads();
  {
    const int tt = (tid >> 4) * 4, ss = (tid & 15) * 4;
    float a[4][4] = {};
#pragma unroll
    for (int d = 0; d < 64; ++d) {
      const v4f qa = *(const v4f*)&Qd[d][tt];
      const v4f ka = *(const v4f*)&Kd3[d][ss];
#pragma unroll
      for (int i = 0; i < 4; ++i)
#pragma unroll
        for (int j = 0; j < 4; ++j) a[i][j] = fmaf(qa[i], ka[j], a[i][j]);
    }
#pragma unroll
    for (int i = 0; i < 4; ++i)
#pragma unroll
      for (int j = 0; j < 4; ++j) {
        const int t = tt + i, s = ss + j;
        Pt[s][t] = (s <= t) ? expf(cc3[t] - cc3[s]) * a[i][j] : 0.f;
      }
  }
  __syncthreads();
  {
    const int tx = tid & 15, ty = tid >> 4;
    const int t0 = ty * 4, dv0 = tx * 2;
    float acc1[4][2] = {}, acc2[4][2] = {};
#pragma unroll
    for (int k = 0; k < 64; ++k) {
      const v4f qa = *(const v4f*)&Qd[k][t0];
      const v2f sv = *(const v2f*)&Sh[k][dv0];
      const v4f pa = *(const v4f*)&Pt[k][t0];
      const v2f uv = *(const v2f*)&Uh[k][dv0];
#pragma unroll
      for (int i = 0; i < 4; ++i)
#pragma unroll
        for (int j = 0; j < 2; ++j) {
          acc1[i][j] = fmaf(qa[i], sv[j], acc1[i][j]);
          acc2[i][j] = fmaf(pa[i], uv[j], acc2[i][j]);
        }
    }
#pragma unroll
    for (int i = 0; i < 4; ++i) {
      const int t = t0 + i;
      const int gt = b * SEQ + c * 64 + t;
      const float wv = wbuf[gt * NEXP + e];
      if (wv > 0.f) {
        const float ex = expf(cc3[t]);
#pragma unroll
        for (int j = 0; j < 2; ++j) {
          const float o = 0.125f * (ex * acc1[i][j] + acc2[i][j]);
          atomicAdd(&coreb[(size_t)gt * DMODEL + h * 64 + dvh * 32 + dv0 + j], wv * o);
        }
      }
    }
  }
}

// ---------------- fallback serial scan (R3-proven) ----------------
__global__ __launch_bounds__(64) void scan_kernel(
    const float* __restrict__ qb, const float* __restrict__ kb,
    const float* __restrict__ vb, const float* __restrict__ betab,
    const float* __restrict__ gbuf, const float* __restrict__ wbuf,
    const int* __restrict__ tidx, const int* __restrict__ tcnt,
    float* __restrict__ coreb) {
  const int vhalf = blockIdx.x & 1, e = blockIdx.x >> 1;
  const int b = blockIdx.y, hh = blockIdx.z;
  const int lane = threadIdx.x;
  const int kh = lane >> 5;
  const int vi = lane & 31;
  const int cv = vhalf * 32 + vi;
  const int* idx = tidx + (e * BATCH + b) * SEQ;
  const int n = tcnt[e * BATCH + b];
  if (n == 0) return;
  const int nm1 = n - 1;
  __shared__ __align__(16) float lk[4][64];
  __shared__ __align__(16) float lq[4][64];
  __shared__ int lidx[SEQ];
  for (int i = lane; i < SEQ; i += 64) lidx[i] = idx[i < n ? i : nm1];
  __syncthreads();
  v2f S2[16];
#pragma unroll
  for (int j = 0; j < 16; ++j) S2[j] = (v2f){0.f, 0.f};
  float kf[4], qf[4], vf[4], gf[4], bf[4], wf[4], egr[4];
  int tcur[4], tok4[4];
#define PREF(SLOT, TK)                                          \
  do {                                                          \
    const int tn_ = b * SEQ + (TK);                             \
    const size_t kq_ = (size_t)tn_ * DMODEL + hh * 64 + lane;   \
    kf[SLOT] = kb[kq_];                                         \
    qf[SLOT] = qb[kq_];                                         \
    vf[SLOT] = vb[(size_t)tn_ * DMODEL + hh * 64 + cv];         \
    gf[SLOT] = gbuf[tn_ * NHEADS + hh];                         \
    bf[SLOT] = betab[tn_ * NHEADS + hh];                        \
    wf[SLOT] = wbuf[tn_ * NEXP + e];                            \
    tcur[SLOT] = tn_;                                           \
  } while (0)
  tok4[0] = lidx[0];
  tok4[1] = lidx[1 < n ? 1 : nm1];
  tok4[2] = lidx[2 < n ? 2 : nm1];
  tok4[3] = lidx[3 < n ? 3 : nm1];
  PREF(0, tok4[0]); PREF(1, tok4[1]); PREF(2, tok4[2]);
  lk[0][lane] = kf[0]; lq[0][lane] = qf[0];
  egr[0] = expf(gf[0]);
  const int m = (n + 3) & ~3;
  for (int i = 0; i < m; i += 4) {
#pragma unroll
    for (int u = 0; u < 4; ++u) {
      const int s = i + u;
      const int sN = (u + 3) & 3;
      const int s1 = (u + 1) & 3;
      PREF(sN, tok4[sN]);
      int a4 = s + 4;
      a4 = a4 < nm1 ? a4 : nm1;
      tok4[u] = lidx[a4];
      __builtin_amdgcn_wave_barrier();
      lk[s1][lane] = kf[s1];
      lq[s1][lane] = qf[s1];
      __builtin_amdgcn_wave_barrier();
      egr[s1] = expf(gf[s1]);
      const v4f* lk4 = (const v4f*)&lk[u][kh * 32];
      const v4f* lq4 = (const v4f*)&lq[u][kh * 32];
      v2f myk[16];
      v2f c0 = (v2f){0.f, 0.f}, c1 = c0, c2 = c0, c3 = c0;
#pragma unroll
      for (int j = 0; j < 8; ++j) {
        const v4f k4 = lk4[j];
        const v2f klo = (v2f){k4.x, k4.y};
        const v2f khi = (v2f){k4.z, k4.w};
        myk[2 * j] = klo; myk[2 * j + 1] = khi;
        if (j & 1) {
          c2 = __builtin_elementwise_fma(klo, S2[2 * j], c2);
          c3 = __builtin_elementwise_fma(khi, S2[2 * j + 1], c3);
        } else {
          c0 = __builtin_elementwise_fma(klo, S2[2 * j], c0);
          c1 = __builtin_elementwise_fma(khi, S2[2 * j + 1], c1);
        }
      }
      const v2f cacc = (c0 + c1) + (c2 + c3);
      float cd = cacc.x + cacc.y;
      cd += __shfl_xor(cd, 32);
      const float egc = egr[u];
      const float delta = (vf[u] - egc * cd) * bf[u];
      const v2f d2 = (v2f){delta, delta};
      const v2f eg2 = (v2f){egc, egc};
      v2f o0 = (v2f){0.f, 0.f}, o1 = o0, o2 = o0, o3 = o0;
#pragma unroll
      for (int j = 0; j < 8; ++j) {
        const v4f q4 = lq4[j];
        const v2f qlo = (v2f){q4.x, q4.y};
        const v2f qhi = (v2f){q4.z, q4.w};
        const v2f s0 = __builtin_elementwise_fma(S2[2 * j], eg2, myk[2 * j] * d2);
        const v2f s1v = __builtin_elementwise_fma(S2[2 * j + 1], eg2, myk[2 * j + 1] * d2);
        S2[2 * j] = s0; S2[2 * j + 1] = s1v;
        if (j & 1) {
          o2 = __builtin_elementwise_fma(qlo, s0, o2);
          o3 = __builtin_elementwise_fma(qhi, s1v, o3);
        } else {
          o0 = __builtin_elementwise_fma(qlo, s0, o0);
          o1 = __builtin_elementwise_fma(qhi, s1v, o1);
        }
      }
      const v2f oacc = (o0 + o1) + (o2 + o3);
      float o = oacc.x + oacc.y;
      o += __shfl_xor(o, 32);
      if (kh == 0 && s < n)
        atomicAdd(&coreb[(size_t)tcur[u] * DMODEL + hh * 64 + cv],
                  o * 0.125f * wf[u]);
    }
  }
#undef PREF
}

// ---------------- fused gated RMSNorm -> bf16 ----------------
__global__ __launch_bounds__(512) void rmsnorm_kernel(
    const float* __restrict__ coreb, const float* __restrict__ gateb,
    const float* __restrict__ wn, u16* __restrict__ outb) {
  const int t = blockIdx.x;
  const int tid = threadIdx.x;
  const int v = tid & 63;
  const float x = coreb[(size_t)t * DMODEL + tid];
  float ss = x * x;
#pragma unroll
  for (int off = 1; off < 64; off <<= 1) ss += __shfl_xor(ss, off);
  const float r = rsqrtf(ss * (1.0f / 64.0f) + 1e-5f);
  const float gt = gateb[(size_t)t * DMODEL + tid];
  outb[(size_t)t * DMODEL + tid] = f2b(x * r * wn[v] * gt);
}

extern "C" void kernel_launch(void* const* d_in, const int* in_sizes, int n_in,
                              void* d_out, int out_size, void* d_ws, size_t ws_size,
                              hipStream_t stream) {
  const float* h       = (const float*)d_in[0];
  const float* Wq      = (const float*)d_in[1];
  const float* Wgate   = (const float*)d_in[2];
  const float* Wk      = (const float*)d_in[3];
  const float* Wv      = (const float*)d_in[4];
  const float* Wb      = (const float*)d_in[5];
  const float* Wa      = (const float*)d_in[6];
  const float* A_log   = (const float*)d_in[7];
  const float* dt_bias = (const float*)d_in[8];
  const float* Wg      = (const float*)d_in[9];
  const float* wn      = (const float*)d_in[10];
  const float* Wo      = (const float*)d_in[11];
  float* out = (float*)d_out;

  char* p = (char*)d_ws;
  const size_t big = (size_t)NTOK * DMODEL;  // 2M elements
  auto alloc = [&](size_t bytes) { char* r = p; p += (bytes + 255) & ~255ull; return r; };
  float* qb    = (float*)alloc(big * 4);
  float* kb    = (float*)alloc(big * 4);
  float* vb    = (float*)alloc(big * 4);
  float* gateb = (float*)alloc(big * 4);
  float* coreb = (float*)alloc(big * 4);
  float* betab = (float*)alloc((size_t)NTOK * NHEADS * 4);
  float* gbuf  = (float*)alloc((size_t)NTOK * NHEADS * 4);
  float* wbuf  = (float*)alloc((size_t)NTOK * NEXP * 4);
  int*   tidx  = (int*)alloc((size_t)NEXP * BATCH * SEQ * 4);
  int*   tcnt  = (int*)alloc(256);
  u16*   hb    = (u16*)alloc(big * 2);
  u16*   nb    = (u16*)alloc(big * 2);
  u16*   wtq   = (u16*)alloc((size_t)DMODEL * DMODEL * 2);
  u16*   wtk   = (u16*)alloc((size_t)DMODEL * DMODEL * 2);
  u16*   wtv   = (u16*)alloc((size_t)DMODEL * DMODEL * 2);
  u16*   wtg   = (u16*)alloc((size_t)DMODEL * DMODEL * 2);
  u16*   wto   = (u16*)alloc((size_t)DMODEL * DMODEL * 2);
  // chunked-path extras
  const size_t nchunks = (size_t)NEXP * BATCH * NHEADS * NCHUNK;  // 2048
  float* U0buf = (float*)alloc(nchunks * 4096 * 4);
  float* Wbuf_ = (float*)alloc(nchunks * 4096 * 4);
  float* Sbuf  = (float*)alloc(nchunks * 4096 * 4);
  float* cbuf  = (float*)alloc(nchunks * 64 * 4);
  const size_t need = (size_t)(p - (char*)d_ws);
  const bool use_chunked = (ws_size >= need);

  zero_kernel<<<dim3(NTOK * DMODEL / 4 / 256), 256, 0, stream>>>((float4*)coreb);

  cast_h_kernel<<<dim3(big / 4 / 256), 256, 0, stream>>>((const float4*)h, (ushort4*)hb);
  dim3 tg(16, 16);
  castT_kernel<<<tg, 256, 0, stream>>>(Wq, wtq);
  castT_kernel<<<tg, 256, 0, stream>>>(Wk, wtk);
  castT_kernel<<<tg, 256, 0, stream>>>(Wv, wtv);
  castT_kernel<<<tg, 256, 0, stream>>>(Wg, wtg);
  castT_kernel<<<tg, 256, 0, stream>>>(Wo, wto);

  router_kernel<<<dim3(NTOK), 64, 0, stream>>>(h, Wb, Wa, Wgate, A_log, dt_bias,
                                               betab, gbuf, wbuf);

  dim3 gg(NTOK / 128, DMODEL / 64);
  gemm_mfma<2><<<gg, 128, 0, stream>>>(hb, wtq, qb);
  gemm_mfma<2><<<gg, 128, 0, stream>>>(hb, wtk, kb);
  gemm_mfma<1><<<gg, 128, 0, stream>>>(hb, wtv, vb);
  gemm_mfma<1><<<gg, 128, 0, stream>>>(hb, wtg, gateb);

  if (use_chunked) {
    chunk_phase1<<<dim3(NCHUNK, NEXP * BATCH, NHEADS), 256, 0, stream>>>(
        kb, vb, betab, gbuf, wbuf, U0buf, Wbuf_, cbuf);
    chunk_phase2<<<dim3(2, NEXP * BATCH, NHEADS), 256, 0, stream>>>(
        kb, cbuf, U0buf, Wbuf_, Sbuf);
    chunk_phase3<<<dim3(NCHUNK, NEXP * BATCH * 2, NHEADS), 256, 0, stream>>>(
        qb, kb, cbuf, U0buf, Sbuf, wbuf, coreb);
  } else {
    compact_kernel<<<dim3(NEXP, BATCH), 64, 0, stream>>>(wbuf, tidx, tcnt);
    scan_kernel<<<dim3(NEXP * 2, BATCH, NHEADS), 64, 0, stream>>>(
        qb, kb, vb, betab, gbuf, wbuf, tidx, tcnt, coreb);
  }

  rmsnorm_kernel<<<dim3(NTOK), 512, 0, stream>>>(coreb, gateb, wn, nb);

  gemm_mfma<0><<<gg, 128, 0, stream>>>(nb, wto, out);
}

// Round 7
// 335.439 us; speedup vs baseline: 9.9871x; 9.9871x over previous
//
#include <hip/hip_runtime.h>
#include <math.h>

#define DMODEL 512
#define NHEADS 8
#define NEXP 4
#define SEQ 1024
#define BATCH 4
#define NTOK 4096  // BATCH * SEQ
#define NCHUNK 16  // SEQ / 64

typedef float v2f __attribute__((ext_vector_type(2)));
typedef float v4f __attribute__((ext_vector_type(4)));
typedef short bf16x8 __attribute__((ext_vector_type(8)));
typedef float f32x4 __attribute__((ext_vector_type(4)));
typedef unsigned short u16;

__device__ __forceinline__ float dev_sigmoid(float x) { return 1.0f / (1.0f + expf(-x)); }
__device__ __forceinline__ float dev_silu(float x) { return x / (1.0f + expf(-x)); }
__device__ __forceinline__ float dev_softplus(float x) {
  return x > 0.0f ? x + log1pf(expf(-x)) : log1pf(expf(x));
}
// fp32 -> bf16 bits, round-to-nearest-even
__device__ __forceinline__ u16 f2b(float f) {
  unsigned int u = __float_as_uint(f);
  unsigned int r = (u + 0x7fffu + ((u >> 16) & 1u)) >> 16;
  return (u16)r;
}
__device__ __forceinline__ ushort4 f2b4(float4 v) {
  ushort4 o; o.x = f2b(v.x); o.y = f2b(v.y); o.z = f2b(v.z); o.w = f2b(v.w); return o;
}

// bf16 LDS row stride in shorts: 72 (144 B) -> 16B-aligned fragments, ~2-way banks
#define BST 72

// ---------------- zero kernel ----------------
__global__ __launch_bounds__(256) void zero_kernel(float4* __restrict__ p) {
  p[(size_t)blockIdx.x * 256 + threadIdx.x] = make_float4(0.f, 0.f, 0.f, 0.f);
}

// ---------------- cast h (fp32) -> bf16 bits ----------------
__global__ __launch_bounds__(256) void cast_h_kernel(const float4* __restrict__ in,
                                                     ushort4* __restrict__ outp) {
  const size_t i = (size_t)blockIdx.x * 256 + threadIdx.x;
  outp[i] = f2b4(in[i]);
}

// ---------------- transpose-cast weight: W[512][512] fp32 -> Wt[n][k] bf16 -------------
__global__ __launch_bounds__(256) void castT_kernel(const float* __restrict__ in,
                                                    u16* __restrict__ outp) {
  __shared__ float tile[32][33];
  const int bx = blockIdx.x * 32;  // k base
  const int by = blockIdx.y * 32;  // n base
  const int c = threadIdx.x & 31, r0 = threadIdx.x >> 5;
#pragma unroll
  for (int r = r0; r < 32; r += 8) tile[r][c] = in[(size_t)(bx + r) * DMODEL + by + c];
  __syncthreads();
#pragma unroll
  for (int r = r0; r < 32; r += 8)
    outp[(size_t)(by + r) * DMODEL + bx + c] = f2b(tile[c][r]);
}

// ---------------- router + beta/g small projections: one wave per token ----------------
__global__ __launch_bounds__(64) void router_kernel(
    const float* __restrict__ h, const float* __restrict__ Wb,
    const float* __restrict__ Wa, const float* __restrict__ Wgate,
    const float* __restrict__ A_log, const float* __restrict__ dt_bias,
    float* __restrict__ beta_o, float* __restrict__ g_o, float* __restrict__ w_o) {
  const int t = blockIdx.x;
  const int lane = threadIdx.x;
  float hv[8];
#pragma unroll
  for (int j = 0; j < 8; ++j) hv[j] = h[(size_t)t * DMODEL + j * 64 + lane];
  float db[8], da[8], dg[4];
#pragma unroll
  for (int c = 0; c < 8; ++c) {
    float s1 = 0.f, s2 = 0.f;
#pragma unroll
    for (int j = 0; j < 8; ++j) {
      int row = j * 64 + lane;
      s1 += hv[j] * Wb[row * NHEADS + c];
      s2 += hv[j] * Wa[row * NHEADS + c];
    }
#pragma unroll
    for (int off = 1; off < 64; off <<= 1) {
      s1 += __shfl_xor(s1, off);
      s2 += __shfl_xor(s2, off);
    }
    db[c] = s1; da[c] = s2;
  }
#pragma unroll
  for (int c = 0; c < 4; ++c) {
    float s = 0.f;
#pragma unroll
    for (int j = 0; j < 8; ++j) s += hv[j] * Wgate[(j * 64 + lane) * NEXP + c];
#pragma unroll
    for (int off = 1; off < 64; off <<= 1) s += __shfl_xor(s, off);
    dg[c] = s;
  }
  if (lane == 0) {
#pragma unroll
    for (int c = 0; c < 8; ++c) {
      beta_o[t * NHEADS + c] = dev_sigmoid(db[c]);
      g_o[t * NHEADS + c] = -expf(A_log[c]) * dev_softplus(da[c] + dt_bias[c]);
    }
    float mx = fmaxf(fmaxf(dg[0], dg[1]), fmaxf(dg[2], dg[3]));
    float p[4]; float sum = 0.f;
#pragma unroll
    for (int c = 0; c < 4; ++c) { p[c] = expf(dg[c] - mx); sum += p[c]; }
#pragma unroll
    for (int c = 0; c < 4; ++c) p[c] /= sum;
    float v1 = -1e30f; int i1 = 0;
#pragma unroll
    for (int c = 0; c < 4; ++c) { if (p[c] > v1) { v1 = p[c]; i1 = c; } }
    float v2 = -1e30f; int i2 = -1;
#pragma unroll
    for (int c = 0; c < 4; ++c) { if (c != i1 && p[c] > v2) { v2 = p[c]; i2 = c; } }
    float s2v = v1 + v2;
#pragma unroll
    for (int c = 0; c < 4; ++c) {
      float wv = 0.f;
      if (c == i1) wv = v1 / s2v;
      else if (c == i2) wv = v2 / s2v;
      w_o[t * NEXP + c] = wv;
    }
  }
}

// ---------------- routed-token compaction (fallback path) ----------------
__global__ __launch_bounds__(64) void compact_kernel(
    const float* __restrict__ wbuf, int* __restrict__ tidx, int* __restrict__ tcnt) {
  const int e = blockIdx.x, b = blockIdx.y;
  const int lane = threadIdx.x;
  int* out = tidx + (e * BATCH + b) * SEQ;
  int cnt = 0;
  for (int g0 = 0; g0 < SEQ; g0 += 64) {
    const int l = g0 + lane;
    const float w = wbuf[(b * SEQ + l) * NEXP + e];
    const unsigned long long m = __ballot(w > 0.f);
    const int pos = __popcll(m & ((1ull << lane) - 1ull));
    if (w > 0.f) out[cnt + pos] = l;
    cnt += __popcll(m);
  }
  if (lane == 0) tcnt[e * BATCH + b] = cnt;
}

// ---------------- bf16 MFMA GEMM (proven R5) ----------------
#define LDA 56
template <int MODE>
__global__ __launch_bounds__(128) void gemm_mfma(
    const u16* __restrict__ A, const u16* __restrict__ Bt,
    float* __restrict__ C) {
  constexpr int K = DMODEL, N = DMODEL;
  __shared__ __align__(16) short As[128 * LDA];
  __shared__ __align__(16) short Bs[64 * LDA];
  const int tid = threadIdx.x;
  const int wave = tid >> 6, lane = tid & 63;
  const int quad = lane >> 4, l16 = lane & 15;
  const int m0 = blockIdx.x * 128, n0 = blockIdx.y * 64;
  const int bn = tid >> 1, bk = (tid & 1) * 16;
  const u16* Abase = A + (size_t)(m0 + tid) * K;
  const u16* Bbase = Bt + (size_t)(n0 + bn) * K + bk;

  f32x4 acc[4][4];
#pragma unroll
  for (int i = 0; i < 4; ++i)
#pragma unroll
    for (int j = 0; j < 4; ++j) acc[i][j] = (f32x4){0.f, 0.f, 0.f, 0.f};

  int4 pa0, pa1, pa2, pa3, pb0, pb1;
  {
    const u16* p = Abase;
    pa0 = *(const int4*)p; pa1 = *(const int4*)(p + 8);
    pa2 = *(const int4*)(p + 16); pa3 = *(const int4*)(p + 24);
    const u16* q = Bbase;
    pb0 = *(const int4*)q; pb1 = *(const int4*)(q + 8);
  }
  for (int kk = 0; kk < K; kk += 32) {
    __syncthreads();
    *(int4*)&As[tid * LDA + 0] = pa0;
    *(int4*)&As[tid * LDA + 8] = pa1;
    *(int4*)&As[tid * LDA + 16] = pa2;
    *(int4*)&As[tid * LDA + 24] = pa3;
    *(int4*)&Bs[bn * LDA + bk] = pb0;
    *(int4*)&Bs[bn * LDA + bk + 8] = pb1;
    __syncthreads();
    if (kk + 32 < K) {
      const u16* p = Abase + kk + 32;
      pa0 = *(const int4*)p; pa1 = *(const int4*)(p + 8);
      pa2 = *(const int4*)(p + 16); pa3 = *(const int4*)(p + 24);
      const u16* q = Bbase + kk + 32;
      pb0 = *(const int4*)q; pb1 = *(const int4*)(q + 8);
    }
    bf16x8 af[4], bfg[4];
#pragma unroll
    for (int mi = 0; mi < 4; ++mi)
      af[mi] = *(const bf16x8*)&As[(wave * 64 + mi * 16 + l16) * LDA + quad * 8];
#pragma unroll
    for (int ni = 0; ni < 4; ++ni)
      bfg[ni] = *(const bf16x8*)&Bs[(ni * 16 + l16) * LDA + quad * 8];
#pragma unroll
    for (int mi = 0; mi < 4; ++mi)
#pragma unroll
      for (int ni = 0; ni < 4; ++ni)
        acc[mi][ni] = __builtin_amdgcn_mfma_f32_16x16x32_bf16(af[mi], bfg[ni],
                                                              acc[mi][ni], 0, 0, 0);
  }
#pragma unroll
  for (int mi = 0; mi < 4; ++mi) {
#pragma unroll
    for (int r = 0; r < 4; ++r) {
      const int row = m0 + wave * 64 + mi * 16 + quad * 4 + r;
      float s[4];
#pragma unroll
      for (int ni = 0; ni < 4; ++ni) {
        float x = acc[mi][ni][r];
        s[ni] = (MODE == 0) ? x : dev_silu(x);
      }
      if (MODE == 2) {
        float ss = s[0] * s[0] + s[1] * s[1] + s[2] * s[2] + s[3] * s[3];
        ss += __shfl_xor(ss, 1);
        ss += __shfl_xor(ss, 2);
        ss += __shfl_xor(ss, 4);
        ss += __shfl_xor(ss, 8);
        const float rn = 1.0f / sqrtf(ss + 1e-6f);
#pragma unroll
        for (int ni = 0; ni < 4; ++ni) s[ni] *= rn;
      }
#pragma unroll
      for (int ni = 0; ni < 4; ++ni)
        C[(size_t)row * N + n0 + ni * 16 + l16] = s[ni];
    }
  }
}

// ================= CHUNKED GATED DELTA RULE (MFMA) =================
// c_t = inclusive masked decay cumsum. T[t][s] = b_t e^{c_t-c_s}(k_t.k_s), s<t.
// (I+T)[U0|W] = [bV | diag(b e^c)K]. Delta = U0 - W S0.
// S' = e^{c63} S0 + sum_s e^{c63-c_s} k_s Delta_s^T.
// o_t = scale(e^{c_t} q_t^T S0 + sum_{s<=t} e^{c_t-c_s}(q_t.k_s) Delta_s).

// ---- phase 1: parallel (chunk, eb, h). KK^T via MFMA; fp32 triangular solve ----
__global__ __launch_bounds__(256) void chunk_phase1(
    const float* __restrict__ kb, const float* __restrict__ vb,
    const float* __restrict__ betab, const float* __restrict__ gbuf,
    const float* __restrict__ wbuf, float* __restrict__ U0buf,
    float* __restrict__ Wbuf, float* __restrict__ cbuf) {
  const int ch = blockIdx.x, eb = blockIdx.y, hh = blockIdx.z;
  const int e = eb >> 2, b = eb & 3;
  const int chunkid = (eb * NHEADS + hh) * NCHUNK + ch;
  const int tid = threadIdx.x;
  const int wave = tid >> 6, lane = tid & 63;
  const int quad = lane >> 4, l16 = lane & 15;

  __shared__ __align__(16) short Kb[64 * BST];
  __shared__ float Tm[64][68];
  __shared__ float cc[64], bb[64], exs[64];

  if (tid < 64) {
    const int gt = b * SEQ + ch * 64 + tid;
    const float w = wbuf[gt * NEXP + e];
    float gv = 0.f, bv = 0.f;
    if (w > 0.f) { gv = gbuf[gt * NHEADS + hh]; bv = betab[gt * NHEADS + hh]; }
    float cum = gv;
#pragma unroll
    for (int off = 1; off < 64; off <<= 1) {
      float o = __shfl_up(cum, off);
      if (tid >= off) cum += o;
    }
    cc[tid] = cum; exs[tid] = expf(cum); bb[tid] = bv;
    cbuf[(size_t)chunkid * 64 + tid] = cum;
  }
  {
    const int t = tid >> 2, d0 = (tid & 3) * 16;
    const float* krow = kb + (size_t)(b * SEQ + ch * 64 + t) * DMODEL + hh * 64 + d0;
#pragma unroll
    for (int j = 0; j < 4; ++j)
      *(ushort4*)&Kb[t * BST + d0 + j * 4] = f2b4(*(const float4*)(krow + j * 4));
  }
  __syncthreads();
  // lower-triangular bands of K K^T
  for (int ni = 0; ni <= wave; ++ni) {
    f32x4 acc = (f32x4){0.f, 0.f, 0.f, 0.f};
#pragma unroll
    for (int ks = 0; ks < 2; ++ks) {
      bf16x8 af = *(const bf16x8*)&Kb[(wave * 16 + l16) * BST + ks * 32 + quad * 8];
      bf16x8 bfr = *(const bf16x8*)&Kb[(ni * 16 + l16) * BST + ks * 32 + quad * 8];
      acc = __builtin_amdgcn_mfma_f32_16x16x32_bf16(af, bfr, acc, 0, 0, 0);
    }
#pragma unroll
    for (int r = 0; r < 4; ++r) {
      const int t = wave * 16 + quad * 4 + r, s = ni * 16 + l16;
      if (s < t) Tm[t][s] = bb[t] * expf(cc[t] - cc[s]) * acc[r];
    }
  }
  __syncthreads();
  // forward substitution: thread = column; waves 0/1 only
  if (tid < 128) {
    const int col = tid & 63;
    const bool isV = tid < 64;
    const float* src = isV ? vb : kb;
    float R[64];
#pragma unroll
    for (int t = 0; t < 64; ++t)
      R[t] = src[(size_t)(b * SEQ + ch * 64 + t) * DMODEL + hh * 64 + col];
    float u[64];
#pragma unroll
    for (int t = 0; t < 64; ++t) {
      const float sc = isV ? bb[t] : bb[t] * exs[t];
      float v0 = sc * R[t], v1 = 0.f;
#pragma unroll
      for (int r = 0; r < t; ++r) {
        if (r & 1) v1 = fmaf(-Tm[t][r], u[r], v1);
        else       v0 = fmaf(-Tm[t][r], u[r], v0);
      }
      u[t] = v0 + v1;
    }
    float* dst = (isV ? U0buf : Wbuf) + (size_t)chunkid * 4096 + col;
#pragma unroll
    for (int t = 0; t < 64; ++t) dst[(size_t)t * 64] = u[t];
  }
}

// ---- phase 2: serial chunk chain per (eb, h). MFMA GEMMs, fp32 state ----
__global__ __launch_bounds__(256) void chunk_phase2(
    const float* __restrict__ kb, const float* __restrict__ cbuf,
    const float* __restrict__ U0buf, const float* __restrict__ Wbuf,
    u16* __restrict__ Utg, u16* __restrict__ Stg) {
  const int eb = blockIdx.x, hh = blockIdx.y;
  const int b = eb & 3;
  const int ebh = eb * NHEADS + hh;
  const int tid = threadIdx.x;
  const int wave = tid >> 6, lane = tid & 63;
  const int quad = lane >> 4, l16 = lane & 15;

  __shared__ float S[64][68];                 // persistent fp32 state [dk][dv]
  __shared__ __align__(16) short Sbt[64 * BST];   // bf16 S^T [dv][dk]
  __shared__ __align__(16) short Wb[64 * BST];    // bf16 W [t][dk]
  __shared__ __align__(16) short Kptb[64 * BST];  // bf16 K^T [dk][t]
  __shared__ __align__(16) short Utb[64 * BST];   // bf16 U^T [dv][t]
  __shared__ __align__(16) short Uextb[64 * BST]; // bf16 (U*ext)^T [dv][t]
  __shared__ float ext[64];
  __shared__ float gamS;

  for (int i = tid; i < 64 * 68; i += 256) (&S[0][0])[i] = 0.f;
  __syncthreads();

  for (int ch = 0; ch < NCHUNK; ++ch) {
    const int chunkid = ebh * NCHUNK + ch;
    const size_t base = (size_t)chunkid * 4096;
    if (tid < 64) {
      const float cv = cbuf[(size_t)chunkid * 64 + tid];
      const float c63 = __shfl(cv, 63);
      ext[tid] = expf(c63 - cv);
      if (tid == 63) gamS = expf(cv);
    }
    {  // stage W rows bf16 (no deps)
      const int t = tid >> 2, d0 = (tid & 3) * 16;
      const float* wrow = Wbuf + base + (size_t)t * 64 + d0;
#pragma unroll
      for (int j = 0; j < 4; ++j)
        *(ushort4*)&Wb[t * BST + d0 + j * 4] = f2b4(*(const float4*)(wrow + j * 4));
    }
    __syncthreads();
    // S^T cast (snapshot of chunk-start S) + K^T cast
    for (int i = tid; i < 4096; i += 256) {
      const int r = i >> 6, col = i & 63;
      Sbt[col * BST + r] = f2b(S[r][col]);
    }
    {
      const int t = tid >> 2, d0 = (tid & 3) * 16;
      const float* krow = kb + (size_t)(b * SEQ + ch * 64 + t) * DMODEL + hh * 64 + d0;
#pragma unroll
      for (int j = 0; j < 16; ++j) Kptb[(d0 + j) * BST + t] = f2b(krow[j]);
    }
    __syncthreads();
    // GEMM1: U = U0 - W * S0 ; build U^T and (U*ext)^T
    for (int ni = 0; ni < 4; ++ni) {
      f32x4 acc = (f32x4){0.f, 0.f, 0.f, 0.f};
#pragma unroll
      for (int ks = 0; ks < 2; ++ks) {
        bf16x8 af = *(const bf16x8*)&Wb[(wave * 16 + l16) * BST + ks * 32 + quad * 8];
        bf16x8 bfr = *(const bf16x8*)&Sbt[(ni * 16 + l16) * BST + ks * 32 + quad * 8];
        acc = __builtin_amdgcn_mfma_f32_16x16x32_bf16(af, bfr, acc, 0, 0, 0);
      }
#pragma unroll
      for (int r = 0; r < 4; ++r) {
        const int t = wave * 16 + quad * 4 + r, dv = ni * 16 + l16;
        const float uv = U0buf[base + (size_t)t * 64 + dv] - acc[r];
        Utb[dv * BST + t] = f2b(uv);
        Uextb[dv * BST + t] = f2b(uv * ext[t]);
      }
    }
    __syncthreads();
    // coalesced copy-out of S^T and U^T snapshots (bf16)
    for (int i = tid; i < 1024; i += 256) {
      const int r = i >> 4, c4 = (i & 15) * 4;
      *(ushort4*)(Stg + base + r * 64 + c4) = *(const ushort4*)&Sbt[r * BST + c4];
      *(ushort4*)(Utg + base + r * 64 + c4) = *(const ushort4*)&Utb[r * BST + c4];
    }
    // GEMM2: S = gam*S + K^T (U*ext)
    for (int ni = 0; ni < 4; ++ni) {
      f32x4 acc = (f32x4){0.f, 0.f, 0.f, 0.f};
#pragma unroll
      for (int ks = 0; ks < 2; ++ks) {
        bf16x8 af = *(const bf16x8*)&Kptb[(wave * 16 + l16) * BST + ks * 32 + quad * 8];
        bf16x8 bfr = *(const bf16x8*)&Uextb[(ni * 16 + l16) * BST + ks * 32 + quad * 8];
        acc = __builtin_amdgcn_mfma_f32_16x16x32_bf16(af, bfr, acc, 0, 0, 0);
      }
      const float g = gamS;
#pragma unroll
      for (int r = 0; r < 4; ++r) {
        const int dk = wave * 16 + quad * 4 + r, dv = ni * 16 + l16;
        S[dk][dv] = g * S[dk][dv] + acc[r];
      }
    }
    __syncthreads();
  }
}

// ---- phase 3: parallel (chunk, eb, h). P = QK^T; O = e^c QS + P U; combine ----
__global__ __launch_bounds__(256) void chunk_phase3(
    const float* __restrict__ qb, const float* __restrict__ kb,
    const float* __restrict__ cbuf, const u16* __restrict__ Utg,
    const u16* __restrict__ Stg, const float* __restrict__ wbuf,
    float* __restrict__ coreb) {
  const int ch = blockIdx.x, eb = blockIdx.y, hh = blockIdx.z;
  const int e = eb >> 2, b = eb & 3;
  const int chunkid = (eb * NHEADS + hh) * NCHUNK + ch;
  const size_t base = (size_t)chunkid * 4096;
  const int tid = threadIdx.x;
  const int wave = tid >> 6, lane = tid & 63;
  const int quad = lane >> 4, l16 = lane & 15;

  __shared__ __align__(16) short Qb[64 * BST];
  __shared__ __align__(16) short Kb3[64 * BST];
  __shared__ __align__(16) short Pb[64 * BST];
  __shared__ __align__(16) short Stb[64 * BST];
  __shared__ __align__(16) short Utb[64 * BST];
  __shared__ float cc3[64];

  if (tid < 64) cc3[tid] = cbuf[(size_t)chunkid * 64 + tid];
  {
    const int t = tid >> 2, d0 = (tid & 3) * 16;
    const size_t ro = (size_t)(b * SEQ + ch * 64 + t) * DMODEL + hh * 64 + d0;
#pragma unroll
    for (int j = 0; j < 4; ++j) {
      *(ushort4*)&Qb[t * BST + d0 + j * 4] = f2b4(*(const float4*)(qb + ro + j * 4));
      *(ushort4*)&Kb3[t * BST + d0 + j * 4] = f2b4(*(const float4*)(kb + ro + j * 4));
    }
  }
  for (int i = tid; i < 1024; i += 256) {
    const int r = i >> 4, c4 = (i & 15) * 4;
    *(ushort4*)&Stb[r * BST + c4] = *(const ushort4*)(Stg + base + r * 64 + c4);
    *(ushort4*)&Utb[r * BST + c4] = *(const ushort4*)(Utg + base + r * 64 + c4);
  }
  __syncthreads();
  // P~[t][s] = (s<=t) e^{c_t-c_s} (q_t.k_s)
  for (int ni = 0; ni < 4; ++ni) {
    f32x4 acc = (f32x4){0.f, 0.f, 0.f, 0.f};
#pragma unroll
    for (int ks = 0; ks < 2; ++ks) {
      bf16x8 af = *(const bf16x8*)&Qb[(wave * 16 + l16) * BST + ks * 32 + quad * 8];
      bf16x8 bfr = *(const bf16x8*)&Kb3[(ni * 16 + l16) * BST + ks * 32 + quad * 8];
      acc = __builtin_amdgcn_mfma_f32_16x16x32_bf16(af, bfr, acc, 0, 0, 0);
    }
#pragma unroll
    for (int r = 0; r < 4; ++r) {
      const int t = wave * 16 + quad * 4 + r, s = ni * 16 + l16;
      const float p = (s <= t) ? expf(cc3[t] - cc3[s]) * acc[r] : 0.f;
      Pb[t * BST + s] = f2b(p);
    }
  }
  __syncthreads();
  // O = 0.125 * (e^{c_t} Q S0 + P~ U)
  for (int ni = 0; ni < 4; ++ni) {
    f32x4 a1 = (f32x4){0.f, 0.f, 0.f, 0.f};
    f32x4 a2 = (f32x4){0.f, 0.f, 0.f, 0.f};
#pragma unroll
    for (int ks = 0; ks < 2; ++ks) {
      bf16x8 afq = *(const bf16x8*)&Qb[(wave * 16 + l16) * BST + ks * 32 + quad * 8];
      bf16x8 bfs = *(const bf16x8*)&Stb[(ni * 16 + l16) * BST + ks * 32 + quad * 8];
      a1 = __builtin_amdgcn_mfma_f32_16x16x32_bf16(afq, bfs, a1, 0, 0, 0);
      bf16x8 afp = *(const bf16x8*)&Pb[(wave * 16 + l16) * BST + ks * 32 + quad * 8];
      bf16x8 bfu = *(const bf16x8*)&Utb[(ni * 16 + l16) * BST + ks * 32 + quad * 8];
      a2 = __builtin_amdgcn_mfma_f32_16x16x32_bf16(afp, bfu, a2, 0, 0, 0);
    }
#pragma unroll
    for (int r = 0; r < 4; ++r) {
      const int t = wave * 16 + quad * 4 + r, dv = ni * 16 + l16;
      const int gt = b * SEQ + ch * 64 + t;
      const float wv = wbuf[gt * NEXP + e];
      if (wv > 0.f) {
        const float o = 0.125f * (expf(cc3[t]) * a1[r] + a2[r]);
        atomicAdd(&coreb[(size_t)gt * DMODEL + hh * 64 + dv], wv * o);
      }
    }
  }
}

// ---------------- fallback serial scan (R3-proven) ----------------
__global__ __launch_bounds__(64) void scan_kernel(
    const float* __restrict__ qb, const float* __restrict__ kb,
    const float* __restrict__ vb, const float* __restrict__ betab,
    const float* __restrict__ gbuf, const float* __restrict__ wbuf,
    const int* __restrict__ tidx, const int* __restrict__ tcnt,
    float* __restrict__ coreb) {
  const int vhalf = blockIdx.x & 1, e = blockIdx.x >> 1;
  const int b = blockIdx.y, hh = blockIdx.z;
  const int lane = threadIdx.x;
  const int kh = lane >> 5;
  const int vi = lane & 31;
  const int cv = vhalf * 32 + vi;
  const int* idx = tidx + (e * BATCH + b) * SEQ;
  const int n = tcnt[e * BATCH + b];
  if (n == 0) return;
  const int nm1 = n - 1;
  __shared__ __align__(16) float lk[4][64];
  __shared__ __align__(16) float lq[4][64];
  __shared__ int lidx[SEQ];
  for (int i = lane; i < SEQ; i += 64) lidx[i] = idx[i < n ? i : nm1];
  __syncthreads();
  v2f S2[16];
#pragma unroll
  for (int j = 0; j < 16; ++j) S2[j] = (v2f){0.f, 0.f};
  float kf[4], qf[4], vf[4], gf[4], bf[4], wf[4], egr[4];
  int tcur[4], tok4[4];
#define PREF(SLOT, TK)                                          \
  do {                                                          \
    const int tn_ = b * SEQ + (TK);                             \
    const size_t kq_ = (size_t)tn_ * DMODEL + hh * 64 + lane;   \
    kf[SLOT] = kb[kq_];                                         \
    qf[SLOT] = qb[kq_];                                         \
    vf[SLOT] = vb[(size_t)tn_ * DMODEL + hh * 64 + cv];         \
    gf[SLOT] = gbuf[tn_ * NHEADS + hh];                         \
    bf[SLOT] = betab[tn_ * NHEADS + hh];                        \
    wf[SLOT] = wbuf[tn_ * NEXP + e];                            \
    tcur[SLOT] = tn_;                                           \
  } while (0)
  tok4[0] = lidx[0];
  tok4[1] = lidx[1 < n ? 1 : nm1];
  tok4[2] = lidx[2 < n ? 2 : nm1];
  tok4[3] = lidx[3 < n ? 3 : nm1];
  PREF(0, tok4[0]); PREF(1, tok4[1]); PREF(2, tok4[2]);
  lk[0][lane] = kf[0]; lq[0][lane] = qf[0];
  egr[0] = expf(gf[0]);
  const int m = (n + 3) & ~3;
  for (int i = 0; i < m; i += 4) {
#pragma unroll
    for (int u = 0; u < 4; ++u) {
      const int s = i + u;
      const int sN = (u + 3) & 3;
      const int s1 = (u + 1) & 3;
      PREF(sN, tok4[sN]);
      int a4 = s + 4;
      a4 = a4 < nm1 ? a4 : nm1;
      tok4[u] = lidx[a4];
      __builtin_amdgcn_wave_barrier();
      lk[s1][lane] = kf[s1];
      lq[s1][lane] = qf[s1];
      __builtin_amdgcn_wave_barrier();
      egr[s1] = expf(gf[s1]);
      const v4f* lk4 = (const v4f*)&lk[u][kh * 32];
      const v4f* lq4 = (const v4f*)&lq[u][kh * 32];
      v2f myk[16];
      v2f c0 = (v2f){0.f, 0.f}, c1 = c0, c2 = c0, c3 = c0;
#pragma unroll
      for (int j = 0; j < 8; ++j) {
        const v4f k4 = lk4[j];
        const v2f klo = (v2f){k4.x, k4.y};
        const v2f khi = (v2f){k4.z, k4.w};
        myk[2 * j] = klo; myk[2 * j + 1] = khi;
        if (j & 1) {
          c2 = __builtin_elementwise_fma(klo, S2[2 * j], c2);
          c3 = __builtin_elementwise_fma(khi, S2[2 * j + 1], c3);
        } else {
          c0 = __builtin_elementwise_fma(klo, S2[2 * j], c0);
          c1 = __builtin_elementwise_fma(khi, S2[2 * j + 1], c1);
        }
      }
      const v2f cacc = (c0 + c1) + (c2 + c3);
      float cd = cacc.x + cacc.y;
      cd += __shfl_xor(cd, 32);
      const float egc = egr[u];
      const float delta = (vf[u] - egc * cd) * bf[u];
      const v2f d2 = (v2f){delta, delta};
      const v2f eg2 = (v2f){egc, egc};
      v2f o0 = (v2f){0.f, 0.f}, o1 = o0, o2 = o0, o3 = o0;
#pragma unroll
      for (int j = 0; j < 8; ++j) {
        const v4f q4 = lq4[j];
        const v2f qlo = (v2f){q4.x, q4.y};
        const v2f qhi = (v2f){q4.z, q4.w};
        const v2f s0 = __builtin_elementwise_fma(S2[2 * j], eg2, myk[2 * j] * d2);
        const v2f s1v = __builtin_elementwise_fma(S2[2 * j + 1], eg2, myk[2 * j + 1] * d2);
        S2[2 * j] = s0; S2[2 * j + 1] = s1v;
        if (j & 1) {
          o2 = __builtin_elementwise_fma(qlo, s0, o2);
          o3 = __builtin_elementwise_fma(qhi, s1v, o3);
        } else {
          o0 = __builtin_elementwise_fma(qlo, s0, o0);
          o1 = __builtin_elementwise_fma(qhi, s1v, o1);
        }
      }
      const v2f oacc = (o0 + o1) + (o2 + o3);
      float o = oacc.x + oacc.y;
      o += __shfl_xor(o, 32);
      if (kh == 0 && s < n)
        atomicAdd(&coreb[(size_t)tcur[u] * DMODEL + hh * 64 + cv],
                  o * 0.125f * wf[u]);
    }
  }
#undef PREF
}

// ---------------- fused gated RMSNorm -> bf16 ----------------
__global__ __launch_bounds__(512) void rmsnorm_kernel(
    const float* __restrict__ coreb, const float* __restrict__ gateb,
    const float* __restrict__ wn, u16* __restrict__ outb) {
  const int t = blockIdx.x;
  const int tid = threadIdx.x;
  const int v = tid & 63;
  const float x = coreb[(size_t)t * DMODEL + tid];
  float ss = x * x;
#pragma unroll
  for (int off = 1; off < 64; off <<= 1) ss += __shfl_xor(ss, off);
  const float r = rsqrtf(ss * (1.0f / 64.0f) + 1e-5f);
  const float gt = gateb[(size_t)t * DMODEL + tid];
  outb[(size_t)t * DMODEL + tid] = f2b(x * r * wn[v] * gt);
}

extern "C" void kernel_launch(void* const* d_in, const int* in_sizes, int n_in,
                              void* d_out, int out_size, void* d_ws, size_t ws_size,
                              hipStream_t stream) {
  const float* h       = (const float*)d_in[0];
  const float* Wq      = (const float*)d_in[1];
  const float* Wgate   = (const float*)d_in[2];
  const float* Wk      = (const float*)d_in[3];
  const float* Wv      = (const float*)d_in[4];
  const float* Wb      = (const float*)d_in[5];
  const float* Wa      = (const float*)d_in[6];
  const float* A_log   = (const float*)d_in[7];
  const float* dt_bias = (const float*)d_in[8];
  const float* Wg      = (const float*)d_in[9];
  const float* wn      = (const float*)d_in[10];
  const float* Wo      = (const float*)d_in[11];
  float* out = (float*)d_out;

  char* p = (char*)d_ws;
  const size_t big = (size_t)NTOK * DMODEL;  // 2M elements
  auto alloc = [&](size_t bytes) { char* r = p; p += (bytes + 255) & ~255ull; return r; };
  float* qb    = (float*)alloc(big * 4);
  float* kb    = (float*)alloc(big * 4);
  float* vb    = (float*)alloc(big * 4);
  float* gateb = (float*)alloc(big * 4);
  float* coreb = (float*)alloc(big * 4);
  float* betab = (float*)alloc((size_t)NTOK * NHEADS * 4);
  float* gbuf  = (float*)alloc((size_t)NTOK * NHEADS * 4);
  float* wbuf  = (float*)alloc((size_t)NTOK * NEXP * 4);
  int*   tidx  = (int*)alloc((size_t)NEXP * BATCH * SEQ * 4);
  int*   tcnt  = (int*)alloc(256);
  u16*   hb    = (u16*)alloc(big * 2);
  u16*   nb    = (u16*)alloc(big * 2);
  u16*   wtq   = (u16*)alloc((size_t)DMODEL * DMODEL * 2);
  u16*   wtk   = (u16*)alloc((size_t)DMODEL * DMODEL * 2);
  u16*   wtv   = (u16*)alloc((size_t)DMODEL * DMODEL * 2);
  u16*   wtg   = (u16*)alloc((size_t)DMODEL * DMODEL * 2);
  u16*   wto   = (u16*)alloc((size_t)DMODEL * DMODEL * 2);
  // chunked-path extras
  const size_t nchunks = (size_t)NEXP * BATCH * NHEADS * NCHUNK;  // 2048
  float* U0buf = (float*)alloc(nchunks * 4096 * 4);
  float* Wbuf_ = (float*)alloc(nchunks * 4096 * 4);
  u16*   Utg   = (u16*)alloc(nchunks * 4096 * 2);
  u16*   Stg   = (u16*)alloc(nchunks * 4096 * 2);
  float* cbuf  = (float*)alloc(nchunks * 64 * 4);
  const size_t need = (size_t)(p - (char*)d_ws);
  const bool use_chunked = (ws_size >= need);

  zero_kernel<<<dim3(NTOK * DMODEL / 4 / 256), 256, 0, stream>>>((float4*)coreb);

  cast_h_kernel<<<dim3(big / 4 / 256), 256, 0, stream>>>((const float4*)h, (ushort4*)hb);
  dim3 tg(16, 16);
  castT_kernel<<<tg, 256, 0, stream>>>(Wq, wtq);
  castT_kernel<<<tg, 256, 0, stream>>>(Wk, wtk);
  castT_kernel<<<tg, 256, 0, stream>>>(Wv, wtv);
  castT_kernel<<<tg, 256, 0, stream>>>(Wg, wtg);
  castT_kernel<<<tg, 256, 0, stream>>>(Wo, wto);

  router_kernel<<<dim3(NTOK), 64, 0, stream>>>(h, Wb, Wa, Wgate, A_log, dt_bias,
                                               betab, gbuf, wbuf);

  dim3 gg(NTOK / 128, DMODEL / 64);
  gemm_mfma<2><<<gg, 128, 0, stream>>>(hb, wtq, qb);
  gemm_mfma<2><<<gg, 128, 0, stream>>>(hb, wtk, kb);
  gemm_mfma<1><<<gg, 128, 0, stream>>>(hb, wtv, vb);
  gemm_mfma<1><<<gg, 128, 0, stream>>>(hb, wtg, gateb);

  if (use_chunked) {
    chunk_phase1<<<dim3(NCHUNK, NEXP * BATCH, NHEADS), 256, 0, stream>>>(
        kb, vb, betab, gbuf, wbuf, U0buf, Wbuf_, cbuf);
    chunk_phase2<<<dim3(NEXP * BATCH, NHEADS), 256, 0, stream>>>(
        kb, cbuf, U0buf, Wbuf_, Utg, Stg);
    chunk_phase3<<<dim3(NCHUNK, NEXP * BATCH, NHEADS), 256, 0, stream>>>(
        qb, kb, cbuf, Utg, Stg, wbuf, coreb);
  } else {
    compact_kernel<<<dim3(NEXP, BATCH), 64, 0, stream>>>(wbuf, tidx, tcnt);
    scan_kernel<<<dim3(NEXP * 2, BATCH, NHEADS), 64, 0, stream>>>(
        qb, kb, vb, betab, gbuf, wbuf, tidx, tcnt, coreb);
  }

  rmsnorm_kernel<<<dim3(NTOK), 512, 0, stream>>>(coreb, gateb, wn, nb);

  gemm_mfma<0><<<gg, 128, 0, stream>>>(nb, wto, out);
}

// Round 8
// 328.765 us; speedup vs baseline: 10.1899x; 1.0203x over previous
//
#include <hip/hip_runtime.h>
#include <math.h>

#define DMODEL 512
#define NHEADS 8
#define NEXP 4
#define SEQ 1024
#define BATCH 4
#define NTOK 4096  // BATCH * SEQ
#define NCHUNK 16  // SEQ / 64

typedef float v2f __attribute__((ext_vector_type(2)));
typedef float v4f __attribute__((ext_vector_type(4)));
typedef short bf16x8 __attribute__((ext_vector_type(8)));
typedef float f32x4 __attribute__((ext_vector_type(4)));
typedef unsigned short u16;

__device__ __forceinline__ float dev_sigmoid(float x) { return 1.0f / (1.0f + expf(-x)); }
__device__ __forceinline__ float dev_silu(float x) { return x / (1.0f + expf(-x)); }
__device__ __forceinline__ float dev_softplus(float x) {
  return x > 0.0f ? x + log1pf(expf(-x)) : log1pf(expf(x));
}
// fp32 -> bf16 bits, round-to-nearest-even
__device__ __forceinline__ u16 f2b(float f) {
  unsigned int u = __float_as_uint(f);
  unsigned int r = (u + 0x7fffu + ((u >> 16) & 1u)) >> 16;
  return (u16)r;
}
__device__ __forceinline__ ushort4 f2b4(float4 v) {
  ushort4 o; o.x = f2b(v.x); o.y = f2b(v.y); o.z = f2b(v.z); o.w = f2b(v.w); return o;
}

// bf16 LDS row stride in shorts: 72 (144 B) -> 16B-aligned fragments
#define BST 72

// ---------------- zero kernel ----------------
__global__ __launch_bounds__(256) void zero_kernel(float4* __restrict__ p) {
  p[(size_t)blockIdx.x * 256 + threadIdx.x] = make_float4(0.f, 0.f, 0.f, 0.f);
}

// ---------------- cast h (fp32) -> bf16 bits ----------------
__global__ __launch_bounds__(256) void cast_h_kernel(const float4* __restrict__ in,
                                                     ushort4* __restrict__ outp) {
  const size_t i = (size_t)blockIdx.x * 256 + threadIdx.x;
  outp[i] = f2b4(in[i]);
}

// ---------------- transpose-cast weight: W[512][512] fp32 -> Wt[n][k] bf16 -------------
__global__ __launch_bounds__(256) void castT_kernel(const float* __restrict__ in,
                                                    u16* __restrict__ outp) {
  __shared__ float tile[32][33];
  const int bx = blockIdx.x * 32;  // k base
  const int by = blockIdx.y * 32;  // n base
  const int c = threadIdx.x & 31, r0 = threadIdx.x >> 5;
#pragma unroll
  for (int r = r0; r < 32; r += 8) tile[r][c] = in[(size_t)(bx + r) * DMODEL + by + c];
  __syncthreads();
#pragma unroll
  for (int r = r0; r < 32; r += 8)
    outp[(size_t)(by + r) * DMODEL + bx + c] = f2b(tile[c][r]);
}

// ---------------- per-(b,h,chunk) K^T bf16 tiles: ktg[tile][dk][t] ----------------
__global__ __launch_bounds__(256) void kT_kernel(const float* __restrict__ kb,
                                                 u16* __restrict__ ktg) {
  const int ch = blockIdx.x, b = blockIdx.y, hh = blockIdx.z;
  const int tile = (b * NHEADS + hh) * NCHUNK + ch;
  const int tid = threadIdx.x;
  __shared__ float tl[64][65];
  {
    const int t = tid >> 2, d0 = (tid & 3) * 16;
    const float* krow = kb + (size_t)(b * SEQ + ch * 64 + t) * DMODEL + hh * 64 + d0;
#pragma unroll
    for (int j = 0; j < 4; ++j) {
      float4 v = *(const float4*)(krow + j * 4);
      tl[t][d0 + j * 4 + 0] = v.x; tl[t][d0 + j * 4 + 1] = v.y;
      tl[t][d0 + j * 4 + 2] = v.z; tl[t][d0 + j * 4 + 3] = v.w;
    }
  }
  __syncthreads();
  {
    const int t = tid & 63, dk0 = (tid >> 6) * 16;
    u16* obase = ktg + (size_t)tile * 4096 + t;
#pragma unroll
    for (int j = 0; j < 16; ++j)
      obase[(size_t)(dk0 + j) * 64] = f2b(tl[t][dk0 + j]);
  }
}

// ---------------- router + beta/g small projections: one wave per token ----------------
__global__ __launch_bounds__(64) void router_kernel(
    const float* __restrict__ h, const float* __restrict__ Wb,
    const float* __restrict__ Wa, const float* __restrict__ Wgate,
    const float* __restrict__ A_log, const float* __restrict__ dt_bias,
    float* __restrict__ beta_o, float* __restrict__ g_o, float* __restrict__ w_o) {
  const int t = blockIdx.x;
  const int lane = threadIdx.x;
  float hv[8];
#pragma unroll
  for (int j = 0; j < 8; ++j) hv[j] = h[(size_t)t * DMODEL + j * 64 + lane];
  float db[8], da[8], dg[4];
#pragma unroll
  for (int c = 0; c < 8; ++c) {
    float s1 = 0.f, s2 = 0.f;
#pragma unroll
    for (int j = 0; j < 8; ++j) {
      int row = j * 64 + lane;
      s1 += hv[j] * Wb[row * NHEADS + c];
      s2 += hv[j] * Wa[row * NHEADS + c];
    }
#pragma unroll
    for (int off = 1; off < 64; off <<= 1) {
      s1 += __shfl_xor(s1, off);
      s2 += __shfl_xor(s2, off);
    }
    db[c] = s1; da[c] = s2;
  }
#pragma unroll
  for (int c = 0; c < 4; ++c) {
    float s = 0.f;
#pragma unroll
    for (int j = 0; j < 8; ++j) s += hv[j] * Wgate[(j * 64 + lane) * NEXP + c];
#pragma unroll
    for (int off = 1; off < 64; off <<= 1) s += __shfl_xor(s, off);
    dg[c] = s;
  }
  if (lane == 0) {
#pragma unroll
    for (int c = 0; c < 8; ++c) {
      beta_o[t * NHEADS + c] = dev_sigmoid(db[c]);
      g_o[t * NHEADS + c] = -expf(A_log[c]) * dev_softplus(da[c] + dt_bias[c]);
    }
    float mx = fmaxf(fmaxf(dg[0], dg[1]), fmaxf(dg[2], dg[3]));
    float p[4]; float sum = 0.f;
#pragma unroll
    for (int c = 0; c < 4; ++c) { p[c] = expf(dg[c] - mx); sum += p[c]; }
#pragma unroll
    for (int c = 0; c < 4; ++c) p[c] /= sum;
    float v1 = -1e30f; int i1 = 0;
#pragma unroll
    for (int c = 0; c < 4; ++c) { if (p[c] > v1) { v1 = p[c]; i1 = c; } }
    float v2 = -1e30f; int i2 = -1;
#pragma unroll
    for (int c = 0; c < 4; ++c) { if (c != i1 && p[c] > v2) { v2 = p[c]; i2 = c; } }
    float s2v = v1 + v2;
#pragma unroll
    for (int c = 0; c < 4; ++c) {
      float wv = 0.f;
      if (c == i1) wv = v1 / s2v;
      else if (c == i2) wv = v2 / s2v;
      w_o[t * NEXP + c] = wv;
    }
  }
}

// ---------------- routed-token compaction (fallback path) ----------------
__global__ __launch_bounds__(64) void compact_kernel(
    const float* __restrict__ wbuf, int* __restrict__ tidx, int* __restrict__ tcnt) {
  const int e = blockIdx.x, b = blockIdx.y;
  const int lane = threadIdx.x;
  int* out = tidx + (e * BATCH + b) * SEQ;
  int cnt = 0;
  for (int g0 = 0; g0 < SEQ; g0 += 64) {
    const int l = g0 + lane;
    const float w = wbuf[(b * SEQ + l) * NEXP + e];
    const unsigned long long m = __ballot(w > 0.f);
    const int pos = __popcll(m & ((1ull << lane) - 1ull));
    if (w > 0.f) out[cnt + pos] = l;
    cnt += __popcll(m);
  }
  if (lane == 0) tcnt[e * BATCH + b] = cnt;
}

// ---------------- bf16 MFMA GEMM (proven R5) ----------------
#define LDA 56
template <int MODE>
__global__ __launch_bounds__(128) void gemm_mfma(
    const u16* __restrict__ A, const u16* __restrict__ Bt,
    float* __restrict__ C) {
  constexpr int K = DMODEL, N = DMODEL;
  __shared__ __align__(16) short As[128 * LDA];
  __shared__ __align__(16) short Bs[64 * LDA];
  const int tid = threadIdx.x;
  const int wave = tid >> 6, lane = tid & 63;
  const int quad = lane >> 4, l16 = lane & 15;
  const int m0 = blockIdx.x * 128, n0 = blockIdx.y * 64;
  const int bn = tid >> 1, bk = (tid & 1) * 16;
  const u16* Abase = A + (size_t)(m0 + tid) * K;
  const u16* Bbase = Bt + (size_t)(n0 + bn) * K + bk;

  f32x4 acc[4][4];
#pragma unroll
  for (int i = 0; i < 4; ++i)
#pragma unroll
    for (int j = 0; j < 4; ++j) acc[i][j] = (f32x4){0.f, 0.f, 0.f, 0.f};

  int4 pa0, pa1, pa2, pa3, pb0, pb1;
  {
    const u16* p = Abase;
    pa0 = *(const int4*)p; pa1 = *(const int4*)(p + 8);
    pa2 = *(const int4*)(p + 16); pa3 = *(const int4*)(p + 24);
    const u16* q = Bbase;
    pb0 = *(const int4*)q; pb1 = *(const int4*)(q + 8);
  }
  for (int kk = 0; kk < K; kk += 32) {
    __syncthreads();
    *(int4*)&As[tid * LDA + 0] = pa0;
    *(int4*)&As[tid * LDA + 8] = pa1;
    *(int4*)&As[tid * LDA + 16] = pa2;
    *(int4*)&As[tid * LDA + 24] = pa3;
    *(int4*)&Bs[bn * LDA + bk] = pb0;
    *(int4*)&Bs[bn * LDA + bk + 8] = pb1;
    __syncthreads();
    if (kk + 32 < K) {
      const u16* p = Abase + kk + 32;
      pa0 = *(const int4*)p; pa1 = *(const int4*)(p + 8);
      pa2 = *(const int4*)(p + 16); pa3 = *(const int4*)(p + 24);
      const u16* q = Bbase + kk + 32;
      pb0 = *(const int4*)q; pb1 = *(const int4*)(q + 8);
    }
    bf16x8 af[4], bfg[4];
#pragma unroll
    for (int mi = 0; mi < 4; ++mi)
      af[mi] = *(const bf16x8*)&As[(wave * 64 + mi * 16 + l16) * LDA + quad * 8];
#pragma unroll
    for (int ni = 0; ni < 4; ++ni)
      bfg[ni] = *(const bf16x8*)&Bs[(ni * 16 + l16) * LDA + quad * 8];
#pragma unroll
    for (int mi = 0; mi < 4; ++mi)
#pragma unroll
      for (int ni = 0; ni < 4; ++ni)
        acc[mi][ni] = __builtin_amdgcn_mfma_f32_16x16x32_bf16(af[mi], bfg[ni],
                                                              acc[mi][ni], 0, 0, 0);
  }
#pragma unroll
  for (int mi = 0; mi < 4; ++mi) {
#pragma unroll
    for (int r = 0; r < 4; ++r) {
      const int row = m0 + wave * 64 + mi * 16 + quad * 4 + r;
      float s[4];
#pragma unroll
      for (int ni = 0; ni < 4; ++ni) {
        float x = acc[mi][ni][r];
        s[ni] = (MODE == 0) ? x : dev_silu(x);
      }
      if (MODE == 2) {
        float ss = s[0] * s[0] + s[1] * s[1] + s[2] * s[2] + s[3] * s[3];
        ss += __shfl_xor(ss, 1);
        ss += __shfl_xor(ss, 2);
        ss += __shfl_xor(ss, 4);
        ss += __shfl_xor(ss, 8);
        const float rn = 1.0f / sqrtf(ss + 1e-6f);
#pragma unroll
        for (int ni = 0; ni < 4; ++ni) s[ni] *= rn;
      }
#pragma unroll
      for (int ni = 0; ni < 4; ++ni)
        C[(size_t)row * N + n0 + ni * 16 + l16] = s[ni];
    }
  }
}

// ================= CHUNKED GATED DELTA RULE (MFMA) =================
// c_t = inclusive masked decay cumsum. T[t][s] = b_t e^{c_t-c_s}(k_t.k_s), s<t.
// (I+T)[U0|W] = [bV | diag(b e^c)K]. Delta = U0 - W S0.
// S' = e^{c63} S0 + sum_s e^{c63-c_s} k_s Delta_s^T.
// o_t = scale(e^{c_t} q_t^T S0 + sum_{s<=t} e^{c_t-c_s}(q_t.k_s) Delta_s).

// ---- phase 1: parallel (chunk, eb, h). KK^T via MFMA; fp32 triangular solve ----
// U0 is stored TRANSPOSED ([dv][t]) for phase2's transpose-free formulation.
__global__ __launch_bounds__(256) void chunk_phase1(
    const float* __restrict__ kb, const float* __restrict__ vb,
    const float* __restrict__ betab, const float* __restrict__ gbuf,
    const float* __restrict__ wbuf, float* __restrict__ U0buf,
    float* __restrict__ Wbuf, float* __restrict__ cbuf) {
  const int ch = blockIdx.x, eb = blockIdx.y, hh = blockIdx.z;
  const int e = eb >> 2, b = eb & 3;
  const int chunkid = (eb * NHEADS + hh) * NCHUNK + ch;
  const int tid = threadIdx.x;
  const int wave = tid >> 6, lane = tid & 63;
  const int quad = lane >> 4, l16 = lane & 15;

  __shared__ __align__(16) short Kb[64 * BST];
  __shared__ float Tm[64][68];
  __shared__ float cc[64], bb[64], exs[64];

  if (tid < 64) {
    const int gt = b * SEQ + ch * 64 + tid;
    const float w = wbuf[gt * NEXP + e];
    float gv = 0.f, bv = 0.f;
    if (w > 0.f) { gv = gbuf[gt * NHEADS + hh]; bv = betab[gt * NHEADS + hh]; }
    float cum = gv;
#pragma unroll
    for (int off = 1; off < 64; off <<= 1) {
      float o = __shfl_up(cum, off);
      if (tid >= off) cum += o;
    }
    cc[tid] = cum; exs[tid] = expf(cum); bb[tid] = bv;
    cbuf[(size_t)chunkid * 64 + tid] = cum;
  }
  {
    const int t = tid >> 2, d0 = (tid & 3) * 16;
    const float* krow = kb + (size_t)(b * SEQ + ch * 64 + t) * DMODEL + hh * 64 + d0;
#pragma unroll
    for (int j = 0; j < 4; ++j)
      *(ushort4*)&Kb[t * BST + d0 + j * 4] = f2b4(*(const float4*)(krow + j * 4));
  }
  __syncthreads();
  // lower-triangular bands of K K^T
  for (int ni = 0; ni <= wave; ++ni) {
    f32x4 acc = (f32x4){0.f, 0.f, 0.f, 0.f};
#pragma unroll
    for (int ks = 0; ks < 2; ++ks) {
      bf16x8 af = *(const bf16x8*)&Kb[(wave * 16 + l16) * BST + ks * 32 + quad * 8];
      bf16x8 bfr = *(const bf16x8*)&Kb[(ni * 16 + l16) * BST + ks * 32 + quad * 8];
      acc = __builtin_amdgcn_mfma_f32_16x16x32_bf16(af, bfr, acc, 0, 0, 0);
    }
#pragma unroll
    for (int r = 0; r < 4; ++r) {
      const int t = wave * 16 + quad * 4 + r, s = ni * 16 + l16;
      if (s < t) Tm[t][s] = bb[t] * expf(cc[t] - cc[s]) * acc[r];
    }
  }
  __syncthreads();
  // forward substitution: thread = column; waves 0/1 only
  if (tid < 128) {
    const int col = tid & 63;
    const bool isV = tid < 64;
    const float* src = isV ? vb : kb;
    float R[64];
#pragma unroll
    for (int t = 0; t < 64; ++t)
      R[t] = src[(size_t)(b * SEQ + ch * 64 + t) * DMODEL + hh * 64 + col];
    float u[64];
#pragma unroll
    for (int t = 0; t < 64; ++t) {
      const float sc = isV ? bb[t] : bb[t] * exs[t];
      float v0 = sc * R[t], v1 = 0.f;
#pragma unroll
      for (int r = 0; r < t; ++r) {
        if (r & 1) v1 = fmaf(-Tm[t][r], u[r], v1);
        else       v0 = fmaf(-Tm[t][r], u[r], v0);
      }
      u[t] = v0 + v1;
    }
    if (isV) {
      // U0^T [dv][t]: contiguous 64-float row per thread
      float* dst = U0buf + (size_t)chunkid * 4096 + (size_t)col * 64;
#pragma unroll
      for (int t = 0; t < 64; ++t) dst[t] = u[t];
    } else {
      // W [t][dk] row-major (natural B-operand layout for phase2)
      float* dst = Wbuf + (size_t)chunkid * 4096 + col;
#pragma unroll
      for (int t = 0; t < 64; ++t) dst[(size_t)t * 64] = u[t];
    }
  }
}

// ---- phase 2: serial chunk chain per (eb, h). Transpose-free S^T formulation ----
// GEMM1': (W*S0)^T[dv][t] = sum_dk S0^T[dv][dk] * W[t][dk]   (A=S^T rows, B=W rows)
// GEMM2': S'^T[dv][dk] = g*S^T + sum_t UextT[dv][t] * K^T[dk][t] (A=UextT, B=K^T rows)
__global__ __launch_bounds__(256) void chunk_phase2(
    const float* __restrict__ cbuf, const float* __restrict__ U0buf,
    const float* __restrict__ Wbuf, const u16* __restrict__ ktg,
    u16* __restrict__ Utg, u16* __restrict__ Stg) {
  const int eb = blockIdx.x, hh = blockIdx.y;
  const int b = eb & 3;
  const int ebh = eb * NHEADS + hh;
  const int tid = threadIdx.x;
  const int wave = tid >> 6, lane = tid & 63;
  const int quad = lane >> 4, l16 = lane & 15;

  __shared__ float Sf[64][68];                    // fp32 S^T [dv][dk]
  __shared__ __align__(16) short Sbt[64 * BST];   // bf16 S^T [dv][dk]
  __shared__ __align__(16) short Wb[64 * BST];    // bf16 W   [t][dk]
  __shared__ __align__(16) short Ktb[64 * BST];   // bf16 K^T [dk][t]
  __shared__ __align__(16) short UextT[64 * BST]; // bf16 (U*ext)^T [dv][t]
  __shared__ float ext[64];
  __shared__ float gamS;

  for (int i = tid; i < 64 * 68; i += 256) (&Sf[0][0])[i] = 0.f;
  __syncthreads();

  const int ktile0 = (b * NHEADS + hh) * NCHUNK;

  for (int ch = 0; ch < NCHUNK; ++ch) {
    const int chunkid = ebh * NCHUNK + ch;
    const size_t base = (size_t)chunkid * 4096;
    const size_t kbase = (size_t)(ktile0 + ch) * 4096;
    if (tid < 64) {
      const float cv = cbuf[(size_t)chunkid * 64 + tid];
      const float c63 = __shfl(cv, 63);
      ext[tid] = expf(c63 - cv);
      if (tid == 63) gamS = expf(cv);
    }
    {  // stage W rows (cast) + K^T rows (copy) — vectorized, conflict-light
      const int r = tid >> 2, c0 = (tid & 3) * 16;
      const float* wrow = Wbuf + base + (size_t)r * 64 + c0;
      const u16* krow = ktg + kbase + (size_t)r * 64 + c0;
#pragma unroll
      for (int j = 0; j < 4; ++j) {
        *(ushort4*)&Wb[r * BST + c0 + j * 4] = f2b4(*(const float4*)(wrow + j * 4));
        *(ushort4*)&Ktb[r * BST + c0 + j * 4] = *(const ushort4*)(krow + j * 4);
      }
    }
    // cast S^T -> bf16 (same orientation: conflict-free)
    for (int i = tid; i < 1024; i += 256) {
      const int dv = i >> 4, d4 = (i & 15) * 4;
      const float* s4 = &Sf[dv][d4];
      ushort4 o; o.x = f2b(s4[0]); o.y = f2b(s4[1]); o.z = f2b(s4[2]); o.w = f2b(s4[3]);
      *(ushort4*)&Sbt[dv * BST + d4] = o;
    }
    __syncthreads();
    // snapshot S0^T bf16 -> global (coalesced)
    for (int i = tid; i < 1024; i += 256) {
      const int r = i >> 4, c4 = (i & 15) * 4;
      *(ushort4*)(Stg + base + r * 64 + c4) = *(const ushort4*)&Sbt[r * BST + c4];
    }
    // GEMM1': C1[dv][t]; U^T = U0^T - C1; store Utg + UextT (lanes along t)
    for (int ni = 0; ni < 4; ++ni) {
      f32x4 acc = (f32x4){0.f, 0.f, 0.f, 0.f};
#pragma unroll
      for (int ks = 0; ks < 2; ++ks) {
        bf16x8 af = *(const bf16x8*)&Sbt[(wave * 16 + l16) * BST + ks * 32 + quad * 8];
        bf16x8 bfr = *(const bf16x8*)&Wb[(ni * 16 + l16) * BST + ks * 32 + quad * 8];
        acc = __builtin_amdgcn_mfma_f32_16x16x32_bf16(af, bfr, acc, 0, 0, 0);
      }
#pragma unroll
      for (int r = 0; r < 4; ++r) {
        const int dv = wave * 16 + quad * 4 + r, t = ni * 16 + l16;
        const float uv = U0buf[base + (size_t)dv * 64 + t] - acc[r];
        Utg[base + (size_t)dv * 64 + t] = f2b(uv);
        UextT[dv * BST + t] = f2b(uv * ext[t]);
      }
    }
    __syncthreads();
    // GEMM2': S^T = g*S^T + UextT * K ; owner-thread fp32 update (conflict-free)
    const float g = gamS;
    for (int ni = 0; ni < 4; ++ni) {
      f32x4 acc = (f32x4){0.f, 0.f, 0.f, 0.f};
#pragma unroll
      for (int ks = 0; ks < 2; ++ks) {
        bf16x8 af = *(const bf16x8*)&UextT[(wave * 16 + l16) * BST + ks * 32 + quad * 8];
        bf16x8 bfr = *(const bf16x8*)&Ktb[(ni * 16 + l16) * BST + ks * 32 + quad * 8];
        acc = __builtin_amdgcn_mfma_f32_16x16x32_bf16(af, bfr, acc, 0, 0, 0);
      }
#pragma unroll
      for (int r = 0; r < 4; ++r) {
        const int dv = wave * 16 + quad * 4 + r, dk = ni * 16 + l16;
        Sf[dv][dk] = g * Sf[dv][dk] + acc[r];
      }
    }
    __syncthreads();
  }
}

// ---- phase 3: parallel (chunk, eb, h). P = QK^T; O = e^c QS + P U; combine ----
__global__ __launch_bounds__(256) void chunk_phase3(
    const float* __restrict__ qb, const float* __restrict__ kb,
    const float* __restrict__ cbuf, const u16* __restrict__ Utg,
    const u16* __restrict__ Stg, const float* __restrict__ wbuf,
    float* __restrict__ coreb) {
  const int ch = blockIdx.x, eb = blockIdx.y, hh = blockIdx.z;
  const int e = eb >> 2, b = eb & 3;
  const int chunkid = (eb * NHEADS + hh) * NCHUNK + ch;
  const size_t base = (size_t)chunkid * 4096;
  const int tid = threadIdx.x;
  const int wave = tid >> 6, lane = tid & 63;
  const int quad = lane >> 4, l16 = lane & 15;

  __shared__ __align__(16) short Qb[64 * BST];
  __shared__ __align__(16) short Kb3[64 * BST];
  __shared__ __align__(16) short Pb[64 * BST];
  __shared__ __align__(16) short Stb[64 * BST];
  __shared__ __align__(16) short Utb[64 * BST];
  __shared__ float cc3[64];

  if (tid < 64) cc3[tid] = cbuf[(size_t)chunkid * 64 + tid];
  {
    const int t = tid >> 2, d0 = (tid & 3) * 16;
    const size_t ro = (size_t)(b * SEQ + ch * 64 + t) * DMODEL + hh * 64 + d0;
#pragma unroll
    for (int j = 0; j < 4; ++j) {
      *(ushort4*)&Qb[t * BST + d0 + j * 4] = f2b4(*(const float4*)(qb + ro + j * 4));
      *(ushort4*)&Kb3[t * BST + d0 + j * 4] = f2b4(*(const float4*)(kb + ro + j * 4));
    }
  }
  for (int i = tid; i < 1024; i += 256) {
    const int r = i >> 4, c4 = (i & 15) * 4;
    *(ushort4*)&Stb[r * BST + c4] = *(const ushort4*)(Stg + base + r * 64 + c4);
    *(ushort4*)&Utb[r * BST + c4] = *(const ushort4*)(Utg + base + r * 64 + c4);
  }
  __syncthreads();
  // P~[t][s] = (s<=t) e^{c_t-c_s} (q_t.k_s)
  for (int ni = 0; ni < 4; ++ni) {
    f32x4 acc = (f32x4){0.f, 0.f, 0.f, 0.f};
#pragma unroll
    for (int ks = 0; ks < 2; ++ks) {
      bf16x8 af = *(const bf16x8*)&Qb[(wave * 16 + l16) * BST + ks * 32 + quad * 8];
      bf16x8 bfr = *(const bf16x8*)&Kb3[(ni * 16 + l16) * BST + ks * 32 + quad * 8];
      acc = __builtin_amdgcn_mfma_f32_16x16x32_bf16(af, bfr, acc, 0, 0, 0);
    }
#pragma unroll
    for (int r = 0; r < 4; ++r) {
      const int t = wave * 16 + quad * 4 + r, s = ni * 16 + l16;
      const float p = (s <= t) ? expf(cc3[t] - cc3[s]) * acc[r] : 0.f;
      Pb[t * BST + s] = f2b(p);
    }
  }
  __syncthreads();
  // O = 0.125 * (e^{c_t} Q S0 + P~ U)
  for (int ni = 0; ni < 4; ++ni) {
    f32x4 a1 = (f32x4){0.f, 0.f, 0.f, 0.f};
    f32x4 a2 = (f32x4){0.f, 0.f, 0.f, 0.f};
#pragma unroll
    for (int ks = 0; ks < 2; ++ks) {
      bf16x8 afq = *(const bf16x8*)&Qb[(wave * 16 + l16) * BST + ks * 32 + quad * 8];
      bf16x8 bfs = *(const bf16x8*)&Stb[(ni * 16 + l16) * BST + ks * 32 + quad * 8];
      a1 = __builtin_amdgcn_mfma_f32_16x16x32_bf16(afq, bfs, a1, 0, 0, 0);
      bf16x8 afp = *(const bf16x8*)&Pb[(wave * 16 + l16) * BST + ks * 32 + quad * 8];
      bf16x8 bfu = *(const bf16x8*)&Utb[(ni * 16 + l16) * BST + ks * 32 + quad * 8];
      a2 = __builtin_amdgcn_mfma_f32_16x16x32_bf16(afp, bfu, a2, 0, 0, 0);
    }
#pragma unroll
    for (int r = 0; r < 4; ++r) {
      const int t = wave * 16 + quad * 4 + r, dv = ni * 16 + l16;
      const int gt = b * SEQ + ch * 64 + t;
      const float wv = wbuf[gt * NEXP + e];
      if (wv > 0.f) {
        const float o = 0.125f * (expf(cc3[t]) * a1[r] + a2[r]);
        atomicAdd(&coreb[(size_t)gt * DMODEL + hh * 64 + dv], wv * o);
      }
    }
  }
}

// ---------------- fallback serial scan (R3-proven) ----------------
__global__ __launch_bounds__(64) void scan_kernel(
    const float* __restrict__ qb, const float* __restrict__ kb,
    const float* __restrict__ vb, const float* __restrict__ betab,
    const float* __restrict__ gbuf, const float* __restrict__ wbuf,
    const int* __restrict__ tidx, const int* __restrict__ tcnt,
    float* __restrict__ coreb) {
  const int vhalf = blockIdx.x & 1, e = blockIdx.x >> 1;
  const int b = blockIdx.y, hh = blockIdx.z;
  const int lane = threadIdx.x;
  const int kh = lane >> 5;
  const int vi = lane & 31;
  const int cv = vhalf * 32 + vi;
  const int* idx = tidx + (e * BATCH + b) * SEQ;
  const int n = tcnt[e * BATCH + b];
  if (n == 0) return;
  const int nm1 = n - 1;
  __shared__ __align__(16) float lk[4][64];
  __shared__ __align__(16) float lq[4][64];
  __shared__ int lidx[SEQ];
  for (int i = lane; i < SEQ; i += 64) lidx[i] = idx[i < n ? i : nm1];
  __syncthreads();
  v2f S2[16];
#pragma unroll
  for (int j = 0; j < 16; ++j) S2[j] = (v2f){0.f, 0.f};
  float kf[4], qf[4], vf[4], gf[4], bf[4], wf[4], egr[4];
  int tcur[4], tok4[4];
#define PREF(SLOT, TK)                                          \
  do {                                                          \
    const int tn_ = b * SEQ + (TK);                             \
    const size_t kq_ = (size_t)tn_ * DMODEL + hh * 64 + lane;   \
    kf[SLOT] = kb[kq_];                                         \
    qf[SLOT] = qb[kq_];                                         \
    vf[SLOT] = vb[(size_t)tn_ * DMODEL + hh * 64 + cv];         \
    gf[SLOT] = gbuf[tn_ * NHEADS + hh];                         \
    bf[SLOT] = betab[tn_ * NHEADS + hh];                        \
    wf[SLOT] = wbuf[tn_ * NEXP + e];                            \
    tcur[SLOT] = tn_;                                           \
  } while (0)
  tok4[0] = lidx[0];
  tok4[1] = lidx[1 < n ? 1 : nm1];
  tok4[2] = lidx[2 < n ? 2 : nm1];
  tok4[3] = lidx[3 < n ? 3 : nm1];
  PREF(0, tok4[0]); PREF(1, tok4[1]); PREF(2, tok4[2]);
  lk[0][lane] = kf[0]; lq[0][lane] = qf[0];
  egr[0] = expf(gf[0]);
  const int m = (n + 3) & ~3;
  for (int i = 0; i < m; i += 4) {
#pragma unroll
    for (int u = 0; u < 4; ++u) {
      const int s = i + u;
      const int sN = (u + 3) & 3;
      const int s1 = (u + 1) & 3;
      PREF(sN, tok4[sN]);
      int a4 = s + 4;
      a4 = a4 < nm1 ? a4 : nm1;
      tok4[u] = lidx[a4];
      __builtin_amdgcn_wave_barrier();
      lk[s1][lane] = kf[s1];
      lq[s1][lane] = qf[s1];
      __builtin_amdgcn_wave_barrier();
      egr[s1] = expf(gf[s1]);
      const v4f* lk4 = (const v4f*)&lk[u][kh * 32];
      const v4f* lq4 = (const v4f*)&lq[u][kh * 32];
      v2f myk[16];
      v2f c0 = (v2f){0.f, 0.f}, c1 = c0, c2 = c0, c3 = c0;
#pragma unroll
      for (int j = 0; j < 8; ++j) {
        const v4f k4 = lk4[j];
        const v2f klo = (v2f){k4.x, k4.y};
        const v2f khi = (v2f){k4.z, k4.w};
        myk[2 * j] = klo; myk[2 * j + 1] = khi;
        if (j & 1) {
          c2 = __builtin_elementwise_fma(klo, S2[2 * j], c2);
          c3 = __builtin_elementwise_fma(khi, S2[2 * j + 1], c3);
        } else {
          c0 = __builtin_elementwise_fma(klo, S2[2 * j], c0);
          c1 = __builtin_elementwise_fma(khi, S2[2 * j + 1], c1);
        }
      }
      const v2f cacc = (c0 + c1) + (c2 + c3);
      float cd = cacc.x + cacc.y;
      cd += __shfl_xor(cd, 32);
      const float egc = egr[u];
      const float delta = (vf[u] - egc * cd) * bf[u];
      const v2f d2 = (v2f){delta, delta};
      const v2f eg2 = (v2f){egc, egc};
      v2f o0 = (v2f){0.f, 0.f}, o1 = o0, o2 = o0, o3 = o0;
#pragma unroll
      for (int j = 0; j < 8; ++j) {
        const v4f q4 = lq4[j];
        const v2f qlo = (v2f){q4.x, q4.y};
        const v2f qhi = (v2f){q4.z, q4.w};
        const v2f s0 = __builtin_elementwise_fma(S2[2 * j], eg2, myk[2 * j] * d2);
        const v2f s1v = __builtin_elementwise_fma(S2[2 * j + 1], eg2, myk[2 * j + 1] * d2);
        S2[2 * j] = s0; S2[2 * j + 1] = s1v;
        if (j & 1) {
          o2 = __builtin_elementwise_fma(qlo, s0, o2);
          o3 = __builtin_elementwise_fma(qhi, s1v, o3);
        } else {
          o0 = __builtin_elementwise_fma(qlo, s0, o0);
          o1 = __builtin_elementwise_fma(qhi, s1v, o1);
        }
      }
      const v2f oacc = (o0 + o1) + (o2 + o3);
      float o = oacc.x + oacc.y;
      o += __shfl_xor(o, 32);
      if (kh == 0 && s < n)
        atomicAdd(&coreb[(size_t)tcur[u] * DMODEL + hh * 64 + cv],
                  o * 0.125f * wf[u]);
    }
  }
#undef PREF
}

// ---------------- fused gated RMSNorm -> bf16 ----------------
__global__ __launch_bounds__(512) void rmsnorm_kernel(
    const float* __restrict__ coreb, const float* __restrict__ gateb,
    const float* __restrict__ wn, u16* __restrict__ outb) {
  const int t = blockIdx.x;
  const int tid = threadIdx.x;
  const int v = tid & 63;
  const float x = coreb[(size_t)t * DMODEL + tid];
  float ss = x * x;
#pragma unroll
  for (int off = 1; off < 64; off <<= 1) ss += __shfl_xor(ss, off);
  const float r = rsqrtf(ss * (1.0f / 64.0f) + 1e-5f);
  const float gt = gateb[(size_t)t * DMODEL + tid];
  outb[(size_t)t * DMODEL + tid] = f2b(x * r * wn[v] * gt);
}

extern "C" void kernel_launch(void* const* d_in, const int* in_sizes, int n_in,
                              void* d_out, int out_size, void* d_ws, size_t ws_size,
                              hipStream_t stream) {
  const float* h       = (const float*)d_in[0];
  const float* Wq      = (const float*)d_in[1];
  const float* Wgate   = (const float*)d_in[2];
  const float* Wk      = (const float*)d_in[3];
  const float* Wv      = (const float*)d_in[4];
  const float* Wb      = (const float*)d_in[5];
  const float* Wa      = (const float*)d_in[6];
  const float* A_log   = (const float*)d_in[7];
  const float* dt_bias = (const float*)d_in[8];
  const float* Wg      = (const float*)d_in[9];
  const float* wn      = (const float*)d_in[10];
  const float* Wo      = (const float*)d_in[11];
  float* out = (float*)d_out;

  char* p = (char*)d_ws;
  const size_t big = (size_t)NTOK * DMODEL;  // 2M elements
  auto alloc = [&](size_t bytes) { char* r = p; p += (bytes + 255) & ~255ull; return r; };
  float* qb    = (float*)alloc(big * 4);
  float* kb    = (float*)alloc(big * 4);
  float* vb    = (float*)alloc(big * 4);
  float* gateb = (float*)alloc(big * 4);
  float* coreb = (float*)alloc(big * 4);
  float* betab = (float*)alloc((size_t)NTOK * NHEADS * 4);
  float* gbuf  = (float*)alloc((size_t)NTOK * NHEADS * 4);
  float* wbuf  = (float*)alloc((size_t)NTOK * NEXP * 4);
  int*   tidx  = (int*)alloc((size_t)NEXP * BATCH * SEQ * 4);
  int*   tcnt  = (int*)alloc(256);
  u16*   hb    = (u16*)alloc(big * 2);
  u16*   nb    = (u16*)alloc(big * 2);
  u16*   wtq   = (u16*)alloc((size_t)DMODEL * DMODEL * 2);
  u16*   wtk   = (u16*)alloc((size_t)DMODEL * DMODEL * 2);
  u16*   wtv   = (u16*)alloc((size_t)DMODEL * DMODEL * 2);
  u16*   wtg   = (u16*)alloc((size_t)DMODEL * DMODEL * 2);
  u16*   wto   = (u16*)alloc((size_t)DMODEL * DMODEL * 2);
  // chunked-path extras
  const size_t nchunks = (size_t)NEXP * BATCH * NHEADS * NCHUNK;  // 2048
  float* U0buf = (float*)alloc(nchunks * 4096 * 4);
  float* Wbuf_ = (float*)alloc(nchunks * 4096 * 4);
  u16*   Utg   = (u16*)alloc(nchunks * 4096 * 2);
  u16*   Stg   = (u16*)alloc(nchunks * 4096 * 2);
  float* cbuf  = (float*)alloc(nchunks * 64 * 4);
  u16*   ktg   = (u16*)alloc((size_t)BATCH * NHEADS * NCHUNK * 4096 * 2);
  const size_t need = (size_t)(p - (char*)d_ws);
  const bool use_chunked = (ws_size >= need);

  zero_kernel<<<dim3(NTOK * DMODEL / 4 / 256), 256, 0, stream>>>((float4*)coreb);

  cast_h_kernel<<<dim3(big / 4 / 256), 256, 0, stream>>>((const float4*)h, (ushort4*)hb);
  dim3 tg(16, 16);
  castT_kernel<<<tg, 256, 0, stream>>>(Wq, wtq);
  castT_kernel<<<tg, 256, 0, stream>>>(Wk, wtk);
  castT_kernel<<<tg, 256, 0, stream>>>(Wv, wtv);
  castT_kernel<<<tg, 256, 0, stream>>>(Wg, wtg);
  castT_kernel<<<tg, 256, 0, stream>>>(Wo, wto);

  router_kernel<<<dim3(NTOK), 64, 0, stream>>>(h, Wb, Wa, Wgate, A_log, dt_bias,
                                               betab, gbuf, wbuf);

  dim3 gg(NTOK / 128, DMODEL / 64);
  gemm_mfma<2><<<gg, 128, 0, stream>>>(hb, wtq, qb);
  gemm_mfma<2><<<gg, 128, 0, stream>>>(hb, wtk, kb);
  gemm_mfma<1><<<gg, 128, 0, stream>>>(hb, wtv, vb);
  gemm_mfma<1><<<gg, 128, 0, stream>>>(hb, wtg, gateb);

  if (use_chunked) {
    kT_kernel<<<dim3(NCHUNK, BATCH, NHEADS), 256, 0, stream>>>(kb, ktg);
    chunk_phase1<<<dim3(NCHUNK, NEXP * BATCH, NHEADS), 256, 0, stream>>>(
        kb, vb, betab, gbuf, wbuf, U0buf, Wbuf_, cbuf);
    chunk_phase2<<<dim3(NEXP * BATCH, NHEADS), 256, 0, stream>>>(
        cbuf, U0buf, Wbuf_, ktg, Utg, Stg);
    chunk_phase3<<<dim3(NCHUNK, NEXP * BATCH, NHEADS), 256, 0, stream>>>(
        qb, kb, cbuf, Utg, Stg, wbuf, coreb);
  } else {
    compact_kernel<<<dim3(NEXP, BATCH), 64, 0, stream>>>(wbuf, tidx, tcnt);
    scan_kernel<<<dim3(NEXP * 2, BATCH, NHEADS), 64, 0, stream>>>(
        qb, kb, vb, betab, gbuf, wbuf, tidx, tcnt, coreb);
  }

  rmsnorm_kernel<<<dim3(NTOK), 512, 0, stream>>>(coreb, gateb, wn, nb);

  gemm_mfma<0><<<gg, 128, 0, stream>>>(nb, wto, out);
}

// Round 10
// 317.519 us; speedup vs baseline: 10.5508x; 1.0354x over previous
//
#include <hip/hip_runtime.h>
#include <math.h>

#define DMODEL 512
#define NHEADS 8
#define NEXP 4
#define SEQ 1024
#define BATCH 4
#define NTOK 4096  // BATCH * SEQ
#define NCHUNK 16  // SEQ / 64

typedef float v2f __attribute__((ext_vector_type(2)));
typedef float v4f __attribute__((ext_vector_type(4)));
typedef short bf16x8 __attribute__((ext_vector_type(8)));
typedef float f32x4 __attribute__((ext_vector_type(4)));
typedef unsigned short u16;

__device__ __forceinline__ float dev_sigmoid(float x) { return 1.0f / (1.0f + expf(-x)); }
__device__ __forceinline__ float dev_silu(float x) { return x / (1.0f + expf(-x)); }
__device__ __forceinline__ float dev_softplus(float x) {
  return x > 0.0f ? x + log1pf(expf(-x)) : log1pf(expf(x));
}
// fp32 -> bf16 bits, round-to-nearest-even
__device__ __forceinline__ u16 f2b(float f) {
  unsigned int u = __float_as_uint(f);
  unsigned int r = (u + 0x7fffu + ((u >> 16) & 1u)) >> 16;
  return (u16)r;
}
__device__ __forceinline__ ushort4 f2b4(float4 v) {
  ushort4 o; o.x = f2b(v.x); o.y = f2b(v.y); o.z = f2b(v.z); o.w = f2b(v.w); return o;
}

// bf16 LDS row stride in shorts: 72 (144 B) -> 16B-aligned fragments
#define BST 72

// ---------------- zero kernel ----------------
__global__ __launch_bounds__(256) void zero_kernel(float4* __restrict__ p) {
  p[(size_t)blockIdx.x * 256 + threadIdx.x] = make_float4(0.f, 0.f, 0.f, 0.f);
}

// ---------------- cast h (fp32) -> bf16 bits ----------------
__global__ __launch_bounds__(256) void cast_h_kernel(const float4* __restrict__ in,
                                                     ushort4* __restrict__ outp) {
  const size_t i = (size_t)blockIdx.x * 256 + threadIdx.x;
  outp[i] = f2b4(in[i]);
}

// ---------------- transpose-cast weight: W[512][512] fp32 -> Wt[n][k] bf16 -------------
__global__ __launch_bounds__(256) void castT_kernel(const float* __restrict__ in,
                                                    u16* __restrict__ outp) {
  __shared__ float tile[32][33];
  const int bx = blockIdx.x * 32;  // k base
  const int by = blockIdx.y * 32;  // n base
  const int c = threadIdx.x & 31, r0 = threadIdx.x >> 5;
#pragma unroll
  for (int r = r0; r < 32; r += 8) tile[r][c] = in[(size_t)(bx + r) * DMODEL + by + c];
  __syncthreads();
#pragma unroll
  for (int r = r0; r < 32; r += 8)
    outp[(size_t)(by + r) * DMODEL + bx + c] = f2b(tile[c][r]);
}

// ---------------- per-(b,h,chunk) K^T bf16 tiles: ktg[tile][dk][t] ----------------
__global__ __launch_bounds__(256) void kT_kernel(const float* __restrict__ kb,
                                                 u16* __restrict__ ktg) {
  const int ch = blockIdx.x, b = blockIdx.y, hh = blockIdx.z;
  const int tile = (b * NHEADS + hh) * NCHUNK + ch;
  const int tid = threadIdx.x;
  __shared__ float tl[64][65];
  {
    const int t = tid >> 2, d0 = (tid & 3) * 16;
    const float* krow = kb + (size_t)(b * SEQ + ch * 64 + t) * DMODEL + hh * 64 + d0;
#pragma unroll
    for (int j = 0; j < 4; ++j) {
      float4 v = *(const float4*)(krow + j * 4);
      tl[t][d0 + j * 4 + 0] = v.x; tl[t][d0 + j * 4 + 1] = v.y;
      tl[t][d0 + j * 4 + 2] = v.z; tl[t][d0 + j * 4 + 3] = v.w;
    }
  }
  __syncthreads();
  {
    const int t = tid & 63, dk0 = (tid >> 6) * 16;
    u16* obase = ktg + (size_t)tile * 4096 + t;
#pragma unroll
    for (int j = 0; j < 16; ++j)
      obase[(size_t)(dk0 + j) * 64] = f2b(tl[t][dk0 + j]);
  }
}

// ---------------- router + beta/g small projections: one wave per token ----------------
__global__ __launch_bounds__(64) void router_kernel(
    const float* __restrict__ h, const float* __restrict__ Wb,
    const float* __restrict__ Wa, const float* __restrict__ Wgate,
    const float* __restrict__ A_log, const float* __restrict__ dt_bias,
    float* __restrict__ beta_o, float* __restrict__ g_o, float* __restrict__ w_o) {
  const int t = blockIdx.x;
  const int lane = threadIdx.x;
  float hv[8];
#pragma unroll
  for (int j = 0; j < 8; ++j) hv[j] = h[(size_t)t * DMODEL + j * 64 + lane];
  float db[8], da[8], dg[4];
#pragma unroll
  for (int c = 0; c < 8; ++c) {
    float s1 = 0.f, s2 = 0.f;
#pragma unroll
    for (int j = 0; j < 8; ++j) {
      int row = j * 64 + lane;
      s1 += hv[j] * Wb[row * NHEADS + c];
      s2 += hv[j] * Wa[row * NHEADS + c];
    }
#pragma unroll
    for (int off = 1; off < 64; off <<= 1) {
      s1 += __shfl_xor(s1, off);
      s2 += __shfl_xor(s2, off);
    }
    db[c] = s1; da[c] = s2;
  }
#pragma unroll
  for (int c = 0; c < 4; ++c) {
    float s = 0.f;
#pragma unroll
    for (int j = 0; j < 8; ++j) s += hv[j] * Wgate[(j * 64 + lane) * NEXP + c];
#pragma unroll
    for (int off = 1; off < 64; off <<= 1) s += __shfl_xor(s, off);
    dg[c] = s;
  }
  if (lane == 0) {
#pragma unroll
    for (int c = 0; c < 8; ++c) {
      beta_o[t * NHEADS + c] = dev_sigmoid(db[c]);
      g_o[t * NHEADS + c] = -expf(A_log[c]) * dev_softplus(da[c] + dt_bias[c]);
    }
    float mx = fmaxf(fmaxf(dg[0], dg[1]), fmaxf(dg[2], dg[3]));
    float p[4]; float sum = 0.f;
#pragma unroll
    for (int c = 0; c < 4; ++c) { p[c] = expf(dg[c] - mx); sum += p[c]; }
#pragma unroll
    for (int c = 0; c < 4; ++c) p[c] /= sum;
    float v1 = -1e30f; int i1 = 0;
#pragma unroll
    for (int c = 0; c < 4; ++c) { if (p[c] > v1) { v1 = p[c]; i1 = c; } }
    float v2 = -1e30f; int i2 = -1;
#pragma unroll
    for (int c = 0; c < 4; ++c) { if (c != i1 && p[c] > v2) { v2 = p[c]; i2 = c; } }
    float s2v = v1 + v2;
#pragma unroll
    for (int c = 0; c < 4; ++c) {
      float wv = 0.f;
      if (c == i1) wv = v1 / s2v;
      else if (c == i2) wv = v2 / s2v;
      w_o[t * NEXP + c] = wv;
    }
  }
}

// ---------------- routed-token compaction (fallback path) ----------------
__global__ __launch_bounds__(64) void compact_kernel(
    const float* __restrict__ wbuf, int* __restrict__ tidx, int* __restrict__ tcnt) {
  const int e = blockIdx.x, b = blockIdx.y;
  const int lane = threadIdx.x;
  int* out = tidx + (e * BATCH + b) * SEQ;
  int cnt = 0;
  for (int g0 = 0; g0 < SEQ; g0 += 64) {
    const int l = g0 + lane;
    const float w = wbuf[(b * SEQ + l) * NEXP + e];
    const unsigned long long m = __ballot(w > 0.f);
    const int pos = __popcll(m & ((1ull << lane) - 1ull));
    if (w > 0.f) out[cnt + pos] = l;
    cnt += __popcll(m);
  }
  if (lane == 0) tcnt[e * BATCH + b] = cnt;
}

// ---------------- bf16 MFMA GEMM (proven R5) ----------------
#define LDA 56
template <int MODE>
__global__ __launch_bounds__(128) void gemm_mfma(
    const u16* __restrict__ A, const u16* __restrict__ Bt,
    float* __restrict__ C) {
  constexpr int K = DMODEL, N = DMODEL;
  __shared__ __align__(16) short As[128 * LDA];
  __shared__ __align__(16) short Bs[64 * LDA];
  const int tid = threadIdx.x;
  const int wave = tid >> 6, lane = tid & 63;
  const int quad = lane >> 4, l16 = lane & 15;
  const int m0 = blockIdx.x * 128, n0 = blockIdx.y * 64;
  const int bn = tid >> 1, bk = (tid & 1) * 16;
  const u16* Abase = A + (size_t)(m0 + tid) * K;
  const u16* Bbase = Bt + (size_t)(n0 + bn) * K + bk;

  f32x4 acc[4][4];
#pragma unroll
  for (int i = 0; i < 4; ++i)
#pragma unroll
    for (int j = 0; j < 4; ++j) acc[i][j] = (f32x4){0.f, 0.f, 0.f, 0.f};

  int4 pa0, pa1, pa2, pa3, pb0, pb1;
  {
    const u16* p = Abase;
    pa0 = *(const int4*)p; pa1 = *(const int4*)(p + 8);
    pa2 = *(const int4*)(p + 16); pa3 = *(const int4*)(p + 24);
    const u16* q = Bbase;
    pb0 = *(const int4*)q; pb1 = *(const int4*)(q + 8);
  }
  for (int kk = 0; kk < K; kk += 32) {
    __syncthreads();
    *(int4*)&As[tid * LDA + 0] = pa0;
    *(int4*)&As[tid * LDA + 8] = pa1;
    *(int4*)&As[tid * LDA + 16] = pa2;
    *(int4*)&As[tid * LDA + 24] = pa3;
    *(int4*)&Bs[bn * LDA + bk] = pb0;
    *(int4*)&Bs[bn * LDA + bk + 8] = pb1;
    __syncthreads();
    if (kk + 32 < K) {
      const u16* p = Abase + kk + 32;
      pa0 = *(const int4*)p; pa1 = *(const int4*)(p + 8);
      pa2 = *(const int4*)(p + 16); pa3 = *(const int4*)(p + 24);
      const u16* q = Bbase + kk + 32;
      pb0 = *(const int4*)q; pb1 = *(const int4*)(q + 8);
    }
    bf16x8 af[4], bfg[4];
#pragma unroll
    for (int mi = 0; mi < 4; ++mi)
      af[mi] = *(const bf16x8*)&As[(wave * 64 + mi * 16 + l16) * LDA + quad * 8];
#pragma unroll
    for (int ni = 0; ni < 4; ++ni)
      bfg[ni] = *(const bf16x8*)&Bs[(ni * 16 + l16) * LDA + quad * 8];
#pragma unroll
    for (int mi = 0; mi < 4; ++mi)
#pragma unroll
      for (int ni = 0; ni < 4; ++ni)
        acc[mi][ni] = __builtin_amdgcn_mfma_f32_16x16x32_bf16(af[mi], bfg[ni],
                                                              acc[mi][ni], 0, 0, 0);
  }
#pragma unroll
  for (int mi = 0; mi < 4; ++mi) {
#pragma unroll
    for (int r = 0; r < 4; ++r) {
      const int row = m0 + wave * 64 + mi * 16 + quad * 4 + r;
      float s[4];
#pragma unroll
      for (int ni = 0; ni < 4; ++ni) {
        float x = acc[mi][ni][r];
        s[ni] = (MODE == 0) ? x : dev_silu(x);
      }
      if (MODE == 2) {
        float ss = s[0] * s[0] + s[1] * s[1] + s[2] * s[2] + s[3] * s[3];
        ss += __shfl_xor(ss, 1);
        ss += __shfl_xor(ss, 2);
        ss += __shfl_xor(ss, 4);
        ss += __shfl_xor(ss, 8);
        const float rn = 1.0f / sqrtf(ss + 1e-6f);
#pragma unroll
        for (int ni = 0; ni < 4; ++ni) s[ni] *= rn;
      }
#pragma unroll
      for (int ni = 0; ni < 4; ++ni)
        C[(size_t)row * N + n0 + ni * 16 + l16] = s[ni];
    }
  }
}

// ================= CHUNKED GATED DELTA RULE (MFMA) =================

// ---- phase 1: blocked-panel forward substitution ----
// NOTE: Xt's MFMA-visible k-region MUST be zero-initialized — the Z-update
// MFMA reads full K=32 granules before later panels are staged, and
// 0 x (NaN garbage) = NaN inside MFMA (zero-padded A does not sanitize).
__global__ __launch_bounds__(256) void chunk_phase1(
    const float* __restrict__ kb, const float* __restrict__ vb,
    const float* __restrict__ betab, const float* __restrict__ gbuf,
    const float* __restrict__ wbuf, float* __restrict__ U0buf,
    float* __restrict__ Wbuf, float* __restrict__ cbuf) {
  const int ch = blockIdx.x, eb = blockIdx.y, hh = blockIdx.z;
  const int e = eb >> 2, b = eb & 3;
  const int chunkid = (eb * NHEADS + hh) * NCHUNK + ch;
  const size_t base = (size_t)chunkid * 4096;
  const int tid = threadIdx.x;
  const int wave = tid >> 6, lane = tid & 63;
  const int quad = lane >> 4, l16 = lane & 15;

  __shared__ __align__(16) short Kb[64 * BST];
  __shared__ __align__(16) short Tb[64 * BST];   // bf16 below-panel T, zeroed elsewhere
  __shared__ float Td[4][16][17];                // fp32 diagonal blocks
  __shared__ __align__(16) short Xt[128 * BST];  // bf16 X^T [c][s]
  __shared__ float Zl[16][136];                  // fp32 panel Z
  __shared__ float cc[64], bb[64], exs[64];

  if (tid < 64) {
    const int gt = b * SEQ + ch * 64 + tid;
    const float w = wbuf[gt * NEXP + e];
    float gv = 0.f, bv = 0.f;
    if (w > 0.f) { gv = gbuf[gt * NHEADS + hh]; bv = betab[gt * NHEADS + hh]; }
    float cum = gv;
#pragma unroll
    for (int off = 1; off < 64; off <<= 1) {
      float o = __shfl_up(cum, off);
      if (tid >= off) cum += o;
    }
    cc[tid] = cum; exs[tid] = expf(cum); bb[tid] = bv;
    cbuf[(size_t)chunkid * 64 + tid] = cum;
  }
  // zero the MFMA-visible k<64 region of Tb AND Xt (see NOTE above)
#pragma unroll
  for (int i = tid; i < 64 * 32; i += 256)
    ((int*)&Tb[(i >> 5) * BST])[i & 31] = 0;
#pragma unroll
  for (int i = tid; i < 128 * 32; i += 256)
    ((int*)&Xt[(i >> 5) * BST])[i & 31] = 0;
  {
    const int t = tid >> 2, d0 = (tid & 3) * 16;
    const float* krow = kb + (size_t)(b * SEQ + ch * 64 + t) * DMODEL + hh * 64 + d0;
#pragma unroll
    for (int j = 0; j < 4; ++j)
      *(ushort4*)&Kb[t * BST + d0 + j * 4] = f2b4(*(const float4*)(krow + j * 4));
  }
  __syncthreads();
  // lower-triangular bands of K K^T -> Tb (below panel) / Td (diag panel)
  for (int ni = 0; ni <= wave; ++ni) {
    f32x4 acc = (f32x4){0.f, 0.f, 0.f, 0.f};
#pragma unroll
    for (int ks = 0; ks < 2; ++ks) {
      bf16x8 af = *(const bf16x8*)&Kb[(wave * 16 + l16) * BST + ks * 32 + quad * 8];
      bf16x8 bfr = *(const bf16x8*)&Kb[(ni * 16 + l16) * BST + ks * 32 + quad * 8];
      acc = __builtin_amdgcn_mfma_f32_16x16x32_bf16(af, bfr, acc, 0, 0, 0);
    }
#pragma unroll
    for (int r = 0; r < 4; ++r) {
      const int t = wave * 16 + quad * 4 + r, s = ni * 16 + l16;
      if (s < t) {
        const float val = bb[t] * expf(cc[t] - cc[s]) * acc[r];
        if (ni == wave) Td[wave][t & 15][s & 15] = val;
        else Tb[t * BST + s] = f2b(val);
      }
    }
  }
  __syncthreads();

  const bool solver = tid < 128;
  const bool isV = tid < 64;
  const int col = tid & 63;
  const float* src = isV ? vb : kb;
  const size_t srow = (size_t)(b * SEQ + ch * 64) * DMODEL + hh * 64 + col;
  float u[16];

#pragma unroll
  for (int p = 0; p < 4; ++p) {
    if (p > 0) {
      // Z_p = sum_{q<p} T_pq X_q : 8 n-tiles across 4 waves, k padded to 32
      const int nch = (p + 1) >> 1;
      f32x4 a0 = (f32x4){0.f, 0.f, 0.f, 0.f};
      f32x4 a1 = (f32x4){0.f, 0.f, 0.f, 0.f};
      for (int ks = 0; ks < nch; ++ks) {
        bf16x8 af = *(const bf16x8*)&Tb[(p * 16 + l16) * BST + ks * 32 + quad * 8];
        bf16x8 b0 = *(const bf16x8*)&Xt[(wave * 32 + l16) * BST + ks * 32 + quad * 8];
        bf16x8 b1 = *(const bf16x8*)&Xt[(wave * 32 + 16 + l16) * BST + ks * 32 + quad * 8];
        a0 = __builtin_amdgcn_mfma_f32_16x16x32_bf16(af, b0, a0, 0, 0, 0);
        a1 = __builtin_amdgcn_mfma_f32_16x16x32_bf16(af, b1, a1, 0, 0, 0);
      }
#pragma unroll
      for (int r = 0; r < 4; ++r) {
        Zl[quad * 4 + r][wave * 32 + l16] = a0[r];
        Zl[quad * 4 + r][wave * 32 + 16 + l16] = a1[r];
      }
      __syncthreads();
    }
    if (solver) {
      // intra-panel serial solve with fp32 diag block
#pragma unroll
      for (int i = 0; i < 16; ++i) {
        const int t = p * 16 + i;
        const float R = src[srow + (size_t)t * DMODEL];
        const float sc = isV ? bb[t] : bb[t] * exs[t];
        float v0 = sc * R - ((p > 0) ? Zl[i][tid] : 0.f);
        float v1 = 0.f;
#pragma unroll
        for (int r = 0; r < i; ++r) {
          if (r & 1) v1 = fmaf(-Td[p][i][r], u[r], v1);
          else       v0 = fmaf(-Td[p][i][r], u[r], v0);
        }
        u[i] = v0 + v1;
      }
      // stage X^T bf16 (B-operand for later panels)
#pragma unroll
      for (int j = 0; j < 4; ++j) {
        ushort4 o;
        o.x = f2b(u[j * 4 + 0]); o.y = f2b(u[j * 4 + 1]);
        o.z = f2b(u[j * 4 + 2]); o.w = f2b(u[j * 4 + 3]);
        *(ushort4*)&Xt[tid * BST + p * 16 + j * 4] = o;
      }
      // global outputs: U0^T rows (contiguous) / W rows (stride-64)
      if (isV) {
        float* dst = U0buf + base + (size_t)col * 64 + p * 16;
#pragma unroll
        for (int j = 0; j < 4; ++j)
          *(float4*)(dst + j * 4) = make_float4(u[j * 4], u[j * 4 + 1], u[j * 4 + 2], u[j * 4 + 3]);
      } else {
        float* dst = Wbuf + base + col;
#pragma unroll
        for (int i = 0; i < 16; ++i) dst[(size_t)(p * 16 + i) * 64] = u[i];
      }
    }
    __syncthreads();
  }
}

// ---- phase 2: serial chunk chain per (eb, h). Transpose-free S^T formulation ----
__global__ __launch_bounds__(256) void chunk_phase2(
    const float* __restrict__ cbuf, const float* __restrict__ U0buf,
    const float* __restrict__ Wbuf, const u16* __restrict__ ktg,
    u16* __restrict__ Utg, u16* __restrict__ Stg) {
  const int eb = blockIdx.x, hh = blockIdx.y;
  const int b = eb & 3;
  const int ebh = eb * NHEADS + hh;
  const int tid = threadIdx.x;
  const int wave = tid >> 6, lane = tid & 63;
  const int quad = lane >> 4, l16 = lane & 15;

  __shared__ float Sf[64][68];                    // fp32 S^T [dv][dk]
  __shared__ __align__(16) short Sbt[64 * BST];   // bf16 S^T [dv][dk]
  __shared__ __align__(16) short Wb[64 * BST];    // bf16 W   [t][dk]
  __shared__ __align__(16) short Ktb[64 * BST];   // bf16 K^T [dk][t]
  __shared__ __align__(16) short UextT[64 * BST]; // bf16 (U*ext)^T [dv][t]
  __shared__ float ext[64];
  __shared__ float gamS;

  for (int i = tid; i < 64 * 68; i += 256) (&Sf[0][0])[i] = 0.f;
  __syncthreads();

  const int ktile0 = (b * NHEADS + hh) * NCHUNK;

  for (int ch = 0; ch < NCHUNK; ++ch) {
    const int chunkid = ebh * NCHUNK + ch;
    const size_t base = (size_t)chunkid * 4096;
    const size_t kbase = (size_t)(ktile0 + ch) * 4096;
    if (tid < 64) {
      const float cv = cbuf[(size_t)chunkid * 64 + tid];
      const float c63 = __shfl(cv, 63);
      ext[tid] = expf(c63 - cv);
      if (tid == 63) gamS = expf(cv);
    }
    {  // stage W rows (cast) + K^T rows (copy)
      const int r = tid >> 2, c0 = (tid & 3) * 16;
      const float* wrow = Wbuf + base + (size_t)r * 64 + c0;
      const u16* krow = ktg + kbase + (size_t)r * 64 + c0;
#pragma unroll
      for (int j = 0; j < 4; ++j) {
        *(ushort4*)&Wb[r * BST + c0 + j * 4] = f2b4(*(const float4*)(wrow + j * 4));
        *(ushort4*)&Ktb[r * BST + c0 + j * 4] = *(const ushort4*)(krow + j * 4);
      }
    }
    // cast S^T -> bf16 (same orientation: conflict-free)
    for (int i = tid; i < 1024; i += 256) {
      const int dv = i >> 4, d4 = (i & 15) * 4;
      const float* s4 = &Sf[dv][d4];
      ushort4 o; o.x = f2b(s4[0]); o.y = f2b(s4[1]); o.z = f2b(s4[2]); o.w = f2b(s4[3]);
      *(ushort4*)&Sbt[dv * BST + d4] = o;
    }
    __syncthreads();
    // snapshot S0^T bf16 -> global (coalesced)
    for (int i = tid; i < 1024; i += 256) {
      const int r = i >> 4, c4 = (i & 15) * 4;
      *(ushort4*)(Stg + base + r * 64 + c4) = *(const ushort4*)&Sbt[r * BST + c4];
    }
    // GEMM1': C1[dv][t]; U^T = U0^T - C1; store Utg + UextT
    for (int ni = 0; ni < 4; ++ni) {
      f32x4 acc = (f32x4){0.f, 0.f, 0.f, 0.f};
#pragma unroll
      for (int ks = 0; ks < 2; ++ks) {
        bf16x8 af = *(const bf16x8*)&Sbt[(wave * 16 + l16) * BST + ks * 32 + quad * 8];
        bf16x8 bfr = *(const bf16x8*)&Wb[(ni * 16 + l16) * BST + ks * 32 + quad * 8];
        acc = __builtin_amdgcn_mfma_f32_16x16x32_bf16(af, bfr, acc, 0, 0, 0);
      }
#pragma unroll
      for (int r = 0; r < 4; ++r) {
        const int dv = wave * 16 + quad * 4 + r, t = ni * 16 + l16;
        const float uv = U0buf[base + (size_t)dv * 64 + t] - acc[r];
        Utg[base + (size_t)dv * 64 + t] = f2b(uv);
        UextT[dv * BST + t] = f2b(uv * ext[t]);
      }
    }
    __syncthreads();
    // GEMM2': S^T = g*S^T + UextT * K ; owner-thread fp32 update
    const float g = gamS;
    for (int ni = 0; ni < 4; ++ni) {
      f32x4 acc = (f32x4){0.f, 0.f, 0.f, 0.f};
#pragma unroll
      for (int ks = 0; ks < 2; ++ks) {
        bf16x8 af = *(const bf16x8*)&UextT[(wave * 16 + l16) * BST + ks * 32 + quad * 8];
        bf16x8 bfr = *(const bf16x8*)&Ktb[(ni * 16 + l16) * BST + ks * 32 + quad * 8];
        acc = __builtin_amdgcn_mfma_f32_16x16x32_bf16(af, bfr, acc, 0, 0, 0);
      }
#pragma unroll
      for (int r = 0; r < 4; ++r) {
        const int dv = wave * 16 + quad * 4 + r, dk = ni * 16 + l16;
        Sf[dv][dk] = g * Sf[dv][dk] + acc[r];
      }
    }
    __syncthreads();
  }
}

// ---- phase 3: parallel (chunk, eb, h). P = QK^T; O = e^c QS + P U; combine ----
__global__ __launch_bounds__(256) void chunk_phase3(
    const float* __restrict__ qb, const float* __restrict__ kb,
    const float* __restrict__ cbuf, const u16* __restrict__ Utg,
    const u16* __restrict__ Stg, const float* __restrict__ wbuf,
    float* __restrict__ coreb) {
  const int ch = blockIdx.x, eb = blockIdx.y, hh = blockIdx.z;
  const int e = eb >> 2, b = eb & 3;
  const int chunkid = (eb * NHEADS + hh) * NCHUNK + ch;
  const size_t base = (size_t)chunkid * 4096;
  const int tid = threadIdx.x;
  const int wave = tid >> 6, lane = tid & 63;
  const int quad = lane >> 4, l16 = lane & 15;

  __shared__ __align__(16) short Qb[64 * BST];
  __shared__ __align__(16) short Kb3[64 * BST];
  __shared__ __align__(16) short Pb[64 * BST];
  __shared__ __align__(16) short Stb[64 * BST];
  __shared__ __align__(16) short Utb[64 * BST];
  __shared__ float cc3[64];

  if (tid < 64) cc3[tid] = cbuf[(size_t)chunkid * 64 + tid];
  {
    const int t = tid >> 2, d0 = (tid & 3) * 16;
    const size_t ro = (size_t)(b * SEQ + ch * 64 + t) * DMODEL + hh * 64 + d0;
#pragma unroll
    for (int j = 0; j < 4; ++j) {
      *(ushort4*)&Qb[t * BST + d0 + j * 4] = f2b4(*(const float4*)(qb + ro + j * 4));
      *(ushort4*)&Kb3[t * BST + d0 + j * 4] = f2b4(*(const float4*)(kb + ro + j * 4));
    }
  }
  for (int i = tid; i < 1024; i += 256) {
    const int r = i >> 4, c4 = (i & 15) * 4;
    *(ushort4*)&Stb[r * BST + c4] = *(const ushort4*)(Stg + base + r * 64 + c4);
    *(ushort4*)&Utb[r * BST + c4] = *(const ushort4*)(Utg + base + r * 64 + c4);
  }
  __syncthreads();
  // P~[t][s] = (s<=t) e^{c_t-c_s} (q_t.k_s)
  for (int ni = 0; ni < 4; ++ni) {
    f32x4 acc = (f32x4){0.f, 0.f, 0.f, 0.f};
#pragma unroll
    for (int ks = 0; ks < 2; ++ks) {
      bf16x8 af = *(const bf16x8*)&Qb[(wave * 16 + l16) * BST + ks * 32 + quad * 8];
      bf16x8 bfr = *(const bf16x8*)&Kb3[(ni * 16 + l16) * BST + ks * 32 + quad * 8];
      acc = __builtin_amdgcn_mfma_f32_16x16x32_bf16(af, bfr, acc, 0, 0, 0);
    }
#pragma unroll
    for (int r = 0; r < 4; ++r) {
      const int t = wave * 16 + quad * 4 + r, s = ni * 16 + l16;
      const float p = (s <= t) ? expf(cc3[t] - cc3[s]) * acc[r] : 0.f;
      Pb[t * BST + s] = f2b(p);
    }
  }
  __syncthreads();
  // O = 0.125 * (e^{c_t} Q S0 + P~ U)
  for (int ni = 0; ni < 4; ++ni) {
    f32x4 a1 = (f32x4){0.f, 0.f, 0.f, 0.f};
    f32x4 a2 = (f32x4){0.f, 0.f, 0.f, 0.f};
#pragma unroll
    for (int ks = 0; ks < 2; ++ks) {
      bf16x8 afq = *(const bf16x8*)&Qb[(wave * 16 + l16) * BST + ks * 32 + quad * 8];
      bf16x8 bfs = *(const bf16x8*)&Stb[(ni * 16 + l16) * BST + ks * 32 + quad * 8];
      a1 = __builtin_amdgcn_mfma_f32_16x16x32_bf16(afq, bfs, a1, 0, 0, 0);
      bf16x8 afp = *(const bf16x8*)&Pb[(wave * 16 + l16) * BST + ks * 32 + quad * 8];
      bf16x8 bfu = *(const bf16x8*)&Utb[(ni * 16 + l16) * BST + ks * 32 + quad * 8];
      a2 = __builtin_amdgcn_mfma_f32_16x16x32_bf16(afp, bfu, a2, 0, 0, 0);
    }
#pragma unroll
    for (int r = 0; r < 4; ++r) {
      const int t = wave * 16 + quad * 4 + r, dv = ni * 16 + l16;
      const int gt = b * SEQ + ch * 64 + t;
      const float wv = wbuf[gt * NEXP + e];
      if (wv > 0.f) {
        const float o = 0.125f * (expf(cc3[t]) * a1[r] + a2[r]);
        atomicAdd(&coreb[(size_t)gt * DMODEL + hh * 64 + dv], wv * o);
      }
    }
  }
}

// ---------------- fallback serial scan (R3-proven) ----------------
__global__ __launch_bounds__(64) void scan_kernel(
    const float* __restrict__ qb, const float* __restrict__ kb,
    const float* __restrict__ vb, const float* __restrict__ betab,
    const float* __restrict__ gbuf, const float* __restrict__ wbuf,
    const int* __restrict__ tidx, const int* __restrict__ tcnt,
    float* __restrict__ coreb) {
  const int vhalf = blockIdx.x & 1, e = blockIdx.x >> 1;
  const int b = blockIdx.y, hh = blockIdx.z;
  const int lane = threadIdx.x;
  const int kh = lane >> 5;
  const int vi = lane & 31;
  const int cv = vhalf * 32 + vi;
  const int* idx = tidx + (e * BATCH + b) * SEQ;
  const int n = tcnt[e * BATCH + b];
  if (n == 0) return;
  const int nm1 = n - 1;
  __shared__ __align__(16) float lk[4][64];
  __shared__ __align__(16) float lq[4][64];
  __shared__ int lidx[SEQ];
  for (int i = lane; i < SEQ; i += 64) lidx[i] = idx[i < n ? i : nm1];
  __syncthreads();
  v2f S2[16];
#pragma unroll
  for (int j = 0; j < 16; ++j) S2[j] = (v2f){0.f, 0.f};
  float kf[4], qf[4], vf[4], gf[4], bf[4], wf[4], egr[4];
  int tcur[4], tok4[4];
#define PREF(SLOT, TK)                                          \
  do {                                                          \
    const int tn_ = b * SEQ + (TK);                             \
    const size_t kq_ = (size_t)tn_ * DMODEL + hh * 64 + lane;   \
    kf[SLOT] = kb[kq_];                                         \
    qf[SLOT] = qb[kq_];                                         \
    vf[SLOT] = vb[(size_t)tn_ * DMODEL + hh * 64 + cv];         \
    gf[SLOT] = gbuf[tn_ * NHEADS + hh];                         \
    bf[SLOT] = betab[tn_ * NHEADS + hh];                        \
    wf[SLOT] = wbuf[tn_ * NEXP + e];                            \
    tcur[SLOT] = tn_;                                           \
  } while (0)
  tok4[0] = lidx[0];
  tok4[1] = lidx[1 < n ? 1 : nm1];
  tok4[2] = lidx[2 < n ? 2 : nm1];
  tok4[3] = lidx[3 < n ? 3 : nm1];
  PREF(0, tok4[0]); PREF(1, tok4[1]); PREF(2, tok4[2]);
  lk[0][lane] = kf[0]; lq[0][lane] = qf[0];
  egr[0] = expf(gf[0]);
  const int m = (n + 3) & ~3;
  for (int i = 0; i < m; i += 4) {
#pragma unroll
    for (int u = 0; u < 4; ++u) {
      const int s = i + u;
      const int sN = (u + 3) & 3;
      const int s1 = (u + 1) & 3;
      PREF(sN, tok4[sN]);
      int a4 = s + 4;
      a4 = a4 < nm1 ? a4 : nm1;
      tok4[u] = lidx[a4];
      __builtin_amdgcn_wave_barrier();
      lk[s1][lane] = kf[s1];
      lq[s1][lane] = qf[s1];
      __builtin_amdgcn_wave_barrier();
      egr[s1] = expf(gf[s1]);
      const v4f* lk4 = (const v4f*)&lk[u][kh * 32];
      const v4f* lq4 = (const v4f*)&lq[u][kh * 32];
      v2f myk[16];
      v2f c0 = (v2f){0.f, 0.f}, c1 = c0, c2 = c0, c3 = c0;
#pragma unroll
      for (int j = 0; j < 8; ++j) {
        const v4f k4 = lk4[j];
        const v2f klo = (v2f){k4.x, k4.y};
        const v2f khi = (v2f){k4.z, k4.w};
        myk[2 * j] = klo; myk[2 * j + 1] = khi;
        if (j & 1) {
          c2 = __builtin_elementwise_fma(klo, S2[2 * j], c2);
          c3 = __builtin_elementwise_fma(khi, S2[2 * j + 1], c3);
        } else {
          c0 = __builtin_elementwise_fma(klo, S2[2 * j], c0);
          c1 = __builtin_elementwise_fma(khi, S2[2 * j + 1], c1);
        }
      }
      const v2f cacc = (c0 + c1) + (c2 + c3);
      float cd = cacc.x + cacc.y;
      cd += __shfl_xor(cd, 32);
      const float egc = egr[u];
      const float delta = (vf[u] - egc * cd) * bf[u];
      const v2f d2 = (v2f){delta, delta};
      const v2f eg2 = (v2f){egc, egc};
      v2f o0 = (v2f){0.f, 0.f}, o1 = o0, o2 = o0, o3 = o0;
#pragma unroll
      for (int j = 0; j < 8; ++j) {
        const v4f q4 = lq4[j];
        const v2f qlo = (v2f){q4.x, q4.y};
        const v2f qhi = (v2f){q4.z, q4.w};
        const v2f s0 = __builtin_elementwise_fma(S2[2 * j], eg2, myk[2 * j] * d2);
        const v2f s1v = __builtin_elementwise_fma(S2[2 * j + 1], eg2, myk[2 * j + 1] * d2);
        S2[2 * j] = s0; S2[2 * j + 1] = s1v;
        if (j & 1) {
          o2 = __builtin_elementwise_fma(qlo, s0, o2);
          o3 = __builtin_elementwise_fma(qhi, s1v, o3);
        } else {
          o0 = __builtin_elementwise_fma(qlo, s0, o0);
          o1 = __builtin_elementwise_fma(qhi, s1v, o1);
        }
      }
      const v2f oacc = (o0 + o1) + (o2 + o3);
      float o = oacc.x + oacc.y;
      o += __shfl_xor(o, 32);
      if (kh == 0 && s < n)
        atomicAdd(&coreb[(size_t)tcur[u] * DMODEL + hh * 64 + cv],
                  o * 0.125f * wf[u]);
    }
  }
#undef PREF
}

// ---------------- fused gated RMSNorm -> bf16 ----------------
__global__ __launch_bounds__(512) void rmsnorm_kernel(
    const float* __restrict__ coreb, const float* __restrict__ gateb,
    const float* __restrict__ wn, u16* __restrict__ outb) {
  const int t = blockIdx.x;
  const int tid = threadIdx.x;
  const int v = tid & 63;
  const float x = coreb[(size_t)t * DMODEL + tid];
  float ss = x * x;
#pragma unroll
  for (int off = 1; off < 64; off <<= 1) ss += __shfl_xor(ss, off);
  const float r = rsqrtf(ss * (1.0f / 64.0f) + 1e-5f);
  const float gt = gateb[(size_t)t * DMODEL + tid];
  outb[(size_t)t * DMODEL + tid] = f2b(x * r * wn[v] * gt);
}

extern "C" void kernel_launch(void* const* d_in, const int* in_sizes, int n_in,
                              void* d_out, int out_size, void* d_ws, size_t ws_size,
                              hipStream_t stream) {
  const float* h       = (const float*)d_in[0];
  const float* Wq      = (const float*)d_in[1];
  const float* Wgate   = (const float*)d_in[2];
  const float* Wk      = (const float*)d_in[3];
  const float* Wv      = (const float*)d_in[4];
  const float* Wb      = (const float*)d_in[5];
  const float* Wa      = (const float*)d_in[6];
  const float* A_log   = (const float*)d_in[7];
  const float* dt_bias = (const float*)d_in[8];
  const float* Wg      = (const float*)d_in[9];
  const float* wn      = (const float*)d_in[10];
  const float* Wo      = (const float*)d_in[11];
  float* out = (float*)d_out;

  char* p = (char*)d_ws;
  const size_t big = (size_t)NTOK * DMODEL;  // 2M elements
  auto alloc = [&](size_t bytes) { char* r = p; p += (bytes + 255) & ~255ull; return r; };
  float* qb    = (float*)alloc(big * 4);
  float* kb    = (float*)alloc(big * 4);
  float* vb    = (float*)alloc(big * 4);
  float* gateb = (float*)alloc(big * 4);
  float* coreb = (float*)alloc(big * 4);
  float* betab = (float*)alloc((size_t)NTOK * NHEADS * 4);
  float* gbuf  = (float*)alloc((size_t)NTOK * NHEADS * 4);
  float* wbuf  = (float*)alloc((size_t)NTOK * NEXP * 4);
  int*   tidx  = (int*)alloc((size_t)NEXP * BATCH * SEQ * 4);
  int*   tcnt  = (int*)alloc(256);
  u16*   hb    = (u16*)alloc(big * 2);
  u16*   nb    = (u16*)alloc(big * 2);
  u16*   wtq   = (u16*)alloc((size_t)DMODEL * DMODEL * 2);
  u16*   wtk   = (u16*)alloc((size_t)DMODEL * DMODEL * 2);
  u16*   wtv   = (u16*)alloc((size_t)DMODEL * DMODEL * 2);
  u16*   wtg   = (u16*)alloc((size_t)DMODEL * DMODEL * 2);
  u16*   wto   = (u16*)alloc((size_t)DMODEL * DMODEL * 2);
  // chunked-path extras
  const size_t nchunks = (size_t)NEXP * BATCH * NHEADS * NCHUNK;  // 2048
  float* U0buf = (float*)alloc(nchunks * 4096 * 4);
  float* Wbuf_ = (float*)alloc(nchunks * 4096 * 4);
  u16*   Utg   = (u16*)alloc(nchunks * 4096 * 2);
  u16*   Stg   = (u16*)alloc(nchunks * 4096 * 2);
  float* cbuf  = (float*)alloc(nchunks * 64 * 4);
  u16*   ktg   = (u16*)alloc((size_t)BATCH * NHEADS * NCHUNK * 4096 * 2);
  const size_t need = (size_t)(p - (char*)d_ws);
  const bool use_chunked = (ws_size >= need);

  zero_kernel<<<dim3(NTOK * DMODEL / 4 / 256), 256, 0, stream>>>((float4*)coreb);

  cast_h_kernel<<<dim3(big / 4 / 256), 256, 0, stream>>>((const float4*)h, (ushort4*)hb);
  dim3 tg(16, 16);
  castT_kernel<<<tg, 256, 0, stream>>>(Wq, wtq);
  castT_kernel<<<tg, 256, 0, stream>>>(Wk, wtk);
  castT_kernel<<<tg, 256, 0, stream>>>(Wv, wtv);
  castT_kernel<<<tg, 256, 0, stream>>>(Wg, wtg);
  castT_kernel<<<tg, 256, 0, stream>>>(Wo, wto);

  router_kernel<<<dim3(NTOK), 64, 0, stream>>>(h, Wb, Wa, Wgate, A_log, dt_bias,
                                               betab, gbuf, wbuf);

  dim3 gg(NTOK / 128, DMODEL / 64);
  gemm_mfma<2><<<gg, 128, 0, stream>>>(hb, wtq, qb);
  gemm_mfma<2><<<gg, 128, 0, stream>>>(hb, wtk, kb);
  gemm_mfma<1><<<gg, 128, 0, stream>>>(hb, wtv, vb);
  gemm_mfma<1><<<gg, 128, 0, stream>>>(hb, wtg, gateb);

  if (use_chunked) {
    kT_kernel<<<dim3(NCHUNK, BATCH, NHEADS), 256, 0, stream>>>(kb, ktg);
    chunk_phase1<<<dim3(NCHUNK, NEXP * BATCH, NHEADS), 256, 0, stream>>>(
        kb, vb, betab, gbuf, wbuf, U0buf, Wbuf_, cbuf);
    chunk_phase2<<<dim3(NEXP * BATCH, NHEADS), 256, 0, stream>>>(
        cbuf, U0buf, Wbuf_, ktg, Utg, Stg);
    chunk_phase3<<<dim3(NCHUNK, NEXP * BATCH, NHEADS), 256, 0, stream>>>(
        qb, kb, cbuf, Utg, Stg, wbuf, coreb);
  } else {
    compact_kernel<<<dim3(NEXP, BATCH), 64, 0, stream>>>(wbuf, tidx, tcnt);
    scan_kernel<<<dim3(NEXP * 2, BATCH, NHEADS), 64, 0, stream>>>(
        qb, kb, vb, betab, gbuf, wbuf, tidx, tcnt, coreb);
  }

  rmsnorm_kernel<<<dim3(NTOK), 512, 0, stream>>>(coreb, gateb, wn, nb);

  gemm_mfma<0><<<gg, 128, 0, stream>>>(nb, wto, out);
}

// Round 11
// 308.533 us; speedup vs baseline: 10.8581x; 1.0291x over previous
//
#include <hip/hip_runtime.h>
#include <math.h>

#define DMODEL 512
#define NHEADS 8
#define NEXP 4
#define SEQ 1024
#define BATCH 4
#define NTOK 4096  // BATCH * SEQ
#define NCHUNK 16  // SEQ / 64

typedef float v2f __attribute__((ext_vector_type(2)));
typedef float v4f __attribute__((ext_vector_type(4)));
typedef short bf16x8 __attribute__((ext_vector_type(8)));
typedef float f32x4 __attribute__((ext_vector_type(4)));
typedef unsigned short u16;

__device__ __forceinline__ float dev_sigmoid(float x) { return 1.0f / (1.0f + expf(-x)); }
__device__ __forceinline__ float dev_silu(float x) { return x / (1.0f + expf(-x)); }
__device__ __forceinline__ float dev_softplus(float x) {
  return x > 0.0f ? x + log1pf(expf(-x)) : log1pf(expf(x));
}
// fp32 -> bf16 bits, round-to-nearest-even
__device__ __forceinline__ u16 f2b(float f) {
  unsigned int u = __float_as_uint(f);
  unsigned int r = (u + 0x7fffu + ((u >> 16) & 1u)) >> 16;
  return (u16)r;
}
__device__ __forceinline__ ushort4 f2b4(float4 v) {
  ushort4 o; o.x = f2b(v.x); o.y = f2b(v.y); o.z = f2b(v.z); o.w = f2b(v.w); return o;
}

// bf16 LDS row stride in shorts: 72 (144 B) -> 16B-aligned fragments
#define BST 72

// ---------------- zero kernel ----------------
__global__ __launch_bounds__(256) void zero_kernel(float4* __restrict__ p) {
  p[(size_t)blockIdx.x * 256 + threadIdx.x] = make_float4(0.f, 0.f, 0.f, 0.f);
}

// ---------------- cast h (fp32) -> bf16 bits ----------------
__global__ __launch_bounds__(256) void cast_h_kernel(const float4* __restrict__ in,
                                                     ushort4* __restrict__ outp) {
  const size_t i = (size_t)blockIdx.x * 256 + threadIdx.x;
  outp[i] = f2b4(in[i]);
}

// ---------------- transpose-cast weight: W[512][512] fp32 -> Wt[n][k] bf16 -------------
__global__ __launch_bounds__(256) void castT_kernel(const float* __restrict__ in,
                                                    u16* __restrict__ outp) {
  __shared__ float tile[32][33];
  const int bx = blockIdx.x * 32;  // k base
  const int by = blockIdx.y * 32;  // n base
  const int c = threadIdx.x & 31, r0 = threadIdx.x >> 5;
#pragma unroll
  for (int r = r0; r < 32; r += 8) tile[r][c] = in[(size_t)(bx + r) * DMODEL + by + c];
  __syncthreads();
#pragma unroll
  for (int r = r0; r < 32; r += 8)
    outp[(size_t)(by + r) * DMODEL + bx + c] = f2b(tile[c][r]);
}

// ---------------- per-(b,h,chunk) K^T bf16 tiles: ktg[tile][dk][t] ----------------
__global__ __launch_bounds__(256) void kT_kernel(const float* __restrict__ kb,
                                                 u16* __restrict__ ktg) {
  const int ch = blockIdx.x, b = blockIdx.y, hh = blockIdx.z;
  const int tile = (b * NHEADS + hh) * NCHUNK + ch;
  const int tid = threadIdx.x;
  __shared__ float tl[64][65];
  {
    const int t = tid >> 2, d0 = (tid & 3) * 16;
    const float* krow = kb + (size_t)(b * SEQ + ch * 64 + t) * DMODEL + hh * 64 + d0;
#pragma unroll
    for (int j = 0; j < 4; ++j) {
      float4 v = *(const float4*)(krow + j * 4);
      tl[t][d0 + j * 4 + 0] = v.x; tl[t][d0 + j * 4 + 1] = v.y;
      tl[t][d0 + j * 4 + 2] = v.z; tl[t][d0 + j * 4 + 3] = v.w;
    }
  }
  __syncthreads();
  {
    const int t = tid & 63, dk0 = (tid >> 6) * 16;
    u16* obase = ktg + (size_t)tile * 4096 + t;
#pragma unroll
    for (int j = 0; j < 16; ++j)
      obase[(size_t)(dk0 + j) * 64] = f2b(tl[t][dk0 + j]);
  }
}

// ---------------- router + beta/g small projections: one wave per token ----------------
__global__ __launch_bounds__(64) void router_kernel(
    const float* __restrict__ h, const float* __restrict__ Wb,
    const float* __restrict__ Wa, const float* __restrict__ Wgate,
    const float* __restrict__ A_log, const float* __restrict__ dt_bias,
    float* __restrict__ beta_o, float* __restrict__ g_o, float* __restrict__ w_o) {
  const int t = blockIdx.x;
  const int lane = threadIdx.x;
  float hv[8];
#pragma unroll
  for (int j = 0; j < 8; ++j) hv[j] = h[(size_t)t * DMODEL + j * 64 + lane];
  float db[8], da[8], dg[4];
#pragma unroll
  for (int c = 0; c < 8; ++c) {
    float s1 = 0.f, s2 = 0.f;
#pragma unroll
    for (int j = 0; j < 8; ++j) {
      int row = j * 64 + lane;
      s1 += hv[j] * Wb[row * NHEADS + c];
      s2 += hv[j] * Wa[row * NHEADS + c];
    }
#pragma unroll
    for (int off = 1; off < 64; off <<= 1) {
      s1 += __shfl_xor(s1, off);
      s2 += __shfl_xor(s2, off);
    }
    db[c] = s1; da[c] = s2;
  }
#pragma unroll
  for (int c = 0; c < 4; ++c) {
    float s = 0.f;
#pragma unroll
    for (int j = 0; j < 8; ++j) s += hv[j] * Wgate[(j * 64 + lane) * NEXP + c];
#pragma unroll
    for (int off = 1; off < 64; off <<= 1) s += __shfl_xor(s, off);
    dg[c] = s;
  }
  if (lane == 0) {
#pragma unroll
    for (int c = 0; c < 8; ++c) {
      beta_o[t * NHEADS + c] = dev_sigmoid(db[c]);
      g_o[t * NHEADS + c] = -expf(A_log[c]) * dev_softplus(da[c] + dt_bias[c]);
    }
    float mx = fmaxf(fmaxf(dg[0], dg[1]), fmaxf(dg[2], dg[3]));
    float p[4]; float sum = 0.f;
#pragma unroll
    for (int c = 0; c < 4; ++c) { p[c] = expf(dg[c] - mx); sum += p[c]; }
#pragma unroll
    for (int c = 0; c < 4; ++c) p[c] /= sum;
    float v1 = -1e30f; int i1 = 0;
#pragma unroll
    for (int c = 0; c < 4; ++c) { if (p[c] > v1) { v1 = p[c]; i1 = c; } }
    float v2 = -1e30f; int i2 = -1;
#pragma unroll
    for (int c = 0; c < 4; ++c) { if (c != i1 && p[c] > v2) { v2 = p[c]; i2 = c; } }
    float s2v = v1 + v2;
#pragma unroll
    for (int c = 0; c < 4; ++c) {
      float wv = 0.f;
      if (c == i1) wv = v1 / s2v;
      else if (c == i2) wv = v2 / s2v;
      w_o[t * NEXP + c] = wv;
    }
  }
}

// ---------------- routed-token compaction (fallback path) ----------------
__global__ __launch_bounds__(64) void compact_kernel(
    const float* __restrict__ wbuf, int* __restrict__ tidx, int* __restrict__ tcnt) {
  const int e = blockIdx.x, b = blockIdx.y;
  const int lane = threadIdx.x;
  int* out = tidx + (e * BATCH + b) * SEQ;
  int cnt = 0;
  for (int g0 = 0; g0 < SEQ; g0 += 64) {
    const int l = g0 + lane;
    const float w = wbuf[(b * SEQ + l) * NEXP + e];
    const unsigned long long m = __ballot(w > 0.f);
    const int pos = __popcll(m & ((1ull << lane) - 1ull));
    if (w > 0.f) out[cnt + pos] = l;
    cnt += __popcll(m);
  }
  if (lane == 0) tcnt[e * BATCH + b] = cnt;
}

// ---------------- bf16 MFMA GEMM (proven R5) ----------------
#define LDA 56
template <int MODE>
__global__ __launch_bounds__(128) void gemm_mfma(
    const u16* __restrict__ A, const u16* __restrict__ Bt,
    float* __restrict__ C) {
  constexpr int K = DMODEL, N = DMODEL;
  __shared__ __align__(16) short As[128 * LDA];
  __shared__ __align__(16) short Bs[64 * LDA];
  const int tid = threadIdx.x;
  const int wave = tid >> 6, lane = tid & 63;
  const int quad = lane >> 4, l16 = lane & 15;
  const int m0 = blockIdx.x * 128, n0 = blockIdx.y * 64;
  const int bn = tid >> 1, bk = (tid & 1) * 16;
  const u16* Abase = A + (size_t)(m0 + tid) * K;
  const u16* Bbase = Bt + (size_t)(n0 + bn) * K + bk;

  f32x4 acc[4][4];
#pragma unroll
  for (int i = 0; i < 4; ++i)
#pragma unroll
    for (int j = 0; j < 4; ++j) acc[i][j] = (f32x4){0.f, 0.f, 0.f, 0.f};

  int4 pa0, pa1, pa2, pa3, pb0, pb1;
  {
    const u16* p = Abase;
    pa0 = *(const int4*)p; pa1 = *(const int4*)(p + 8);
    pa2 = *(const int4*)(p + 16); pa3 = *(const int4*)(p + 24);
    const u16* q = Bbase;
    pb0 = *(const int4*)q; pb1 = *(const int4*)(q + 8);
  }
  for (int kk = 0; kk < K; kk += 32) {
    __syncthreads();
    *(int4*)&As[tid * LDA + 0] = pa0;
    *(int4*)&As[tid * LDA + 8] = pa1;
    *(int4*)&As[tid * LDA + 16] = pa2;
    *(int4*)&As[tid * LDA + 24] = pa3;
    *(int4*)&Bs[bn * LDA + bk] = pb0;
    *(int4*)&Bs[bn * LDA + bk + 8] = pb1;
    __syncthreads();
    if (kk + 32 < K) {
      const u16* p = Abase + kk + 32;
      pa0 = *(const int4*)p; pa1 = *(const int4*)(p + 8);
      pa2 = *(const int4*)(p + 16); pa3 = *(const int4*)(p + 24);
      const u16* q = Bbase + kk + 32;
      pb0 = *(const int4*)q; pb1 = *(const int4*)(q + 8);
    }
    bf16x8 af[4], bfg[4];
#pragma unroll
    for (int mi = 0; mi < 4; ++mi)
      af[mi] = *(const bf16x8*)&As[(wave * 64 + mi * 16 + l16) * LDA + quad * 8];
#pragma unroll
    for (int ni = 0; ni < 4; ++ni)
      bfg[ni] = *(const bf16x8*)&Bs[(ni * 16 + l16) * LDA + quad * 8];
#pragma unroll
    for (int mi = 0; mi < 4; ++mi)
#pragma unroll
      for (int ni = 0; ni < 4; ++ni)
        acc[mi][ni] = __builtin_amdgcn_mfma_f32_16x16x32_bf16(af[mi], bfg[ni],
                                                              acc[mi][ni], 0, 0, 0);
  }
#pragma unroll
  for (int mi = 0; mi < 4; ++mi) {
#pragma unroll
    for (int r = 0; r < 4; ++r) {
      const int row = m0 + wave * 64 + mi * 16 + quad * 4 + r;
      float s[4];
#pragma unroll
      for (int ni = 0; ni < 4; ++ni) {
        float x = acc[mi][ni][r];
        s[ni] = (MODE == 0) ? x : dev_silu(x);
      }
      if (MODE == 2) {
        float ss = s[0] * s[0] + s[1] * s[1] + s[2] * s[2] + s[3] * s[3];
        ss += __shfl_xor(ss, 1);
        ss += __shfl_xor(ss, 2);
        ss += __shfl_xor(ss, 4);
        ss += __shfl_xor(ss, 8);
        const float rn = 1.0f / sqrtf(ss + 1e-6f);
#pragma unroll
        for (int ni = 0; ni < 4; ++ni) s[ni] *= rn;
      }
#pragma unroll
      for (int ni = 0; ni < 4; ++ni)
        C[(size_t)row * N + n0 + ni * 16 + l16] = s[ni];
    }
  }
}

// ================= CHUNKED GATED DELTA RULE (MFMA) =================

// ---- phase 1: blocked-panel forward substitution (proven R10) ----
__global__ __launch_bounds__(256) void chunk_phase1(
    const float* __restrict__ kb, const float* __restrict__ vb,
    const float* __restrict__ betab, const float* __restrict__ gbuf,
    const float* __restrict__ wbuf, float* __restrict__ U0buf,
    float* __restrict__ Wbuf, float* __restrict__ cbuf) {
  const int ch = blockIdx.x, eb = blockIdx.y, hh = blockIdx.z;
  const int e = eb >> 2, b = eb & 3;
  const int chunkid = (eb * NHEADS + hh) * NCHUNK + ch;
  const size_t base = (size_t)chunkid * 4096;
  const int tid = threadIdx.x;
  const int wave = tid >> 6, lane = tid & 63;
  const int quad = lane >> 4, l16 = lane & 15;

  __shared__ __align__(16) short Kb[64 * BST];
  __shared__ __align__(16) short Tb[64 * BST];   // bf16 below-panel T, zeroed elsewhere
  __shared__ float Td[4][16][17];                // fp32 diagonal blocks
  __shared__ __align__(16) short Xt[128 * BST];  // bf16 X^T [c][s]
  __shared__ float Zl[16][136];                  // fp32 panel Z
  __shared__ float cc[64], bb[64], exs[64];

  if (tid < 64) {
    const int gt = b * SEQ + ch * 64 + tid;
    const float w = wbuf[gt * NEXP + e];
    float gv = 0.f, bv = 0.f;
    if (w > 0.f) { gv = gbuf[gt * NHEADS + hh]; bv = betab[gt * NHEADS + hh]; }
    float cum = gv;
#pragma unroll
    for (int off = 1; off < 64; off <<= 1) {
      float o = __shfl_up(cum, off);
      if (tid >= off) cum += o;
    }
    cc[tid] = cum; exs[tid] = expf(cum); bb[tid] = bv;
    cbuf[(size_t)chunkid * 64 + tid] = cum;
  }
  // zero the MFMA-visible k<64 region of Tb AND Xt (0 x NaN = NaN in MFMA)
#pragma unroll
  for (int i = tid; i < 64 * 32; i += 256)
    ((int*)&Tb[(i >> 5) * BST])[i & 31] = 0;
#pragma unroll
  for (int i = tid; i < 128 * 32; i += 256)
    ((int*)&Xt[(i >> 5) * BST])[i & 31] = 0;
  {
    const int t = tid >> 2, d0 = (tid & 3) * 16;
    const float* krow = kb + (size_t)(b * SEQ + ch * 64 + t) * DMODEL + hh * 64 + d0;
#pragma unroll
    for (int j = 0; j < 4; ++j)
      *(ushort4*)&Kb[t * BST + d0 + j * 4] = f2b4(*(const float4*)(krow + j * 4));
  }
  __syncthreads();
  // lower-triangular bands of K K^T -> Tb (below panel) / Td (diag panel)
  for (int ni = 0; ni <= wave; ++ni) {
    f32x4 acc = (f32x4){0.f, 0.f, 0.f, 0.f};
#pragma unroll
    for (int ks = 0; ks < 2; ++ks) {
      bf16x8 af = *(const bf16x8*)&Kb[(wave * 16 + l16) * BST + ks * 32 + quad * 8];
      bf16x8 bfr = *(const bf16x8*)&Kb[(ni * 16 + l16) * BST + ks * 32 + quad * 8];
      acc = __builtin_amdgcn_mfma_f32_16x16x32_bf16(af, bfr, acc, 0, 0, 0);
    }
#pragma unroll
    for (int r = 0; r < 4; ++r) {
      const int t = wave * 16 + quad * 4 + r, s = ni * 16 + l16;
      if (s < t) {
        const float val = bb[t] * expf(cc[t] - cc[s]) * acc[r];
        if (ni == wave) Td[wave][t & 15][s & 15] = val;
        else Tb[t * BST + s] = f2b(val);
      }
    }
  }
  __syncthreads();

  const bool solver = tid < 128;
  const bool isV = tid < 64;
  const int col = tid & 63;
  const float* src = isV ? vb : kb;
  const size_t srow = (size_t)(b * SEQ + ch * 64) * DMODEL + hh * 64 + col;
  float u[16];

#pragma unroll
  for (int p = 0; p < 4; ++p) {
    if (p > 0) {
      const int nch = (p + 1) >> 1;
      f32x4 a0 = (f32x4){0.f, 0.f, 0.f, 0.f};
      f32x4 a1 = (f32x4){0.f, 0.f, 0.f, 0.f};
      for (int ks = 0; ks < nch; ++ks) {
        bf16x8 af = *(const bf16x8*)&Tb[(p * 16 + l16) * BST + ks * 32 + quad * 8];
        bf16x8 b0 = *(const bf16x8*)&Xt[(wave * 32 + l16) * BST + ks * 32 + quad * 8];
        bf16x8 b1 = *(const bf16x8*)&Xt[(wave * 32 + 16 + l16) * BST + ks * 32 + quad * 8];
        a0 = __builtin_amdgcn_mfma_f32_16x16x32_bf16(af, b0, a0, 0, 0, 0);
        a1 = __builtin_amdgcn_mfma_f32_16x16x32_bf16(af, b1, a1, 0, 0, 0);
      }
#pragma unroll
      for (int r = 0; r < 4; ++r) {
        Zl[quad * 4 + r][wave * 32 + l16] = a0[r];
        Zl[quad * 4 + r][wave * 32 + 16 + l16] = a1[r];
      }
      __syncthreads();
    }
    if (solver) {
#pragma unroll
      for (int i = 0; i < 16; ++i) {
        const int t = p * 16 + i;
        const float R = src[srow + (size_t)t * DMODEL];
        const float sc = isV ? bb[t] : bb[t] * exs[t];
        float v0 = sc * R - ((p > 0) ? Zl[i][tid] : 0.f);
        float v1 = 0.f;
#pragma unroll
        for (int r = 0; r < i; ++r) {
          if (r & 1) v1 = fmaf(-Td[p][i][r], u[r], v1);
          else       v0 = fmaf(-Td[p][i][r], u[r], v0);
        }
        u[i] = v0 + v1;
      }
#pragma unroll
      for (int j = 0; j < 4; ++j) {
        ushort4 o;
        o.x = f2b(u[j * 4 + 0]); o.y = f2b(u[j * 4 + 1]);
        o.z = f2b(u[j * 4 + 2]); o.w = f2b(u[j * 4 + 3]);
        *(ushort4*)&Xt[tid * BST + p * 16 + j * 4] = o;
      }
      if (isV) {
        float* dst = U0buf + base + (size_t)col * 64 + p * 16;
#pragma unroll
        for (int j = 0; j < 4; ++j)
          *(float4*)(dst + j * 4) = make_float4(u[j * 4], u[j * 4 + 1], u[j * 4 + 2], u[j * 4 + 3]);
      } else {
        float* dst = Wbuf + base + col;
#pragma unroll
        for (int i = 0; i < 16; ++i) dst[(size_t)(p * 16 + i) * 64] = u[i];
      }
    }
    __syncthreads();
  }
}

// ---- phase 2: serial chunk chain, dv-split (grid z=2) + register prefetch ----
// Per block: S^T half [32 dv][64 dk]. GEMM1': (W*S0)^T half = Sbt x Wb;
// GEMM2': S'^T = g*S^T + UextT x Ktb. Next chunk's W/K^T/U0/c are loaded into
// registers right after the staging barrier -> global latency overlaps compute.
__global__ __launch_bounds__(256) void chunk_phase2(
    const float* __restrict__ cbuf, const float* __restrict__ U0buf,
    const float* __restrict__ Wbuf, const u16* __restrict__ ktg,
    u16* __restrict__ Utg, u16* __restrict__ Stg) {
  const int eb = blockIdx.x, hh = blockIdx.y, dvh = blockIdx.z;
  const int b = eb & 3;
  const int ebh = eb * NHEADS + hh;
  const int tid = threadIdx.x;
  const int wave = tid >> 6, lane = tid & 63;
  const int quad = lane >> 4, l16 = lane & 15;
  const int mi = wave >> 1;           // local dv tile (0..1)
  const int nb0 = (wave & 1) * 2;     // ni base (0 or 2)
  const int dvl0 = mi * 16 + quad * 4;  // local dv row base (+r)
  const int dvg0 = dvh * 32;          // global dv offset

  __shared__ float Sf[32][68];                    // fp32 S^T half [dvl][dk]
  __shared__ __align__(16) short Sbt[32 * BST];   // bf16 S^T half
  __shared__ __align__(16) short Wb[64 * BST];    // bf16 W [t][dk]
  __shared__ __align__(16) short Ktb[64 * BST];   // bf16 K^T [dk][t]
  __shared__ __align__(16) short UextT[32 * BST]; // bf16 (U*ext)^T half [dvl][t]
  __shared__ float ext[64];
  __shared__ float gam_sh;

  for (int i = tid; i < 32 * 68; i += 256) (&Sf[0][0])[i] = 0.f;

  const int ktile0 = (b * NHEADS + hh) * NCHUNK;
  const int sr = tid >> 2, sc = (tid & 3) * 16;  // staging row/col

  // prefetch registers (chunk ch): W 16 floats, K^T 16 shorts, U0 8 floats, c 1
  float4 wreg[4];
  int4 ktreg[2];
  float u0cur[2][4], u0nxt[2][4];
  float cvreg;

#define P2_PREF(CH, WD, KD, UD, CV)                                          \
  do {                                                                       \
    const int ch_ = (CH) < NCHUNK ? (CH) : (NCHUNK - 1);                     \
    const size_t b_ = (size_t)(ebh * NCHUNK + ch_) * 4096;                   \
    const size_t kb_ = (size_t)(ktile0 + ch_) * 4096;                        \
    const float* wr_ = Wbuf + b_ + (size_t)sr * 64 + sc;                     \
    WD[0] = *(const float4*)(wr_ + 0);  WD[1] = *(const float4*)(wr_ + 4);   \
    WD[2] = *(const float4*)(wr_ + 8);  WD[3] = *(const float4*)(wr_ + 12);  \
    const u16* kr_ = ktg + kb_ + (size_t)sr * 64 + sc;                       \
    KD[0] = *(const int4*)kr_; KD[1] = *(const int4*)(kr_ + 8);              \
    _Pragma("unroll")                                                        \
    for (int ni_ = 0; ni_ < 2; ++ni_)                                        \
      _Pragma("unroll")                                                      \
      for (int r_ = 0; r_ < 4; ++r_)                                         \
        UD[ni_][r_] = U0buf[b_ + (size_t)(dvg0 + dvl0 + r_) * 64 +           \
                            (nb0 + ni_) * 16 + l16];                         \
    CV = cbuf[(size_t)(ebh * NCHUNK + ch_) * 64 + (tid & 63)];               \
  } while (0)

  P2_PREF(0, wreg, ktreg, u0cur, cvreg);
  __syncthreads();  // Sf zero-init visible

  for (int ch = 0; ch < NCHUNK; ++ch) {
    const size_t base = (size_t)(ebh * NCHUNK + ch) * 4096;
    // ---- stage from registers ----
    if (tid < 64) {
      const float c63 = __shfl(cvreg, 63);
      ext[tid] = expf(c63 - cvreg);
      if (tid == 63) gam_sh = expf(cvreg);
    }
#pragma unroll
    for (int j = 0; j < 4; ++j)
      *(ushort4*)&Wb[sr * BST + sc + j * 4] = f2b4(wreg[j]);
    *(int4*)&Ktb[sr * BST + sc] = ktreg[0];
    *(int4*)&Ktb[sr * BST + sc + 8] = ktreg[1];
    // cast S^T (chunk-start state) -> bf16
    for (int i = tid; i < 512; i += 256) {
      const int dv = i >> 4, d4 = (i & 15) * 4;
      const float* s4 = &Sf[dv][d4];
      ushort4 o; o.x = f2b(s4[0]); o.y = f2b(s4[1]); o.z = f2b(s4[2]); o.w = f2b(s4[3]);
      *(ushort4*)&Sbt[dv * BST + d4] = o;
    }
    __syncthreads();  // barrier A: staging visible
    // ---- issue prefetch for ch+1 (lands during GEMM1+GEMM2) ----
    P2_PREF(ch + 1, wreg, ktreg, u0nxt, cvreg);
    // snapshot S0^T half -> global (coalesced)
    for (int i = tid; i < 512; i += 256) {
      const int r = i >> 4, c4 = (i & 15) * 4;
      *(ushort4*)(Stg + base + (size_t)(dvg0 + r) * 64 + c4) = *(const ushort4*)&Sbt[r * BST + c4];
    }
    // GEMM1': C1[dvl][t] = Sbt x Wb ; U^T = U0^T - C1 -> Utg + UextT
#pragma unroll
    for (int ni = 0; ni < 2; ++ni) {
      f32x4 acc = (f32x4){0.f, 0.f, 0.f, 0.f};
#pragma unroll
      for (int ks = 0; ks < 2; ++ks) {
        bf16x8 af = *(const bf16x8*)&Sbt[(mi * 16 + l16) * BST + ks * 32 + quad * 8];
        bf16x8 bfr = *(const bf16x8*)&Wb[((nb0 + ni) * 16 + l16) * BST + ks * 32 + quad * 8];
        acc = __builtin_amdgcn_mfma_f32_16x16x32_bf16(af, bfr, acc, 0, 0, 0);
      }
#pragma unroll
      for (int r = 0; r < 4; ++r) {
        const int dvl = dvl0 + r, t = (nb0 + ni) * 16 + l16;
        const float uv = u0cur[ni][r] - acc[r];
        Utg[base + (size_t)(dvg0 + dvl) * 64 + t] = f2b(uv);
        UextT[dvl * BST + t] = f2b(uv * ext[t]);
      }
    }
    __syncthreads();  // barrier B: UextT visible
    // GEMM2': S^T = g*S^T + UextT x Ktb ; owner-thread fp32 update
    const float g = gam_sh;
#pragma unroll
    for (int ni = 0; ni < 2; ++ni) {
      f32x4 acc = (f32x4){0.f, 0.f, 0.f, 0.f};
#pragma unroll
      for (int ks = 0; ks < 2; ++ks) {
        bf16x8 af = *(const bf16x8*)&UextT[(mi * 16 + l16) * BST + ks * 32 + quad * 8];
        bf16x8 bfr = *(const bf16x8*)&Ktb[((nb0 + ni) * 16 + l16) * BST + ks * 32 + quad * 8];
        acc = __builtin_amdgcn_mfma_f32_16x16x32_bf16(af, bfr, acc, 0, 0, 0);
      }
#pragma unroll
      for (int r = 0; r < 4; ++r) {
        const int dvl = dvl0 + r, dk = (nb0 + ni) * 16 + l16;
        Sf[dvl][dk] = g * Sf[dvl][dk] + acc[r];
      }
    }
    // rotate U0 prefetch
#pragma unroll
    for (int ni = 0; ni < 2; ++ni)
#pragma unroll
      for (int r = 0; r < 4; ++r) u0cur[ni][r] = u0nxt[ni][r];
    __syncthreads();  // barrier C: Sf update + LDS reuse safe
  }
#undef P2_PREF
}

// ---- phase 3: parallel (chunk, eb, h). P = QK^T; O = e^c QS + P U; combine ----
__global__ __launch_bounds__(256) void chunk_phase3(
    const float* __restrict__ qb, const float* __restrict__ kb,
    const float* __restrict__ cbuf, const u16* __restrict__ Utg,
    const u16* __restrict__ Stg, const float* __restrict__ wbuf,
    float* __restrict__ coreb) {
  const int ch = blockIdx.x, eb = blockIdx.y, hh = blockIdx.z;
  const int e = eb >> 2, b = eb & 3;
  const int chunkid = (eb * NHEADS + hh) * NCHUNK + ch;
  const size_t base = (size_t)chunkid * 4096;
  const int tid = threadIdx.x;
  const int wave = tid >> 6, lane = tid & 63;
  const int quad = lane >> 4, l16 = lane & 15;

  __shared__ __align__(16) short Qb[64 * BST];
  __shared__ __align__(16) short Kb3[64 * BST];
  __shared__ __align__(16) short Pb[64 * BST];
  __shared__ __align__(16) short Stb[64 * BST];
  __shared__ __align__(16) short Utb[64 * BST];
  __shared__ float cc3[64];

  if (tid < 64) cc3[tid] = cbuf[(size_t)chunkid * 64 + tid];
  {
    const int t = tid >> 2, d0 = (tid & 3) * 16;
    const size_t ro = (size_t)(b * SEQ + ch * 64 + t) * DMODEL + hh * 64 + d0;
#pragma unroll
    for (int j = 0; j < 4; ++j) {
      *(ushort4*)&Qb[t * BST + d0 + j * 4] = f2b4(*(const float4*)(qb + ro + j * 4));
      *(ushort4*)&Kb3[t * BST + d0 + j * 4] = f2b4(*(const float4*)(kb + ro + j * 4));
    }
  }
  for (int i = tid; i < 1024; i += 256) {
    const int r = i >> 4, c4 = (i & 15) * 4;
    *(ushort4*)&Stb[r * BST + c4] = *(const ushort4*)(Stg + base + r * 64 + c4);
    *(ushort4*)&Utb[r * BST + c4] = *(const ushort4*)(Utg + base + r * 64 + c4);
  }
  __syncthreads();
  // P~[t][s] = (s<=t) e^{c_t-c_s} (q_t.k_s)
  for (int ni = 0; ni < 4; ++ni) {
    f32x4 acc = (f32x4){0.f, 0.f, 0.f, 0.f};
#pragma unroll
    for (int ks = 0; ks < 2; ++ks) {
      bf16x8 af = *(const bf16x8*)&Qb[(wave * 16 + l16) * BST + ks * 32 + quad * 8];
      bf16x8 bfr = *(const bf16x8*)&Kb3[(ni * 16 + l16) * BST + ks * 32 + quad * 8];
      acc = __builtin_amdgcn_mfma_f32_16x16x32_bf16(af, bfr, acc, 0, 0, 0);
    }
#pragma unroll
    for (int r = 0; r < 4; ++r) {
      const int t = wave * 16 + quad * 4 + r, s = ni * 16 + l16;
      const float p = (s <= t) ? expf(cc3[t] - cc3[s]) * acc[r] : 0.f;
      Pb[t * BST + s] = f2b(p);
    }
  }
  __syncthreads();
  // O = 0.125 * (e^{c_t} Q S0 + P~ U)
  for (int ni = 0; ni < 4; ++ni) {
    f32x4 a1 = (f32x4){0.f, 0.f, 0.f, 0.f};
    f32x4 a2 = (f32x4){0.f, 0.f, 0.f, 0.f};
#pragma unroll
    for (int ks = 0; ks < 2; ++ks) {
      bf16x8 afq = *(const bf16x8*)&Qb[(wave * 16 + l16) * BST + ks * 32 + quad * 8];
      bf16x8 bfs = *(const bf16x8*)&Stb[(ni * 16 + l16) * BST + ks * 32 + quad * 8];
      a1 = __builtin_amdgcn_mfma_f32_16x16x32_bf16(afq, bfs, a1, 0, 0, 0);
      bf16x8 afp = *(const bf16x8*)&Pb[(wave * 16 + l16) * BST + ks * 32 + quad * 8];
      bf16x8 bfu = *(const bf16x8*)&Utb[(ni * 16 + l16) * BST + ks * 32 + quad * 8];
      a2 = __builtin_amdgcn_mfma_f32_16x16x32_bf16(afp, bfu, a2, 0, 0, 0);
    }
#pragma unroll
    for (int r = 0; r < 4; ++r) {
      const int t = wave * 16 + quad * 4 + r, dv = ni * 16 + l16;
      const int gt = b * SEQ + ch * 64 + t;
      const float wv = wbuf[gt * NEXP + e];
      if (wv > 0.f) {
        const float o = 0.125f * (expf(cc3[t]) * a1[r] + a2[r]);
        atomicAdd(&coreb[(size_t)gt * DMODEL + hh * 64 + dv], wv * o);
      }
    }
  }
}

// ---------------- fallback serial scan (R3-proven) ----------------
__global__ __launch_bounds__(64) void scan_kernel(
    const float* __restrict__ qb, const float* __restrict__ kb,
    const float* __restrict__ vb, const float* __restrict__ betab,
    const float* __restrict__ gbuf, const float* __restrict__ wbuf,
    const int* __restrict__ tidx, const int* __restrict__ tcnt,
    float* __restrict__ coreb) {
  const int vhalf = blockIdx.x & 1, e = blockIdx.x >> 1;
  const int b = blockIdx.y, hh = blockIdx.z;
  const int lane = threadIdx.x;
  const int kh = lane >> 5;
  const int vi = lane & 31;
  const int cv = vhalf * 32 + vi;
  const int* idx = tidx + (e * BATCH + b) * SEQ;
  const int n = tcnt[e * BATCH + b];
  if (n == 0) return;
  const int nm1 = n - 1;
  __shared__ __align__(16) float lk[4][64];
  __shared__ __align__(16) float lq[4][64];
  __shared__ int lidx[SEQ];
  for (int i = lane; i < SEQ; i += 64) lidx[i] = idx[i < n ? i : nm1];
  __syncthreads();
  v2f S2[16];
#pragma unroll
  for (int j = 0; j < 16; ++j) S2[j] = (v2f){0.f, 0.f};
  float kf[4], qf[4], vf[4], gf[4], bf[4], wf[4], egr[4];
  int tcur[4], tok4[4];
#define PREF(SLOT, TK)                                          \
  do {                                                          \
    const int tn_ = b * SEQ + (TK);                             \
    const size_t kq_ = (size_t)tn_ * DMODEL + hh * 64 + lane;   \
    kf[SLOT] = kb[kq_];                                         \
    qf[SLOT] = qb[kq_];                                         \
    vf[SLOT] = vb[(size_t)tn_ * DMODEL + hh * 64 + cv];         \
    gf[SLOT] = gbuf[tn_ * NHEADS + hh];                         \
    bf[SLOT] = betab[tn_ * NHEADS + hh];                        \
    wf[SLOT] = wbuf[tn_ * NEXP + e];                            \
    tcur[SLOT] = tn_;                                           \
  } while (0)
  tok4[0] = lidx[0];
  tok4[1] = lidx[1 < n ? 1 : nm1];
  tok4[2] = lidx[2 < n ? 2 : nm1];
  tok4[3] = lidx[3 < n ? 3 : nm1];
  PREF(0, tok4[0]); PREF(1, tok4[1]); PREF(2, tok4[2]);
  lk[0][lane] = kf[0]; lq[0][lane] = qf[0];
  egr[0] = expf(gf[0]);
  const int m = (n + 3) & ~3;
  for (int i = 0; i < m; i += 4) {
#pragma unroll
    for (int u = 0; u < 4; ++u) {
      const int s = i + u;
      const int sN = (u + 3) & 3;
      const int s1 = (u + 1) & 3;
      PREF(sN, tok4[sN]);
      int a4 = s + 4;
      a4 = a4 < nm1 ? a4 : nm1;
      tok4[u] = lidx[a4];
      __builtin_amdgcn_wave_barrier();
      lk[s1][lane] = kf[s1];
      lq[s1][lane] = qf[s1];
      __builtin_amdgcn_wave_barrier();
      egr[s1] = expf(gf[s1]);
      const v4f* lk4 = (const v4f*)&lk[u][kh * 32];
      const v4f* lq4 = (const v4f*)&lq[u][kh * 32];
      v2f myk[16];
      v2f c0 = (v2f){0.f, 0.f}, c1 = c0, c2 = c0, c3 = c0;
#pragma unroll
      for (int j = 0; j < 8; ++j) {
        const v4f k4 = lk4[j];
        const v2f klo = (v2f){k4.x, k4.y};
        const v2f khi = (v2f){k4.z, k4.w};
        myk[2 * j] = klo; myk[2 * j + 1] = khi;
        if (j & 1) {
          c2 = __builtin_elementwise_fma(klo, S2[2 * j], c2);
          c3 = __builtin_elementwise_fma(khi, S2[2 * j + 1], c3);
        } else {
          c0 = __builtin_elementwise_fma(klo, S2[2 * j], c0);
          c1 = __builtin_elementwise_fma(khi, S2[2 * j + 1], c1);
        }
      }
      const v2f cacc = (c0 + c1) + (c2 + c3);
      float cd = cacc.x + cacc.y;
      cd += __shfl_xor(cd, 32);
      const float egc = egr[u];
      const float delta = (vf[u] - egc * cd) * bf[u];
      const v2f d2 = (v2f){delta, delta};
      const v2f eg2 = (v2f){egc, egc};
      v2f o0 = (v2f){0.f, 0.f}, o1 = o0, o2 = o0, o3 = o0;
#pragma unroll
      for (int j = 0; j < 8; ++j) {
        const v4f q4 = lq4[j];
        const v2f qlo = (v2f){q4.x, q4.y};
        const v2f qhi = (v2f){q4.z, q4.w};
        const v2f s0 = __builtin_elementwise_fma(S2[2 * j], eg2, myk[2 * j] * d2);
        const v2f s1v = __builtin_elementwise_fma(S2[2 * j + 1], eg2, myk[2 * j + 1] * d2);
        S2[2 * j] = s0; S2[2 * j + 1] = s1v;
        if (j & 1) {
          o2 = __builtin_elementwise_fma(qlo, s0, o2);
          o3 = __builtin_elementwise_fma(qhi, s1v, o3);
        } else {
          o0 = __builtin_elementwise_fma(qlo, s0, o0);
          o1 = __builtin_elementwise_fma(qhi, s1v, o1);
        }
      }
      const v2f oacc = (o0 + o1) + (o2 + o3);
      float o = oacc.x + oacc.y;
      o += __shfl_xor(o, 32);
      if (kh == 0 && s < n)
        atomicAdd(&coreb[(size_t)tcur[u] * DMODEL + hh * 64 + cv],
                  o * 0.125f * wf[u]);
    }
  }
#undef PREF
}

// ---------------- fused gated RMSNorm -> bf16 ----------------
__global__ __launch_bounds__(512) void rmsnorm_kernel(
    const float* __restrict__ coreb, const float* __restrict__ gateb,
    const float* __restrict__ wn, u16* __restrict__ outb) {
  const int t = blockIdx.x;
  const int tid = threadIdx.x;
  const int v = tid & 63;
  const float x = coreb[(size_t)t * DMODEL + tid];
  float ss = x * x;
#pragma unroll
  for (int off = 1; off < 64; off <<= 1) ss += __shfl_xor(ss, off);
  const float r = rsqrtf(ss * (1.0f / 64.0f) + 1e-5f);
  const float gt = gateb[(size_t)t * DMODEL + tid];
  outb[(size_t)t * DMODEL + tid] = f2b(x * r * wn[v] * gt);
}

extern "C" void kernel_launch(void* const* d_in, const int* in_sizes, int n_in,
                              void* d_out, int out_size, void* d_ws, size_t ws_size,
                              hipStream_t stream) {
  const float* h       = (const float*)d_in[0];
  const float* Wq      = (const float*)d_in[1];
  const float* Wgate   = (const float*)d_in[2];
  const float* Wk      = (const float*)d_in[3];
  const float* Wv      = (const float*)d_in[4];
  const float* Wb      = (const float*)d_in[5];
  const float* Wa      = (const float*)d_in[6];
  const float* A_log   = (const float*)d_in[7];
  const float* dt_bias = (const float*)d_in[8];
  const float* Wg      = (const float*)d_in[9];
  const float* wn      = (const float*)d_in[10];
  const float* Wo      = (const float*)d_in[11];
  float* out = (float*)d_out;

  char* p = (char*)d_ws;
  const size_t big = (size_t)NTOK * DMODEL;  // 2M elements
  auto alloc = [&](size_t bytes) { char* r = p; p += (bytes + 255) & ~255ull; return r; };
  float* qb    = (float*)alloc(big * 4);
  float* kb    = (float*)alloc(big * 4);
  float* vb    = (float*)alloc(big * 4);
  float* gateb = (float*)alloc(big * 4);
  float* coreb = (float*)alloc(big * 4);
  float* betab = (float*)alloc((size_t)NTOK * NHEADS * 4);
  float* gbuf  = (float*)alloc((size_t)NTOK * NHEADS * 4);
  float* wbuf  = (float*)alloc((size_t)NTOK * NEXP * 4);
  int*   tidx  = (int*)alloc((size_t)NEXP * BATCH * SEQ * 4);
  int*   tcnt  = (int*)alloc(256);
  u16*   hb    = (u16*)alloc(big * 2);
  u16*   nb    = (u16*)alloc(big * 2);
  u16*   wtq   = (u16*)alloc((size_t)DMODEL * DMODEL * 2);
  u16*   wtk   = (u16*)alloc((size_t)DMODEL * DMODEL * 2);
  u16*   wtv   = (u16*)alloc((size_t)DMODEL * DMODEL * 2);
  u16*   wtg   = (u16*)alloc((size_t)DMODEL * DMODEL * 2);
  u16*   wto   = (u16*)alloc((size_t)DMODEL * DMODEL * 2);
  // chunked-path extras
  const size_t nchunks = (size_t)NEXP * BATCH * NHEADS * NCHUNK;  // 2048
  float* U0buf = (float*)alloc(nchunks * 4096 * 4);
  float* Wbuf_ = (float*)alloc(nchunks * 4096 * 4);
  u16*   Utg   = (u16*)alloc(nchunks * 4096 * 2);
  u16*   Stg   = (u16*)alloc(nchunks * 4096 * 2);
  float* cbuf  = (float*)alloc(nchunks * 64 * 4);
  u16*   ktg   = (u16*)alloc((size_t)BATCH * NHEADS * NCHUNK * 4096 * 2);
  const size_t need = (size_t)(p - (char*)d_ws);
  const bool use_chunked = (ws_size >= need);

  zero_kernel<<<dim3(NTOK * DMODEL / 4 / 256), 256, 0, stream>>>((float4*)coreb);

  cast_h_kernel<<<dim3(big / 4 / 256), 256, 0, stream>>>((const float4*)h, (ushort4*)hb);
  dim3 tg(16, 16);
  castT_kernel<<<tg, 256, 0, stream>>>(Wq, wtq);
  castT_kernel<<<tg, 256, 0, stream>>>(Wk, wtk);
  castT_kernel<<<tg, 256, 0, stream>>>(Wv, wtv);
  castT_kernel<<<tg, 256, 0, stream>>>(Wg, wtg);
  castT_kernel<<<tg, 256, 0, stream>>>(Wo, wto);

  router_kernel<<<dim3(NTOK), 64, 0, stream>>>(h, Wb, Wa, Wgate, A_log, dt_bias,
                                               betab, gbuf, wbuf);

  dim3 gg(NTOK / 128, DMODEL / 64);
  gemm_mfma<2><<<gg, 128, 0, stream>>>(hb, wtq, qb);
  gemm_mfma<2><<<gg, 128, 0, stream>>>(hb, wtk, kb);
  gemm_mfma<1><<<gg, 128, 0, stream>>>(hb, wtv, vb);
  gemm_mfma<1><<<gg, 128, 0, stream>>>(hb, wtg, gateb);

  if (use_chunked) {
    kT_kernel<<<dim3(NCHUNK, BATCH, NHEADS), 256, 0, stream>>>(kb, ktg);
    chunk_phase1<<<dim3(NCHUNK, NEXP * BATCH, NHEADS), 256, 0, stream>>>(
        kb, vb, betab, gbuf, wbuf, U0buf, Wbuf_, cbuf);
    chunk_phase2<<<dim3(NEXP * BATCH, NHEADS, 2), 256, 0, stream>>>(
        cbuf, U0buf, Wbuf_, ktg, Utg, Stg);
    chunk_phase3<<<dim3(NCHUNK, NEXP * BATCH, NHEADS), 256, 0, stream>>>(
        qb, kb, cbuf, Utg, Stg, wbuf, coreb);
  } else {
    compact_kernel<<<dim3(NEXP, BATCH), 64, 0, stream>>>(wbuf, tidx, tcnt);
    scan_kernel<<<dim3(NEXP * 2, BATCH, NHEADS), 64, 0, stream>>>(
        qb, kb, vb, betab, gbuf, wbuf, tidx, tcnt, coreb);
  }

  rmsnorm_kernel<<<dim3(NTOK), 512, 0, stream>>>(coreb, gateb, wn, nb);

  gemm_mfma<0><<<gg, 128, 0, stream>>>(nb, wto, out);
}

// Round 12
// 264.192 us; speedup vs baseline: 12.6804x; 1.1678x over previous
//
#include <hip/hip_runtime.h>
#include <math.h>

#define DMODEL 512
#define NHEADS 8
#define NEXP 4
#define SEQ 1024
#define BATCH 4
#define NTOK 4096  // BATCH * SEQ
#define NCHUNK 16  // SEQ / 64

typedef float v2f __attribute__((ext_vector_type(2)));
typedef float v4f __attribute__((ext_vector_type(4)));
typedef short bf16x8 __attribute__((ext_vector_type(8)));
typedef float f32x4 __attribute__((ext_vector_type(4)));
typedef unsigned short u16;

__device__ __forceinline__ float dev_sigmoid(float x) { return 1.0f / (1.0f + expf(-x)); }
__device__ __forceinline__ float dev_silu(float x) { return x / (1.0f + expf(-x)); }
__device__ __forceinline__ float dev_softplus(float x) {
  return x > 0.0f ? x + log1pf(expf(-x)) : log1pf(expf(x));
}
// fp32 -> bf16 bits, round-to-nearest-even
__device__ __forceinline__ u16 f2b(float f) {
  unsigned int u = __float_as_uint(f);
  unsigned int r = (u + 0x7fffu + ((u >> 16) & 1u)) >> 16;
  return (u16)r;
}
__device__ __forceinline__ ushort4 f2b4(float4 v) {
  ushort4 o; o.x = f2b(v.x); o.y = f2b(v.y); o.z = f2b(v.z); o.w = f2b(v.w); return o;
}

// bf16 LDS row stride in shorts: 72 (144 B) -> 16B-aligned fragments
#define BST 72

// ======== fused prep kernel: zero(coreb) | cast_h | castT x5 | router ========
// blockIdx.x segments: [0,2048) zero, [2048,4096) cast_h, [4096,5376) castT,
// [5376,6400) router (4 waves/block, 1 token/wave). All 256 threads.
#define SEG_ZERO 2048
#define SEG_CASTH 4096
#define SEG_CASTT 5376
#define SEG_TOTAL 6400
__global__ __launch_bounds__(256) void prep_kernel(
    const float* __restrict__ h, float* __restrict__ coreb, u16* __restrict__ hb,
    const float* __restrict__ Wq, const float* __restrict__ Wk,
    const float* __restrict__ Wv, const float* __restrict__ Wg,
    const float* __restrict__ Wo, u16* __restrict__ wtq, u16* __restrict__ wtk,
    u16* __restrict__ wtv, u16* __restrict__ wtg, u16* __restrict__ wto,
    const float* __restrict__ Wb, const float* __restrict__ Wa,
    const float* __restrict__ Wgate, const float* __restrict__ A_log,
    const float* __restrict__ dt_bias, float* __restrict__ beta_o,
    float* __restrict__ g_o, float* __restrict__ w_o) {
  const int bid = blockIdx.x;
  const int tid = threadIdx.x;
  if (bid < SEG_ZERO) {
    ((float4*)coreb)[(size_t)bid * 256 + tid] = make_float4(0.f, 0.f, 0.f, 0.f);
  } else if (bid < SEG_CASTH) {
    const size_t i = (size_t)(bid - SEG_ZERO) * 256 + tid;
    ((ushort4*)hb)[i] = f2b4(((const float4*)h)[i]);
  } else if (bid < SEG_CASTT) {
    const int local = bid - SEG_CASTH;
    const int which = local >> 8, rem = local & 255;
    const float* in; u16* outp;
    if (which == 0)      { in = Wq; outp = wtq; }
    else if (which == 1) { in = Wk; outp = wtk; }
    else if (which == 2) { in = Wv; outp = wtv; }
    else if (which == 3) { in = Wg; outp = wtg; }
    else                 { in = Wo; outp = wto; }
    __shared__ float tile[32][33];
    const int bx = (rem & 15) * 32, by = (rem >> 4) * 32;
    const int c = tid & 31, r0 = tid >> 5;
#pragma unroll
    for (int r = r0; r < 32; r += 8) tile[r][c] = in[(size_t)(bx + r) * DMODEL + by + c];
    __syncthreads();
#pragma unroll
    for (int r = r0; r < 32; r += 8)
      outp[(size_t)(by + r) * DMODEL + bx + c] = f2b(tile[c][r]);
  } else {
    // router: token t = (bid-SEG_CASTT)*4 + wave
    const int t = (bid - SEG_CASTT) * 4 + (tid >> 6);
    const int lane = tid & 63;
    float hv[8];
#pragma unroll
    for (int j = 0; j < 8; ++j) hv[j] = h[(size_t)t * DMODEL + j * 64 + lane];
    float db[8], da[8], dg[4];
#pragma unroll
    for (int c = 0; c < 8; ++c) {
      float s1 = 0.f, s2 = 0.f;
#pragma unroll
      for (int j = 0; j < 8; ++j) {
        int row = j * 64 + lane;
        s1 += hv[j] * Wb[row * NHEADS + c];
        s2 += hv[j] * Wa[row * NHEADS + c];
      }
#pragma unroll
      for (int off = 1; off < 64; off <<= 1) {
        s1 += __shfl_xor(s1, off);
        s2 += __shfl_xor(s2, off);
      }
      db[c] = s1; da[c] = s2;
    }
#pragma unroll
    for (int c = 0; c < 4; ++c) {
      float s = 0.f;
#pragma unroll
      for (int j = 0; j < 8; ++j) s += hv[j] * Wgate[(j * 64 + lane) * NEXP + c];
#pragma unroll
      for (int off = 1; off < 64; off <<= 1) s += __shfl_xor(s, off);
      dg[c] = s;
    }
    if (lane == 0) {
#pragma unroll
      for (int c = 0; c < 8; ++c) {
        beta_o[t * NHEADS + c] = dev_sigmoid(db[c]);
        g_o[t * NHEADS + c] = -expf(A_log[c]) * dev_softplus(da[c] + dt_bias[c]);
      }
      float mx = fmaxf(fmaxf(dg[0], dg[1]), fmaxf(dg[2], dg[3]));
      float p[4]; float sum = 0.f;
#pragma unroll
      for (int c = 0; c < 4; ++c) { p[c] = expf(dg[c] - mx); sum += p[c]; }
#pragma unroll
      for (int c = 0; c < 4; ++c) p[c] /= sum;
      float v1 = -1e30f; int i1 = 0;
#pragma unroll
      for (int c = 0; c < 4; ++c) { if (p[c] > v1) { v1 = p[c]; i1 = c; } }
      float v2 = -1e30f; int i2 = -1;
#pragma unroll
      for (int c = 0; c < 4; ++c) { if (c != i1 && p[c] > v2) { v2 = p[c]; i2 = c; } }
      float s2v = v1 + v2;
#pragma unroll
      for (int c = 0; c < 4; ++c) {
        float wv = 0.f;
        if (c == i1) wv = v1 / s2v;
        else if (c == i2) wv = v2 / s2v;
        w_o[t * NEXP + c] = wv;
      }
    }
  }
}

// ---------------- per-(b,h,chunk) K^T bf16 tiles: ktg[tile][dk][t] ----------------
__global__ __launch_bounds__(256) void kT_kernel(const float* __restrict__ kb,
                                                 u16* __restrict__ ktg) {
  const int ch = blockIdx.x, b = blockIdx.y, hh = blockIdx.z;
  const int tile = (b * NHEADS + hh) * NCHUNK + ch;
  const int tid = threadIdx.x;
  __shared__ float tl[64][65];
  {
    const int t = tid >> 2, d0 = (tid & 3) * 16;
    const float* krow = kb + (size_t)(b * SEQ + ch * 64 + t) * DMODEL + hh * 64 + d0;
#pragma unroll
    for (int j = 0; j < 4; ++j) {
      float4 v = *(const float4*)(krow + j * 4);
      tl[t][d0 + j * 4 + 0] = v.x; tl[t][d0 + j * 4 + 1] = v.y;
      tl[t][d0 + j * 4 + 2] = v.z; tl[t][d0 + j * 4 + 3] = v.w;
    }
  }
  __syncthreads();
  {
    const int t = tid & 63, dk0 = (tid >> 6) * 16;
    u16* obase = ktg + (size_t)tile * 4096 + t;
#pragma unroll
    for (int j = 0; j < 16; ++j)
      obase[(size_t)(dk0 + j) * 64] = f2b(tl[t][dk0 + j]);
  }
}

// ---------------- routed-token compaction (fallback path) ----------------
__global__ __launch_bounds__(64) void compact_kernel(
    const float* __restrict__ wbuf, int* __restrict__ tidx, int* __restrict__ tcnt) {
  const int e = blockIdx.x, b = blockIdx.y;
  const int lane = threadIdx.x;
  int* out = tidx + (e * BATCH + b) * SEQ;
  int cnt = 0;
  for (int g0 = 0; g0 < SEQ; g0 += 64) {
    const int l = g0 + lane;
    const float w = wbuf[(b * SEQ + l) * NEXP + e];
    const unsigned long long m = __ballot(w > 0.f);
    const int pos = __popcll(m & ((1ull << lane) - 1ull));
    if (w > 0.f) out[cnt + pos] = l;
    cnt += __popcll(m);
  }
  if (lane == 0) tcnt[e * BATCH + b] = cnt;
}

// ---------------- bf16 MFMA GEMM core (proven R5), runtime mode ----------------
#define LDA 56
__device__ __forceinline__ void gemm_body(
    const u16* __restrict__ A, const u16* __restrict__ Bt,
    float* __restrict__ C, int m0, int n0, int mode) {
  constexpr int K = DMODEL, N = DMODEL;
  __shared__ __align__(16) short As[128 * LDA];
  __shared__ __align__(16) short Bs[64 * LDA];
  const int tid = threadIdx.x;
  const int wave = tid >> 6, lane = tid & 63;
  const int quad = lane >> 4, l16 = lane & 15;
  const int bn = tid >> 1, bk = (tid & 1) * 16;
  const u16* Abase = A + (size_t)(m0 + tid) * K;
  const u16* Bbase = Bt + (size_t)(n0 + bn) * K + bk;

  f32x4 acc[4][4];
#pragma unroll
  for (int i = 0; i < 4; ++i)
#pragma unroll
    for (int j = 0; j < 4; ++j) acc[i][j] = (f32x4){0.f, 0.f, 0.f, 0.f};

  int4 pa0, pa1, pa2, pa3, pb0, pb1;
  {
    const u16* p = Abase;
    pa0 = *(const int4*)p; pa1 = *(const int4*)(p + 8);
    pa2 = *(const int4*)(p + 16); pa3 = *(const int4*)(p + 24);
    const u16* q = Bbase;
    pb0 = *(const int4*)q; pb1 = *(const int4*)(q + 8);
  }
  for (int kk = 0; kk < K; kk += 32) {
    __syncthreads();
    *(int4*)&As[tid * LDA + 0] = pa0;
    *(int4*)&As[tid * LDA + 8] = pa1;
    *(int4*)&As[tid * LDA + 16] = pa2;
    *(int4*)&As[tid * LDA + 24] = pa3;
    *(int4*)&Bs[bn * LDA + bk] = pb0;
    *(int4*)&Bs[bn * LDA + bk + 8] = pb1;
    __syncthreads();
    if (kk + 32 < K) {
      const u16* p = Abase + kk + 32;
      pa0 = *(const int4*)p; pa1 = *(const int4*)(p + 8);
      pa2 = *(const int4*)(p + 16); pa3 = *(const int4*)(p + 24);
      const u16* q = Bbase + kk + 32;
      pb0 = *(const int4*)q; pb1 = *(const int4*)(q + 8);
    }
    bf16x8 af[4], bfg[4];
#pragma unroll
    for (int mi = 0; mi < 4; ++mi)
      af[mi] = *(const bf16x8*)&As[(wave * 64 + mi * 16 + l16) * LDA + quad * 8];
#pragma unroll
    for (int ni = 0; ni < 4; ++ni)
      bfg[ni] = *(const bf16x8*)&Bs[(ni * 16 + l16) * LDA + quad * 8];
#pragma unroll
    for (int mi = 0; mi < 4; ++mi)
#pragma unroll
      for (int ni = 0; ni < 4; ++ni)
        acc[mi][ni] = __builtin_amdgcn_mfma_f32_16x16x32_bf16(af[mi], bfg[ni],
                                                              acc[mi][ni], 0, 0, 0);
  }
#pragma unroll
  for (int mi = 0; mi < 4; ++mi) {
#pragma unroll
    for (int r = 0; r < 4; ++r) {
      const int row = m0 + wave * 64 + mi * 16 + quad * 4 + r;
      float s[4];
#pragma unroll
      for (int ni = 0; ni < 4; ++ni) {
        float x = acc[mi][ni][r];
        s[ni] = (mode == 0) ? x : dev_silu(x);
      }
      if (mode == 2) {
        float ss = s[0] * s[0] + s[1] * s[1] + s[2] * s[2] + s[3] * s[3];
        ss += __shfl_xor(ss, 1);
        ss += __shfl_xor(ss, 2);
        ss += __shfl_xor(ss, 4);
        ss += __shfl_xor(ss, 8);
        const float rn = 1.0f / sqrtf(ss + 1e-6f);
#pragma unroll
        for (int ni = 0; ni < 4; ++ni) s[ni] *= rn;
      }
#pragma unroll
      for (int ni = 0; ni < 4; ++ni)
        C[(size_t)row * N + n0 + ni * 16 + l16] = s[ni];
    }
  }
}

// batched 4-way projection GEMM: z selects weight/output/mode
__global__ __launch_bounds__(128) void gemm4_kernel(
    const u16* __restrict__ A,
    const u16* __restrict__ B0, const u16* __restrict__ B1,
    const u16* __restrict__ B2, const u16* __restrict__ B3,
    float* __restrict__ C0, float* __restrict__ C1,
    float* __restrict__ C2, float* __restrict__ C3) {
  const int z = blockIdx.z;
  const u16* Bt; float* C; int mode;
  if (z == 0)      { Bt = B0; C = C0; mode = 2; }
  else if (z == 1) { Bt = B1; C = C1; mode = 2; }
  else if (z == 2) { Bt = B2; C = C2; mode = 1; }
  else             { Bt = B3; C = C3; mode = 1; }
  gemm_body(A, Bt, C, blockIdx.x * 128, blockIdx.y * 64, mode);
}

__global__ __launch_bounds__(128) void gemm_out_kernel(
    const u16* __restrict__ A, const u16* __restrict__ Bt, float* __restrict__ C) {
  gemm_body(A, Bt, C, blockIdx.x * 128, blockIdx.y * 64, 0);
}

// ================= CHUNKED GATED DELTA RULE (MFMA) =================

// ---- phase 1: blocked-panel forward substitution (proven R10) ----
__global__ __launch_bounds__(256) void chunk_phase1(
    const float* __restrict__ kb, const float* __restrict__ vb,
    const float* __restrict__ betab, const float* __restrict__ gbuf,
    const float* __restrict__ wbuf, float* __restrict__ U0buf,
    float* __restrict__ Wbuf, float* __restrict__ cbuf) {
  const int ch = blockIdx.x, eb = blockIdx.y, hh = blockIdx.z;
  const int e = eb >> 2, b = eb & 3;
  const int chunkid = (eb * NHEADS + hh) * NCHUNK + ch;
  const size_t base = (size_t)chunkid * 4096;
  const int tid = threadIdx.x;
  const int wave = tid >> 6, lane = tid & 63;
  const int quad = lane >> 4, l16 = lane & 15;

  __shared__ __align__(16) short Kb[64 * BST];
  __shared__ __align__(16) short Tb[64 * BST];   // bf16 below-panel T, zeroed elsewhere
  __shared__ float Td[4][16][17];                // fp32 diagonal blocks
  __shared__ __align__(16) short Xt[128 * BST];  // bf16 X^T [c][s]
  __shared__ float Zl[16][136];                  // fp32 panel Z
  __shared__ float cc[64], bb[64], exs[64];

  if (tid < 64) {
    const int gt = b * SEQ + ch * 64 + tid;
    const float w = wbuf[gt * NEXP + e];
    float gv = 0.f, bv = 0.f;
    if (w > 0.f) { gv = gbuf[gt * NHEADS + hh]; bv = betab[gt * NHEADS + hh]; }
    float cum = gv;
#pragma unroll
    for (int off = 1; off < 64; off <<= 1) {
      float o = __shfl_up(cum, off);
      if (tid >= off) cum += o;
    }
    cc[tid] = cum; exs[tid] = expf(cum); bb[tid] = bv;
    cbuf[(size_t)chunkid * 64 + tid] = cum;
  }
  // zero the MFMA-visible k<64 region of Tb AND Xt (0 x NaN = NaN in MFMA)
#pragma unroll
  for (int i = tid; i < 64 * 32; i += 256)
    ((int*)&Tb[(i >> 5) * BST])[i & 31] = 0;
#pragma unroll
  for (int i = tid; i < 128 * 32; i += 256)
    ((int*)&Xt[(i >> 5) * BST])[i & 31] = 0;
  {
    const int t = tid >> 2, d0 = (tid & 3) * 16;
    const float* krow = kb + (size_t)(b * SEQ + ch * 64 + t) * DMODEL + hh * 64 + d0;
#pragma unroll
    for (int j = 0; j < 4; ++j)
      *(ushort4*)&Kb[t * BST + d0 + j * 4] = f2b4(*(const float4*)(krow + j * 4));
  }
  __syncthreads();
  // lower-triangular bands of K K^T -> Tb (below panel) / Td (diag panel)
  for (int ni = 0; ni <= wave; ++ni) {
    f32x4 acc = (f32x4){0.f, 0.f, 0.f, 0.f};
#pragma unroll
    for (int ks = 0; ks < 2; ++ks) {
      bf16x8 af = *(const bf16x8*)&Kb[(wave * 16 + l16) * BST + ks * 32 + quad * 8];
      bf16x8 bfr = *(const bf16x8*)&Kb[(ni * 16 + l16) * BST + ks * 32 + quad * 8];
      acc = __builtin_amdgcn_mfma_f32_16x16x32_bf16(af, bfr, acc, 0, 0, 0);
    }
#pragma unroll
    for (int r = 0; r < 4; ++r) {
      const int t = wave * 16 + quad * 4 + r, s = ni * 16 + l16;
      if (s < t) {
        const float val = bb[t] * expf(cc[t] - cc[s]) * acc[r];
        if (ni == wave) Td[wave][t & 15][s & 15] = val;
        else Tb[t * BST + s] = f2b(val);
      }
    }
  }
  __syncthreads();

  const bool solver = tid < 128;
  const bool isV = tid < 64;
  const int col = tid & 63;
  const float* src = isV ? vb : kb;
  const size_t srow = (size_t)(b * SEQ + ch * 64) * DMODEL + hh * 64 + col;
  float u[16];

#pragma unroll
  for (int p = 0; p < 4; ++p) {
    if (p > 0) {
      const int nch = (p + 1) >> 1;
      f32x4 a0 = (f32x4){0.f, 0.f, 0.f, 0.f};
      f32x4 a1 = (f32x4){0.f, 0.f, 0.f, 0.f};
      for (int ks = 0; ks < nch; ++ks) {
        bf16x8 af = *(const bf16x8*)&Tb[(p * 16 + l16) * BST + ks * 32 + quad * 8];
        bf16x8 b0 = *(const bf16x8*)&Xt[(wave * 32 + l16) * BST + ks * 32 + quad * 8];
        bf16x8 b1 = *(const bf16x8*)&Xt[(wave * 32 + 16 + l16) * BST + ks * 32 + quad * 8];
        a0 = __builtin_amdgcn_mfma_f32_16x16x32_bf16(af, b0, a0, 0, 0, 0);
        a1 = __builtin_amdgcn_mfma_f32_16x16x32_bf16(af, b1, a1, 0, 0, 0);
      }
#pragma unroll
      for (int r = 0; r < 4; ++r) {
        Zl[quad * 4 + r][wave * 32 + l16] = a0[r];
        Zl[quad * 4 + r][wave * 32 + 16 + l16] = a1[r];
      }
      __syncthreads();
    }
    if (solver) {
#pragma unroll
      for (int i = 0; i < 16; ++i) {
        const int t = p * 16 + i;
        const float R = src[srow + (size_t)t * DMODEL];
        const float sc = isV ? bb[t] : bb[t] * exs[t];
        float v0 = sc * R - ((p > 0) ? Zl[i][tid] : 0.f);
        float v1 = 0.f;
#pragma unroll
        for (int r = 0; r < i; ++r) {
          if (r & 1) v1 = fmaf(-Td[p][i][r], u[r], v1);
          else       v0 = fmaf(-Td[p][i][r], u[r], v0);
        }
        u[i] = v0 + v1;
      }
#pragma unroll
      for (int j = 0; j < 4; ++j) {
        ushort4 o;
        o.x = f2b(u[j * 4 + 0]); o.y = f2b(u[j * 4 + 1]);
        o.z = f2b(u[j * 4 + 2]); o.w = f2b(u[j * 4 + 3]);
        *(ushort4*)&Xt[tid * BST + p * 16 + j * 4] = o;
      }
      if (isV) {
        float* dst = U0buf + base + (size_t)col * 64 + p * 16;
#pragma unroll
        for (int j = 0; j < 4; ++j)
          *(float4*)(dst + j * 4) = make_float4(u[j * 4], u[j * 4 + 1], u[j * 4 + 2], u[j * 4 + 3]);
      } else {
        float* dst = Wbuf + base + col;
#pragma unroll
        for (int i = 0; i < 16; ++i) dst[(size_t)(p * 16 + i) * 64] = u[i];
      }
    }
    __syncthreads();
  }
}

// ---- phase 2: serial chunk chain, dv-split (grid z=2) + register prefetch ----
__global__ __launch_bounds__(256) void chunk_phase2(
    const float* __restrict__ cbuf, const float* __restrict__ U0buf,
    const float* __restrict__ Wbuf, const u16* __restrict__ ktg,
    u16* __restrict__ Utg, u16* __restrict__ Stg) {
  const int eb = blockIdx.x, hh = blockIdx.y, dvh = blockIdx.z;
  const int b = eb & 3;
  const int ebh = eb * NHEADS + hh;
  const int tid = threadIdx.x;
  const int wave = tid >> 6, lane = tid & 63;
  const int quad = lane >> 4, l16 = lane & 15;
  const int mi = wave >> 1;           // local dv tile (0..1)
  const int nb0 = (wave & 1) * 2;     // ni base (0 or 2)
  const int dvl0 = mi * 16 + quad * 4;  // local dv row base (+r)
  const int dvg0 = dvh * 32;          // global dv offset

  __shared__ float Sf[32][68];                    // fp32 S^T half [dvl][dk]
  __shared__ __align__(16) short Sbt[32 * BST];   // bf16 S^T half
  __shared__ __align__(16) short Wb[64 * BST];    // bf16 W [t][dk]
  __shared__ __align__(16) short Ktb[64 * BST];   // bf16 K^T [dk][t]
  __shared__ __align__(16) short UextT[32 * BST]; // bf16 (U*ext)^T half [dvl][t]
  __shared__ float ext[64];
  __shared__ float gam_sh;

  for (int i = tid; i < 32 * 68; i += 256) (&Sf[0][0])[i] = 0.f;

  const int ktile0 = (b * NHEADS + hh) * NCHUNK;
  const int sr = tid >> 2, sc = (tid & 3) * 16;  // staging row/col

  float4 wreg[4];
  int4 ktreg[2];
  float u0cur[2][4], u0nxt[2][4];
  float cvreg;

#define P2_PREF(CH, WD, KD, UD, CV)                                          \
  do {                                                                       \
    const int ch_ = (CH) < NCHUNK ? (CH) : (NCHUNK - 1);                     \
    const size_t b_ = (size_t)(ebh * NCHUNK + ch_) * 4096;                   \
    const size_t kb_ = (size_t)(ktile0 + ch_) * 4096;                        \
    const float* wr_ = Wbuf + b_ + (size_t)sr * 64 + sc;                     \
    WD[0] = *(const float4*)(wr_ + 0);  WD[1] = *(const float4*)(wr_ + 4);   \
    WD[2] = *(const float4*)(wr_ + 8);  WD[3] = *(const float4*)(wr_ + 12);  \
    const u16* kr_ = ktg + kb_ + (size_t)sr * 64 + sc;                       \
    KD[0] = *(const int4*)kr_; KD[1] = *(const int4*)(kr_ + 8);              \
    _Pragma("unroll")                                                        \
    for (int ni_ = 0; ni_ < 2; ++ni_)                                        \
      _Pragma("unroll")                                                      \
      for (int r_ = 0; r_ < 4; ++r_)                                         \
        UD[ni_][r_] = U0buf[b_ + (size_t)(dvg0 + dvl0 + r_) * 64 +           \
                            (nb0 + ni_) * 16 + l16];                         \
    CV = cbuf[(size_t)(ebh * NCHUNK + ch_) * 64 + (tid & 63)];               \
  } while (0)

  P2_PREF(0, wreg, ktreg, u0cur, cvreg);
  __syncthreads();  // Sf zero-init visible

  for (int ch = 0; ch < NCHUNK; ++ch) {
    const size_t base = (size_t)(ebh * NCHUNK + ch) * 4096;
    if (tid < 64) {
      const float c63 = __shfl(cvreg, 63);
      ext[tid] = expf(c63 - cvreg);
      if (tid == 63) gam_sh = expf(cvreg);
    }
#pragma unroll
    for (int j = 0; j < 4; ++j)
      *(ushort4*)&Wb[sr * BST + sc + j * 4] = f2b4(wreg[j]);
    *(int4*)&Ktb[sr * BST + sc] = ktreg[0];
    *(int4*)&Ktb[sr * BST + sc + 8] = ktreg[1];
    for (int i = tid; i < 512; i += 256) {
      const int dv = i >> 4, d4 = (i & 15) * 4;
      const float* s4 = &Sf[dv][d4];
      ushort4 o; o.x = f2b(s4[0]); o.y = f2b(s4[1]); o.z = f2b(s4[2]); o.w = f2b(s4[3]);
      *(ushort4*)&Sbt[dv * BST + d4] = o;
    }
    __syncthreads();  // barrier A: staging visible
    P2_PREF(ch + 1, wreg, ktreg, u0nxt, cvreg);
    for (int i = tid; i < 512; i += 256) {
      const int r = i >> 4, c4 = (i & 15) * 4;
      *(ushort4*)(Stg + base + (size_t)(dvg0 + r) * 64 + c4) = *(const ushort4*)&Sbt[r * BST + c4];
    }
#pragma unroll
    for (int ni = 0; ni < 2; ++ni) {
      f32x4 acc = (f32x4){0.f, 0.f, 0.f, 0.f};
#pragma unroll
      for (int ks = 0; ks < 2; ++ks) {
        bf16x8 af = *(const bf16x8*)&Sbt[(mi * 16 + l16) * BST + ks * 32 + quad * 8];
        bf16x8 bfr = *(const bf16x8*)&Wb[((nb0 + ni) * 16 + l16) * BST + ks * 32 + quad * 8];
        acc = __builtin_amdgcn_mfma_f32_16x16x32_bf16(af, bfr, acc, 0, 0, 0);
      }
#pragma unroll
      for (int r = 0; r < 4; ++r) {
        const int dvl = dvl0 + r, t = (nb0 + ni) * 16 + l16;
        const float uv = u0cur[ni][r] - acc[r];
        Utg[base + (size_t)(dvg0 + dvl) * 64 + t] = f2b(uv);
        UextT[dvl * BST + t] = f2b(uv * ext[t]);
      }
    }
    __syncthreads();  // barrier B: UextT visible
    const float g = gam_sh;
#pragma unroll
    for (int ni = 0; ni < 2; ++ni) {
      f32x4 acc = (f32x4){0.f, 0.f, 0.f, 0.f};
#pragma unroll
      for (int ks = 0; ks < 2; ++ks) {
        bf16x8 af = *(const bf16x8*)&UextT[(mi * 16 + l16) * BST + ks * 32 + quad * 8];
        bf16x8 bfr = *(const bf16x8*)&Ktb[((nb0 + ni) * 16 + l16) * BST + ks * 32 + quad * 8];
        acc = __builtin_amdgcn_mfma_f32_16x16x32_bf16(af, bfr, acc, 0, 0, 0);
      }
#pragma unroll
      for (int r = 0; r < 4; ++r) {
        const int dvl = dvl0 + r, dk = (nb0 + ni) * 16 + l16;
        Sf[dvl][dk] = g * Sf[dvl][dk] + acc[r];
      }
    }
#pragma unroll
    for (int ni = 0; ni < 2; ++ni)
#pragma unroll
      for (int r = 0; r < 4; ++r) u0cur[ni][r] = u0nxt[ni][r];
    __syncthreads();  // barrier C: Sf update + LDS reuse safe
  }
#undef P2_PREF
}

// ---- phase 3: parallel (chunk, eb, h). P = QK^T; O = e^c QS + P U; combine ----
__global__ __launch_bounds__(256) void chunk_phase3(
    const float* __restrict__ qb, const float* __restrict__ kb,
    const float* __restrict__ cbuf, const u16* __restrict__ Utg,
    const u16* __restrict__ Stg, const float* __restrict__ wbuf,
    float* __restrict__ coreb) {
  const int ch = blockIdx.x, eb = blockIdx.y, hh = blockIdx.z;
  const int e = eb >> 2, b = eb & 3;
  const int chunkid = (eb * NHEADS + hh) * NCHUNK + ch;
  const size_t base = (size_t)chunkid * 4096;
  const int tid = threadIdx.x;
  const int wave = tid >> 6, lane = tid & 63;
  const int quad = lane >> 4, l16 = lane & 15;

  __shared__ __align__(16) short Qb[64 * BST];
  __shared__ __align__(16) short Kb3[64 * BST];
  __shared__ __align__(16) short Pb[64 * BST];
  __shared__ __align__(16) short Stb[64 * BST];
  __shared__ __align__(16) short Utb[64 * BST];
  __shared__ float cc3[64];

  if (tid < 64) cc3[tid] = cbuf[(size_t)chunkid * 64 + tid];
  {
    const int t = tid >> 2, d0 = (tid & 3) * 16;
    const size_t ro = (size_t)(b * SEQ + ch * 64 + t) * DMODEL + hh * 64 + d0;
#pragma unroll
    for (int j = 0; j < 4; ++j) {
      *(ushort4*)&Qb[t * BST + d0 + j * 4] = f2b4(*(const float4*)(qb + ro + j * 4));
      *(ushort4*)&Kb3[t * BST + d0 + j * 4] = f2b4(*(const float4*)(kb + ro + j * 4));
    }
  }
  for (int i = tid; i < 1024; i += 256) {
    const int r = i >> 4, c4 = (i & 15) * 4;
    *(ushort4*)&Stb[r * BST + c4] = *(const ushort4*)(Stg + base + r * 64 + c4);
    *(ushort4*)&Utb[r * BST + c4] = *(const ushort4*)(Utg + base + r * 64 + c4);
  }
  __syncthreads();
  for (int ni = 0; ni < 4; ++ni) {
    f32x4 acc = (f32x4){0.f, 0.f, 0.f, 0.f};
#pragma unroll
    for (int ks = 0; ks < 2; ++ks) {
      bf16x8 af = *(const bf16x8*)&Qb[(wave * 16 + l16) * BST + ks * 32 + quad * 8];
      bf16x8 bfr = *(const bf16x8*)&Kb3[(ni * 16 + l16) * BST + ks * 32 + quad * 8];
      acc = __builtin_amdgcn_mfma_f32_16x16x32_bf16(af, bfr, acc, 0, 0, 0);
    }
#pragma unroll
    for (int r = 0; r < 4; ++r) {
      const int t = wave * 16 + quad * 4 + r, s = ni * 16 + l16;
      const float p = (s <= t) ? expf(cc3[t] - cc3[s]) * acc[r] : 0.f;
      Pb[t * BST + s] = f2b(p);
    }
  }
  __syncthreads();
  for (int ni = 0; ni < 4; ++ni) {
    f32x4 a1 = (f32x4){0.f, 0.f, 0.f, 0.f};
    f32x4 a2 = (f32x4){0.f, 0.f, 0.f, 0.f};
#pragma unroll
    for (int ks = 0; ks < 2; ++ks) {
      bf16x8 afq = *(const bf16x8*)&Qb[(wave * 16 + l16) * BST + ks * 32 + quad * 8];
      bf16x8 bfs = *(const bf16x8*)&Stb[(ni * 16 + l16) * BST + ks * 32 + quad * 8];
      a1 = __builtin_amdgcn_mfma_f32_16x16x32_bf16(afq, bfs, a1, 0, 0, 0);
      bf16x8 afp = *(const bf16x8*)&Pb[(wave * 16 + l16) * BST + ks * 32 + quad * 8];
      bf16x8 bfu = *(const bf16x8*)&Utb[(ni * 16 + l16) * BST + ks * 32 + quad * 8];
      a2 = __builtin_amdgcn_mfma_f32_16x16x32_bf16(afp, bfu, a2, 0, 0, 0);
    }
#pragma unroll
    for (int r = 0; r < 4; ++r) {
      const int t = wave * 16 + quad * 4 + r, dv = ni * 16 + l16;
      const int gt = b * SEQ + ch * 64 + t;
      const float wv = wbuf[gt * NEXP + e];
      if (wv > 0.f) {
        const float o = 0.125f * (expf(cc3[t]) * a1[r] + a2[r]);
        atomicAdd(&coreb[(size_t)gt * DMODEL + hh * 64 + dv], wv * o);
      }
    }
  }
}

// ---------------- fallback serial scan (R3-proven) ----------------
__global__ __launch_bounds__(64) void scan_kernel(
    const float* __restrict__ qb, const float* __restrict__ kb,
    const float* __restrict__ vb, const float* __restrict__ betab,
    const float* __restrict__ gbuf, const float* __restrict__ wbuf,
    const int* __restrict__ tidx, const int* __restrict__ tcnt,
    float* __restrict__ coreb) {
  const int vhalf = blockIdx.x & 1, e = blockIdx.x >> 1;
  const int b = blockIdx.y, hh = blockIdx.z;
  const int lane = threadIdx.x;
  const int kh = lane >> 5;
  const int vi = lane & 31;
  const int cv = vhalf * 32 + vi;
  const int* idx = tidx + (e * BATCH + b) * SEQ;
  const int n = tcnt[e * BATCH + b];
  if (n == 0) return;
  const int nm1 = n - 1;
  __shared__ __align__(16) float lk[4][64];
  __shared__ __align__(16) float lq[4][64];
  __shared__ int lidx[SEQ];
  for (int i = lane; i < SEQ; i += 64) lidx[i] = idx[i < n ? i : nm1];
  __syncthreads();
  v2f S2[16];
#pragma unroll
  for (int j = 0; j < 16; ++j) S2[j] = (v2f){0.f, 0.f};
  float kf[4], qf[4], vf[4], gf[4], bf[4], wf[4], egr[4];
  int tcur[4], tok4[4];
#define PREF(SLOT, TK)                                          \
  do {                                                          \
    const int tn_ = b * SEQ + (TK);                             \
    const size_t kq_ = (size_t)tn_ * DMODEL + hh * 64 + lane;   \
    kf[SLOT] = kb[kq_];                                         \
    qf[SLOT] = qb[kq_];                                         \
    vf[SLOT] = vb[(size_t)tn_ * DMODEL + hh * 64 + cv];         \
    gf[SLOT] = gbuf[tn_ * NHEADS + hh];                         \
    bf[SLOT] = betab[tn_ * NHEADS + hh];                        \
    wf[SLOT] = wbuf[tn_ * NEXP + e];                            \
    tcur[SLOT] = tn_;                                           \
  } while (0)
  tok4[0] = lidx[0];
  tok4[1] = lidx[1 < n ? 1 : nm1];
  tok4[2] = lidx[2 < n ? 2 : nm1];
  tok4[3] = lidx[3 < n ? 3 : nm1];
  PREF(0, tok4[0]); PREF(1, tok4[1]); PREF(2, tok4[2]);
  lk[0][lane] = kf[0]; lq[0][lane] = qf[0];
  egr[0] = expf(gf[0]);
  const int m = (n + 3) & ~3;
  for (int i = 0; i < m; i += 4) {
#pragma unroll
    for (int u = 0; u < 4; ++u) {
      const int s = i + u;
      const int sN = (u + 3) & 3;
      const int s1 = (u + 1) & 3;
      PREF(sN, tok4[sN]);
      int a4 = s + 4;
      a4 = a4 < nm1 ? a4 : nm1;
      tok4[u] = lidx[a4];
      __builtin_amdgcn_wave_barrier();
      lk[s1][lane] = kf[s1];
      lq[s1][lane] = qf[s1];
      __builtin_amdgcn_wave_barrier();
      egr[s1] = expf(gf[s1]);
      const v4f* lk4 = (const v4f*)&lk[u][kh * 32];
      const v4f* lq4 = (const v4f*)&lq[u][kh * 32];
      v2f myk[16];
      v2f c0 = (v2f){0.f, 0.f}, c1 = c0, c2 = c0, c3 = c0;
#pragma unroll
      for (int j = 0; j < 8; ++j) {
        const v4f k4 = lk4[j];
        const v2f klo = (v2f){k4.x, k4.y};
        const v2f khi = (v2f){k4.z, k4.w};
        myk[2 * j] = klo; myk[2 * j + 1] = khi;
        if (j & 1) {
          c2 = __builtin_elementwise_fma(klo, S2[2 * j], c2);
          c3 = __builtin_elementwise_fma(khi, S2[2 * j + 1], c3);
        } else {
          c0 = __builtin_elementwise_fma(klo, S2[2 * j], c0);
          c1 = __builtin_elementwise_fma(khi, S2[2 * j + 1], c1);
        }
      }
      const v2f cacc = (c0 + c1) + (c2 + c3);
      float cd = cacc.x + cacc.y;
      cd += __shfl_xor(cd, 32);
      const float egc = egr[u];
      const float delta = (vf[u] - egc * cd) * bf[u];
      const v2f d2 = (v2f){delta, delta};
      const v2f eg2 = (v2f){egc, egc};
      v2f o0 = (v2f){0.f, 0.f}, o1 = o0, o2 = o0, o3 = o0;
#pragma unroll
      for (int j = 0; j < 8; ++j) {
        const v4f q4 = lq4[j];
        const v2f qlo = (v2f){q4.x, q4.y};
        const v2f qhi = (v2f){q4.z, q4.w};
        const v2f s0 = __builtin_elementwise_fma(S2[2 * j], eg2, myk[2 * j] * d2);
        const v2f s1v = __builtin_elementwise_fma(S2[2 * j + 1], eg2, myk[2 * j + 1] * d2);
        S2[2 * j] = s0; S2[2 * j + 1] = s1v;
        if (j & 1) {
          o2 = __builtin_elementwise_fma(qlo, s0, o2);
          o3 = __builtin_elementwise_fma(qhi, s1v, o3);
        } else {
          o0 = __builtin_elementwise_fma(qlo, s0, o0);
          o1 = __builtin_elementwise_fma(qhi, s1v, o1);
        }
      }
      const v2f oacc = (o0 + o1) + (o2 + o3);
      float o = oacc.x + oacc.y;
      o += __shfl_xor(o, 32);
      if (kh == 0 && s < n)
        atomicAdd(&coreb[(size_t)tcur[u] * DMODEL + hh * 64 + cv],
                  o * 0.125f * wf[u]);
    }
  }
#undef PREF
}

// ---------------- fused gated RMSNorm -> bf16 ----------------
__global__ __launch_bounds__(512) void rmsnorm_kernel(
    const float* __restrict__ coreb, const float* __restrict__ gateb,
    const float* __restrict__ wn, u16* __restrict__ outb) {
  const int t = blockIdx.x;
  const int tid = threadIdx.x;
  const int v = tid & 63;
  const float x = coreb[(size_t)t * DMODEL + tid];
  float ss = x * x;
#pragma unroll
  for (int off = 1; off < 64; off <<= 1) ss += __shfl_xor(ss, off);
  const float r = rsqrtf(ss * (1.0f / 64.0f) + 1e-5f);
  const float gt = gateb[(size_t)t * DMODEL + tid];
  outb[(size_t)t * DMODEL + tid] = f2b(x * r * wn[v] * gt);
}

extern "C" void kernel_launch(void* const* d_in, const int* in_sizes, int n_in,
                              void* d_out, int out_size, void* d_ws, size_t ws_size,
                              hipStream_t stream) {
  const float* h       = (const float*)d_in[0];
  const float* Wq      = (const float*)d_in[1];
  const float* Wgate   = (const float*)d_in[2];
  const float* Wk      = (const float*)d_in[3];
  const float* Wv      = (const float*)d_in[4];
  const float* Wb      = (const float*)d_in[5];
  const float* Wa      = (const float*)d_in[6];
  const float* A_log   = (const float*)d_in[7];
  const float* dt_bias = (const float*)d_in[8];
  const float* Wg      = (const float*)d_in[9];
  const float* wn      = (const float*)d_in[10];
  const float* Wo      = (const float*)d_in[11];
  float* out = (float*)d_out;

  char* p = (char*)d_ws;
  const size_t big = (size_t)NTOK * DMODEL;  // 2M elements
  auto alloc = [&](size_t bytes) { char* r = p; p += (bytes + 255) & ~255ull; return r; };
  float* qb    = (float*)alloc(big * 4);
  float* kb    = (float*)alloc(big * 4);
  float* vb    = (float*)alloc(big * 4);
  float* gateb = (float*)alloc(big * 4);
  float* coreb = (float*)alloc(big * 4);
  float* betab = (float*)alloc((size_t)NTOK * NHEADS * 4);
  float* gbuf  = (float*)alloc((size_t)NTOK * NHEADS * 4);
  float* wbuf  = (float*)alloc((size_t)NTOK * NEXP * 4);
  int*   tidx  = (int*)alloc((size_t)NEXP * BATCH * SEQ * 4);
  int*   tcnt  = (int*)alloc(256);
  u16*   hb    = (u16*)alloc(big * 2);
  u16*   nb    = (u16*)alloc(big * 2);
  u16*   wtq   = (u16*)alloc((size_t)DMODEL * DMODEL * 2);
  u16*   wtk   = (u16*)alloc((size_t)DMODEL * DMODEL * 2);
  u16*   wtv   = (u16*)alloc((size_t)DMODEL * DMODEL * 2);
  u16*   wtg   = (u16*)alloc((size_t)DMODEL * DMODEL * 2);
  u16*   wto   = (u16*)alloc((size_t)DMODEL * DMODEL * 2);
  // chunked-path extras
  const size_t nchunks = (size_t)NEXP * BATCH * NHEADS * NCHUNK;  // 2048
  float* U0buf = (float*)alloc(nchunks * 4096 * 4);
  float* Wbuf_ = (float*)alloc(nchunks * 4096 * 4);
  u16*   Utg   = (u16*)alloc(nchunks * 4096 * 2);
  u16*   Stg   = (u16*)alloc(nchunks * 4096 * 2);
  float* cbuf  = (float*)alloc(nchunks * 64 * 4);
  u16*   ktg   = (u16*)alloc((size_t)BATCH * NHEADS * NCHUNK * 4096 * 2);
  const size_t need = (size_t)(p - (char*)d_ws);
  const bool use_chunked = (ws_size >= need);

  // fused prep: zero coreb + cast h + transpose-cast 5 weights + router
  prep_kernel<<<dim3(SEG_TOTAL), 256, 0, stream>>>(
      h, coreb, hb, Wq, Wk, Wv, Wg, Wo, wtq, wtk, wtv, wtg, wto,
      Wb, Wa, Wgate, A_log, dt_bias, betab, gbuf, wbuf);

  // batched projection GEMMs (z: Wq/Wk -> l2norm+silu, Wv/Wg -> silu)
  gemm4_kernel<<<dim3(NTOK / 128, DMODEL / 64, 4), 128, 0, stream>>>(
      hb, wtq, wtk, wtv, wtg, qb, kb, vb, gateb);

  if (use_chunked) {
    kT_kernel<<<dim3(NCHUNK, BATCH, NHEADS), 256, 0, stream>>>(kb, ktg);
    chunk_phase1<<<dim3(NCHUNK, NEXP * BATCH, NHEADS), 256, 0, stream>>>(
        kb, vb, betab, gbuf, wbuf, U0buf, Wbuf_, cbuf);
    chunk_phase2<<<dim3(NEXP * BATCH, NHEADS, 2), 256, 0, stream>>>(
        cbuf, U0buf, Wbuf_, ktg, Utg, Stg);
    chunk_phase3<<<dim3(NCHUNK, NEXP * BATCH, NHEADS), 256, 0, stream>>>(
        qb, kb, cbuf, Utg, Stg, wbuf, coreb);
  } else {
    compact_kernel<<<dim3(NEXP, BATCH), 64, 0, stream>>>(wbuf, tidx, tcnt);
    scan_kernel<<<dim3(NEXP * 2, BATCH, NHEADS), 64, 0, stream>>>(
        qb, kb, vb, betab, gbuf, wbuf, tidx, tcnt, coreb);
  }

  rmsnorm_kernel<<<dim3(NTOK), 512, 0, stream>>>(coreb, gateb, wn, nb);

  gemm_out_kernel<<<dim3(NTOK / 128, DMODEL / 64), 128, 0, stream>>>(nb, wto, out);
}

// Round 13
// 259.469 us; speedup vs baseline: 12.9113x; 1.0182x over previous
//
#include <hip/hip_runtime.h>
#include <math.h>

#define DMODEL 512
#define NHEADS 8
#define NEXP 4
#define SEQ 1024
#define BATCH 4
#define NTOK 4096  // BATCH * SEQ
#define NCHUNK 16  // SEQ / 64

typedef float v2f __attribute__((ext_vector_type(2)));
typedef float v4f __attribute__((ext_vector_type(4)));
typedef short bf16x8 __attribute__((ext_vector_type(8)));
typedef float f32x4 __attribute__((ext_vector_type(4)));
typedef unsigned short u16;

__device__ __forceinline__ float dev_sigmoid(float x) { return 1.0f / (1.0f + expf(-x)); }
__device__ __forceinline__ float dev_silu(float x) { return x / (1.0f + expf(-x)); }
__device__ __forceinline__ float dev_softplus(float x) {
  return x > 0.0f ? x + log1pf(expf(-x)) : log1pf(expf(x));
}
// fp32 -> bf16 bits, round-to-nearest-even
__device__ __forceinline__ u16 f2b(float f) {
  unsigned int u = __float_as_uint(f);
  unsigned int r = (u + 0x7fffu + ((u >> 16) & 1u)) >> 16;
  return (u16)r;
}
__device__ __forceinline__ ushort4 f2b4(float4 v) {
  ushort4 o; o.x = f2b(v.x); o.y = f2b(v.y); o.z = f2b(v.z); o.w = f2b(v.w); return o;
}

// bf16 LDS row stride in shorts: 72 (144 B) -> 16B-aligned fragments
#define BST 72

// ======== fused prep kernel: zero(coreb) | cast_h | castT x5 | router ========
#define SEG_ZERO 2048
#define SEG_CASTH 4096
#define SEG_CASTT 5376
#define SEG_TOTAL 6400
__global__ __launch_bounds__(256) void prep_kernel(
    const float* __restrict__ h, float* __restrict__ coreb, u16* __restrict__ hb,
    const float* __restrict__ Wq, const float* __restrict__ Wk,
    const float* __restrict__ Wv, const float* __restrict__ Wg,
    const float* __restrict__ Wo, u16* __restrict__ wtq, u16* __restrict__ wtk,
    u16* __restrict__ wtv, u16* __restrict__ wtg, u16* __restrict__ wto,
    const float* __restrict__ Wb, const float* __restrict__ Wa,
    const float* __restrict__ Wgate, const float* __restrict__ A_log,
    const float* __restrict__ dt_bias, float* __restrict__ beta_o,
    float* __restrict__ g_o, float* __restrict__ w_o) {
  const int bid = blockIdx.x;
  const int tid = threadIdx.x;
  if (bid < SEG_ZERO) {
    ((float4*)coreb)[(size_t)bid * 256 + tid] = make_float4(0.f, 0.f, 0.f, 0.f);
  } else if (bid < SEG_CASTH) {
    const size_t i = (size_t)(bid - SEG_ZERO) * 256 + tid;
    ((ushort4*)hb)[i] = f2b4(((const float4*)h)[i]);
  } else if (bid < SEG_CASTT) {
    const int local = bid - SEG_CASTH;
    const int which = local >> 8, rem = local & 255;
    const float* in; u16* outp;
    if (which == 0)      { in = Wq; outp = wtq; }
    else if (which == 1) { in = Wk; outp = wtk; }
    else if (which == 2) { in = Wv; outp = wtv; }
    else if (which == 3) { in = Wg; outp = wtg; }
    else                 { in = Wo; outp = wto; }
    __shared__ float tile[32][33];
    const int bx = (rem & 15) * 32, by = (rem >> 4) * 32;
    const int c = tid & 31, r0 = tid >> 5;
#pragma unroll
    for (int r = r0; r < 32; r += 8) tile[r][c] = in[(size_t)(bx + r) * DMODEL + by + c];
    __syncthreads();
#pragma unroll
    for (int r = r0; r < 32; r += 8)
      outp[(size_t)(by + r) * DMODEL + bx + c] = f2b(tile[c][r]);
  } else {
    // router: token t = (bid-SEG_CASTT)*4 + wave
    const int t = (bid - SEG_CASTT) * 4 + (tid >> 6);
    const int lane = tid & 63;
    float hv[8];
#pragma unroll
    for (int j = 0; j < 8; ++j) hv[j] = h[(size_t)t * DMODEL + j * 64 + lane];
    float db[8], da[8], dg[4];
#pragma unroll
    for (int c = 0; c < 8; ++c) {
      float s1 = 0.f, s2 = 0.f;
#pragma unroll
      for (int j = 0; j < 8; ++j) {
        int row = j * 64 + lane;
        s1 += hv[j] * Wb[row * NHEADS + c];
        s2 += hv[j] * Wa[row * NHEADS + c];
      }
#pragma unroll
      for (int off = 1; off < 64; off <<= 1) {
        s1 += __shfl_xor(s1, off);
        s2 += __shfl_xor(s2, off);
      }
      db[c] = s1; da[c] = s2;
    }
#pragma unroll
    for (int c = 0; c < 4; ++c) {
      float s = 0.f;
#pragma unroll
      for (int j = 0; j < 8; ++j) s += hv[j] * Wgate[(j * 64 + lane) * NEXP + c];
#pragma unroll
      for (int off = 1; off < 64; off <<= 1) s += __shfl_xor(s, off);
      dg[c] = s;
    }
    if (lane == 0) {
#pragma unroll
      for (int c = 0; c < 8; ++c) {
        beta_o[t * NHEADS + c] = dev_sigmoid(db[c]);
        g_o[t * NHEADS + c] = -expf(A_log[c]) * dev_softplus(da[c] + dt_bias[c]);
      }
      float mx = fmaxf(fmaxf(dg[0], dg[1]), fmaxf(dg[2], dg[3]));
      float p[4]; float sum = 0.f;
#pragma unroll
      for (int c = 0; c < 4; ++c) { p[c] = expf(dg[c] - mx); sum += p[c]; }
#pragma unroll
      for (int c = 0; c < 4; ++c) p[c] /= sum;
      float v1 = -1e30f; int i1 = 0;
#pragma unroll
      for (int c = 0; c < 4; ++c) { if (p[c] > v1) { v1 = p[c]; i1 = c; } }
      float v2 = -1e30f; int i2 = -1;
#pragma unroll
      for (int c = 0; c < 4; ++c) { if (c != i1 && p[c] > v2) { v2 = p[c]; i2 = c; } }
      float s2v = v1 + v2;
#pragma unroll
      for (int c = 0; c < 4; ++c) {
        float wv = 0.f;
        if (c == i1) wv = v1 / s2v;
        else if (c == i2) wv = v2 / s2v;
        w_o[t * NEXP + c] = wv;
      }
    }
  }
}

// ---------------- routed-token compaction (fallback path) ----------------
__global__ __launch_bounds__(64) void compact_kernel(
    const float* __restrict__ wbuf, int* __restrict__ tidx, int* __restrict__ tcnt) {
  const int e = blockIdx.x, b = blockIdx.y;
  const int lane = threadIdx.x;
  int* out = tidx + (e * BATCH + b) * SEQ;
  int cnt = 0;
  for (int g0 = 0; g0 < SEQ; g0 += 64) {
    const int l = g0 + lane;
    const float w = wbuf[(b * SEQ + l) * NEXP + e];
    const unsigned long long m = __ballot(w > 0.f);
    const int pos = __popcll(m & ((1ull << lane) - 1ull));
    if (w > 0.f) out[cnt + pos] = l;
    cnt += __popcll(m);
  }
  if (lane == 0) tcnt[e * BATCH + b] = cnt;
}

// ---------------- bf16 MFMA GEMM core (proven R5), runtime mode ----------------
#define LDA 56
__device__ __forceinline__ void gemm_body(
    const u16* __restrict__ A, const u16* __restrict__ Bt,
    float* __restrict__ C, int m0, int n0, int mode) {
  constexpr int K = DMODEL, N = DMODEL;
  __shared__ __align__(16) short As[128 * LDA];
  __shared__ __align__(16) short Bs[64 * LDA];
  const int tid = threadIdx.x;
  const int wave = tid >> 6, lane = tid & 63;
  const int quad = lane >> 4, l16 = lane & 15;
  const int bn = tid >> 1, bk = (tid & 1) * 16;
  const u16* Abase = A + (size_t)(m0 + tid) * K;
  const u16* Bbase = Bt + (size_t)(n0 + bn) * K + bk;

  f32x4 acc[4][4];
#pragma unroll
  for (int i = 0; i < 4; ++i)
#pragma unroll
    for (int j = 0; j < 4; ++j) acc[i][j] = (f32x4){0.f, 0.f, 0.f, 0.f};

  int4 pa0, pa1, pa2, pa3, pb0, pb1;
  {
    const u16* p = Abase;
    pa0 = *(const int4*)p; pa1 = *(const int4*)(p + 8);
    pa2 = *(const int4*)(p + 16); pa3 = *(const int4*)(p + 24);
    const u16* q = Bbase;
    pb0 = *(const int4*)q; pb1 = *(const int4*)(q + 8);
  }
  for (int kk = 0; kk < K; kk += 32) {
    __syncthreads();
    *(int4*)&As[tid * LDA + 0] = pa0;
    *(int4*)&As[tid * LDA + 8] = pa1;
    *(int4*)&As[tid * LDA + 16] = pa2;
    *(int4*)&As[tid * LDA + 24] = pa3;
    *(int4*)&Bs[bn * LDA + bk] = pb0;
    *(int4*)&Bs[bn * LDA + bk + 8] = pb1;
    __syncthreads();
    if (kk + 32 < K) {
      const u16* p = Abase + kk + 32;
      pa0 = *(const int4*)p; pa1 = *(const int4*)(p + 8);
      pa2 = *(const int4*)(p + 16); pa3 = *(const int4*)(p + 24);
      const u16* q = Bbase + kk + 32;
      pb0 = *(const int4*)q; pb1 = *(const int4*)(q + 8);
    }
    bf16x8 af[4], bfg[4];
#pragma unroll
    for (int mi = 0; mi < 4; ++mi)
      af[mi] = *(const bf16x8*)&As[(wave * 64 + mi * 16 + l16) * LDA + quad * 8];
#pragma unroll
    for (int ni = 0; ni < 4; ++ni)
      bfg[ni] = *(const bf16x8*)&Bs[(ni * 16 + l16) * LDA + quad * 8];
#pragma unroll
    for (int mi = 0; mi < 4; ++mi)
#pragma unroll
      for (int ni = 0; ni < 4; ++ni)
        acc[mi][ni] = __builtin_amdgcn_mfma_f32_16x16x32_bf16(af[mi], bfg[ni],
                                                              acc[mi][ni], 0, 0, 0);
  }
#pragma unroll
  for (int mi = 0; mi < 4; ++mi) {
#pragma unroll
    for (int r = 0; r < 4; ++r) {
      const int row = m0 + wave * 64 + mi * 16 + quad * 4 + r;
      float s[4];
#pragma unroll
      for (int ni = 0; ni < 4; ++ni) {
        float x = acc[mi][ni][r];
        s[ni] = (mode == 0) ? x : dev_silu(x);
      }
      if (mode == 2) {
        float ss = s[0] * s[0] + s[1] * s[1] + s[2] * s[2] + s[3] * s[3];
        ss += __shfl_xor(ss, 1);
        ss += __shfl_xor(ss, 2);
        ss += __shfl_xor(ss, 4);
        ss += __shfl_xor(ss, 8);
        const float rn = 1.0f / sqrtf(ss + 1e-6f);
#pragma unroll
        for (int ni = 0; ni < 4; ++ni) s[ni] *= rn;
      }
#pragma unroll
      for (int ni = 0; ni < 4; ++ni)
        C[(size_t)row * N + n0 + ni * 16 + l16] = s[ni];
    }
  }
}

// batched 4-way projection GEMM: z selects weight/output/mode
__global__ __launch_bounds__(128) void gemm4_kernel(
    const u16* __restrict__ A,
    const u16* __restrict__ B0, const u16* __restrict__ B1,
    const u16* __restrict__ B2, const u16* __restrict__ B3,
    float* __restrict__ C0, float* __restrict__ C1,
    float* __restrict__ C2, float* __restrict__ C3) {
  const int z = blockIdx.z;
  const u16* Bt; float* C; int mode;
  if (z == 0)      { Bt = B0; C = C0; mode = 2; }
  else if (z == 1) { Bt = B1; C = C1; mode = 2; }
  else if (z == 2) { Bt = B2; C = C2; mode = 1; }
  else             { Bt = B3; C = C3; mode = 1; }
  gemm_body(A, Bt, C, blockIdx.x * 128, blockIdx.y * 64, mode);
}

__global__ __launch_bounds__(128) void gemm_out_kernel(
    const u16* __restrict__ A, const u16* __restrict__ Bt, float* __restrict__ C) {
  gemm_body(A, Bt, C, blockIdx.x * 128, blockIdx.y * 64, 0);
}

// ================= CHUNKED GATED DELTA RULE (MFMA) =================

// ---- phase 1: blocked-panel forward substitution (proven R10) ----
// Also emits the ktg K^T tile (e==0 blocks only) from the already-staged Kb,
// replacing the former standalone kT_kernel.
__global__ __launch_bounds__(256) void chunk_phase1(
    const float* __restrict__ kb, const float* __restrict__ vb,
    const float* __restrict__ betab, const float* __restrict__ gbuf,
    const float* __restrict__ wbuf, float* __restrict__ U0buf,
    float* __restrict__ Wbuf, float* __restrict__ cbuf,
    u16* __restrict__ ktg) {
  const int ch = blockIdx.x, eb = blockIdx.y, hh = blockIdx.z;
  const int e = eb >> 2, b = eb & 3;
  const int chunkid = (eb * NHEADS + hh) * NCHUNK + ch;
  const size_t base = (size_t)chunkid * 4096;
  const int tid = threadIdx.x;
  const int wave = tid >> 6, lane = tid & 63;
  const int quad = lane >> 4, l16 = lane & 15;

  __shared__ __align__(16) short Kb[64 * BST];
  __shared__ __align__(16) short Tb[64 * BST];   // bf16 below-panel T, zeroed elsewhere
  __shared__ float Td[4][16][17];                // fp32 diagonal blocks
  __shared__ __align__(16) short Xt[128 * BST];  // bf16 X^T [c][s]
  __shared__ float Zl[16][136];                  // fp32 panel Z
  __shared__ float cc[64], bb[64], exs[64];

  if (tid < 64) {
    const int gt = b * SEQ + ch * 64 + tid;
    const float w = wbuf[gt * NEXP + e];
    float gv = 0.f, bv = 0.f;
    if (w > 0.f) { gv = gbuf[gt * NHEADS + hh]; bv = betab[gt * NHEADS + hh]; }
    float cum = gv;
#pragma unroll
    for (int off = 1; off < 64; off <<= 1) {
      float o = __shfl_up(cum, off);
      if (tid >= off) cum += o;
    }
    cc[tid] = cum; exs[tid] = expf(cum); bb[tid] = bv;
    cbuf[(size_t)chunkid * 64 + tid] = cum;
  }
  // zero the MFMA-visible k<64 region of Tb AND Xt (0 x NaN = NaN in MFMA)
#pragma unroll
  for (int i = tid; i < 64 * 32; i += 256)
    ((int*)&Tb[(i >> 5) * BST])[i & 31] = 0;
#pragma unroll
  for (int i = tid; i < 128 * 32; i += 256)
    ((int*)&Xt[(i >> 5) * BST])[i & 31] = 0;
  {
    const int t = tid >> 2, d0 = (tid & 3) * 16;
    const float* krow = kb + (size_t)(b * SEQ + ch * 64 + t) * DMODEL + hh * 64 + d0;
#pragma unroll
    for (int j = 0; j < 4; ++j)
      *(ushort4*)&Kb[t * BST + d0 + j * 4] = f2b4(*(const float4*)(krow + j * 4));
  }
  __syncthreads();
  // emit ktg[dk][t] for phase2 (e==0 blocks only; Kb is staged & synced)
  if (eb < 4) {
    u16* obase = ktg + (size_t)((b * NHEADS + hh) * NCHUNK + ch) * 4096;
    for (int i = tid; i < 4096; i += 256) {
      const int dk = i >> 6, t = i & 63;
      obase[i] = (u16)Kb[t * BST + dk];
    }
  }
  // lower-triangular bands of K K^T -> Tb (below panel) / Td (diag panel)
  for (int ni = 0; ni <= wave; ++ni) {
    f32x4 acc = (f32x4){0.f, 0.f, 0.f, 0.f};
#pragma unroll
    for (int ks = 0; ks < 2; ++ks) {
      bf16x8 af = *(const bf16x8*)&Kb[(wave * 16 + l16) * BST + ks * 32 + quad * 8];
      bf16x8 bfr = *(const bf16x8*)&Kb[(ni * 16 + l16) * BST + ks * 32 + quad * 8];
      acc = __builtin_amdgcn_mfma_f32_16x16x32_bf16(af, bfr, acc, 0, 0, 0);
    }
#pragma unroll
    for (int r = 0; r < 4; ++r) {
      const int t = wave * 16 + quad * 4 + r, s = ni * 16 + l16;
      if (s < t) {
        const float val = bb[t] * expf(cc[t] - cc[s]) * acc[r];
        if (ni == wave) Td[wave][t & 15][s & 15] = val;
        else Tb[t * BST + s] = f2b(val);
      }
    }
  }
  __syncthreads();

  const bool solver = tid < 128;
  const bool isV = tid < 64;
  const int col = tid & 63;
  const float* src = isV ? vb : kb;
  const size_t srow = (size_t)(b * SEQ + ch * 64) * DMODEL + hh * 64 + col;
  float u[16];

#pragma unroll
  for (int p = 0; p < 4; ++p) {
    if (p > 0) {
      const int nch = (p + 1) >> 1;
      f32x4 a0 = (f32x4){0.f, 0.f, 0.f, 0.f};
      f32x4 a1 = (f32x4){0.f, 0.f, 0.f, 0.f};
      for (int ks = 0; ks < nch; ++ks) {
        bf16x8 af = *(const bf16x8*)&Tb[(p * 16 + l16) * BST + ks * 32 + quad * 8];
        bf16x8 b0 = *(const bf16x8*)&Xt[(wave * 32 + l16) * BST + ks * 32 + quad * 8];
        bf16x8 b1 = *(const bf16x8*)&Xt[(wave * 32 + 16 + l16) * BST + ks * 32 + quad * 8];
        a0 = __builtin_amdgcn_mfma_f32_16x16x32_bf16(af, b0, a0, 0, 0, 0);
        a1 = __builtin_amdgcn_mfma_f32_16x16x32_bf16(af, b1, a1, 0, 0, 0);
      }
#pragma unroll
      for (int r = 0; r < 4; ++r) {
        Zl[quad * 4 + r][wave * 32 + l16] = a0[r];
        Zl[quad * 4 + r][wave * 32 + 16 + l16] = a1[r];
      }
      __syncthreads();
    }
    if (solver) {
#pragma unroll
      for (int i = 0; i < 16; ++i) {
        const int t = p * 16 + i;
        const float R = src[srow + (size_t)t * DMODEL];
        const float sc = isV ? bb[t] : bb[t] * exs[t];
        float v0 = sc * R - ((p > 0) ? Zl[i][tid] : 0.f);
        float v1 = 0.f;
#pragma unroll
        for (int r = 0; r < i; ++r) {
          if (r & 1) v1 = fmaf(-Td[p][i][r], u[r], v1);
          else       v0 = fmaf(-Td[p][i][r], u[r], v0);
        }
        u[i] = v0 + v1;
      }
#pragma unroll
      for (int j = 0; j < 4; ++j) {
        ushort4 o;
        o.x = f2b(u[j * 4 + 0]); o.y = f2b(u[j * 4 + 1]);
        o.z = f2b(u[j * 4 + 2]); o.w = f2b(u[j * 4 + 3]);
        *(ushort4*)&Xt[tid * BST + p * 16 + j * 4] = o;
      }
      if (isV) {
        float* dst = U0buf + base + (size_t)col * 64 + p * 16;
#pragma unroll
        for (int j = 0; j < 4; ++j)
          *(float4*)(dst + j * 4) = make_float4(u[j * 4], u[j * 4 + 1], u[j * 4 + 2], u[j * 4 + 3]);
      } else {
        float* dst = Wbuf + base + col;
#pragma unroll
        for (int i = 0; i < 16; ++i) dst[(size_t)(p * 16 + i) * 64] = u[i];
      }
    }
    __syncthreads();
  }
}

// ---- phase 2: serial chunk chain, dv-split (grid z=2) + register prefetch ----
__global__ __launch_bounds__(256) void chunk_phase2(
    const float* __restrict__ cbuf, const float* __restrict__ U0buf,
    const float* __restrict__ Wbuf, const u16* __restrict__ ktg,
    u16* __restrict__ Utg, u16* __restrict__ Stg) {
  const int eb = blockIdx.x, hh = blockIdx.y, dvh = blockIdx.z;
  const int b = eb & 3;
  const int ebh = eb * NHEADS + hh;
  const int tid = threadIdx.x;
  const int wave = tid >> 6, lane = tid & 63;
  const int quad = lane >> 4, l16 = lane & 15;
  const int mi = wave >> 1;           // local dv tile (0..1)
  const int nb0 = (wave & 1) * 2;     // ni base (0 or 2)
  const int dvl0 = mi * 16 + quad * 4;  // local dv row base (+r)
  const int dvg0 = dvh * 32;          // global dv offset

  __shared__ float Sf[32][68];                    // fp32 S^T half [dvl][dk]
  __shared__ __align__(16) short Sbt[32 * BST];   // bf16 S^T half
  __shared__ __align__(16) short Wb[64 * BST];    // bf16 W [t][dk]
  __shared__ __align__(16) short Ktb[64 * BST];   // bf16 K^T [dk][t]
  __shared__ __align__(16) short UextT[32 * BST]; // bf16 (U*ext)^T half [dvl][t]
  __shared__ float ext[64];
  __shared__ float gam_sh;

  for (int i = tid; i < 32 * 68; i += 256) (&Sf[0][0])[i] = 0.f;

  const int ktile0 = (b * NHEADS + hh) * NCHUNK;
  const int sr = tid >> 2, sc = (tid & 3) * 16;  // staging row/col

  float4 wreg[4];
  int4 ktreg[2];
  float u0cur[2][4], u0nxt[2][4];
  float cvreg;

#define P2_PREF(CH, WD, KD, UD, CV)                                          \
  do {                                                                       \
    const int ch_ = (CH) < NCHUNK ? (CH) : (NCHUNK - 1);                     \
    const size_t b_ = (size_t)(ebh * NCHUNK + ch_) * 4096;                   \
    const size_t kb_ = (size_t)(ktile0 + ch_) * 4096;                        \
    const float* wr_ = Wbuf + b_ + (size_t)sr * 64 + sc;                     \
    WD[0] = *(const float4*)(wr_ + 0);  WD[1] = *(const float4*)(wr_ + 4);   \
    WD[2] = *(const float4*)(wr_ + 8);  WD[3] = *(const float4*)(wr_ + 12);  \
    const u16* kr_ = ktg + kb_ + (size_t)sr * 64 + sc;                       \
    KD[0] = *(const int4*)kr_; KD[1] = *(const int4*)(kr_ + 8);              \
    _Pragma("unroll")                                                        \
    for (int ni_ = 0; ni_ < 2; ++ni_)                                        \
      _Pragma("unroll")                                                      \
      for (int r_ = 0; r_ < 4; ++r_)                                         \
        UD[ni_][r_] = U0buf[b_ + (size_t)(dvg0 + dvl0 + r_) * 64 +           \
                            (nb0 + ni_) * 16 + l16];                         \
    CV = cbuf[(size_t)(ebh * NCHUNK + ch_) * 64 + (tid & 63)];               \
  } while (0)

  P2_PREF(0, wreg, ktreg, u0cur, cvreg);
  __syncthreads();  // Sf zero-init visible

  for (int ch = 0; ch < NCHUNK; ++ch) {
    const size_t base = (size_t)(ebh * NCHUNK + ch) * 4096;
    if (tid < 64) {
      const float c63 = __shfl(cvreg, 63);
      ext[tid] = expf(c63 - cvreg);
      if (tid == 63) gam_sh = expf(cvreg);
    }
#pragma unroll
    for (int j = 0; j < 4; ++j)
      *(ushort4*)&Wb[sr * BST + sc + j * 4] = f2b4(wreg[j]);
    *(int4*)&Ktb[sr * BST + sc] = ktreg[0];
    *(int4*)&Ktb[sr * BST + sc + 8] = ktreg[1];
    for (int i = tid; i < 512; i += 256) {
      const int dv = i >> 4, d4 = (i & 15) * 4;
      const float* s4 = &Sf[dv][d4];
      ushort4 o; o.x = f2b(s4[0]); o.y = f2b(s4[1]); o.z = f2b(s4[2]); o.w = f2b(s4[3]);
      *(ushort4*)&Sbt[dv * BST + d4] = o;
    }
    __syncthreads();  // barrier A: staging visible
    P2_PREF(ch + 1, wreg, ktreg, u0nxt, cvreg);
    for (int i = tid; i < 512; i += 256) {
      const int r = i >> 4, c4 = (i & 15) * 4;
      *(ushort4*)(Stg + base + (size_t)(dvg0 + r) * 64 + c4) = *(const ushort4*)&Sbt[r * BST + c4];
    }
#pragma unroll
    for (int ni = 0; ni < 2; ++ni) {
      f32x4 acc = (f32x4){0.f, 0.f, 0.f, 0.f};
#pragma unroll
      for (int ks = 0; ks < 2; ++ks) {
        bf16x8 af = *(const bf16x8*)&Sbt[(mi * 16 + l16) * BST + ks * 32 + quad * 8];
        bf16x8 bfr = *(const bf16x8*)&Wb[((nb0 + ni) * 16 + l16) * BST + ks * 32 + quad * 8];
        acc = __builtin_amdgcn_mfma_f32_16x16x32_bf16(af, bfr, acc, 0, 0, 0);
      }
#pragma unroll
      for (int r = 0; r < 4; ++r) {
        const int dvl = dvl0 + r, t = (nb0 + ni) * 16 + l16;
        const float uv = u0cur[ni][r] - acc[r];
        Utg[base + (size_t)(dvg0 + dvl) * 64 + t] = f2b(uv);
        UextT[dvl * BST + t] = f2b(uv * ext[t]);
      }
    }
    __syncthreads();  // barrier B: UextT visible
    const float g = gam_sh;
#pragma unroll
    for (int ni = 0; ni < 2; ++ni) {
      f32x4 acc = (f32x4){0.f, 0.f, 0.f, 0.f};
#pragma unroll
      for (int ks = 0; ks < 2; ++ks) {
        bf16x8 af = *(const bf16x8*)&UextT[(mi * 16 + l16) * BST + ks * 32 + quad * 8];
        bf16x8 bfr = *(const bf16x8*)&Ktb[((nb0 + ni) * 16 + l16) * BST + ks * 32 + quad * 8];
        acc = __builtin_amdgcn_mfma_f32_16x16x32_bf16(af, bfr, acc, 0, 0, 0);
      }
#pragma unroll
      for (int r = 0; r < 4; ++r) {
        const int dvl = dvl0 + r, dk = (nb0 + ni) * 16 + l16;
        Sf[dvl][dk] = g * Sf[dvl][dk] + acc[r];
      }
    }
#pragma unroll
    for (int ni = 0; ni < 2; ++ni)
#pragma unroll
      for (int r = 0; r < 4; ++r) u0cur[ni][r] = u0nxt[ni][r];
    __syncthreads();  // barrier C: Sf update + LDS reuse safe
  }
#undef P2_PREF
}

// ---- phase 3: parallel (chunk, eb, h). P = QK^T; O = e^c QS + P U; combine ----
// St/Ut B-operand fragments are loaded DIRECTLY from global (coalesced 16B/lane,
// same traffic as LDS staging) -> 2 fewer LDS arrays, higher occupancy.
__global__ __launch_bounds__(256) void chunk_phase3(
    const float* __restrict__ qb, const float* __restrict__ kb,
    const float* __restrict__ cbuf, const u16* __restrict__ Utg,
    const u16* __restrict__ Stg, const float* __restrict__ wbuf,
    float* __restrict__ coreb) {
  const int ch = blockIdx.x, eb = blockIdx.y, hh = blockIdx.z;
  const int e = eb >> 2, b = eb & 3;
  const int chunkid = (eb * NHEADS + hh) * NCHUNK + ch;
  const size_t base = (size_t)chunkid * 4096;
  const int tid = threadIdx.x;
  const int wave = tid >> 6, lane = tid & 63;
  const int quad = lane >> 4, l16 = lane & 15;

  __shared__ __align__(16) short Qb[64 * BST];
  __shared__ __align__(16) short Kb3[64 * BST];
  __shared__ __align__(16) short Pb[64 * BST];
  __shared__ float cc3[64];

  if (tid < 64) cc3[tid] = cbuf[(size_t)chunkid * 64 + tid];
  {
    const int t = tid >> 2, d0 = (tid & 3) * 16;
    const size_t ro = (size_t)(b * SEQ + ch * 64 + t) * DMODEL + hh * 64 + d0;
#pragma unroll
    for (int j = 0; j < 4; ++j) {
      *(ushort4*)&Qb[t * BST + d0 + j * 4] = f2b4(*(const float4*)(qb + ro + j * 4));
      *(ushort4*)&Kb3[t * BST + d0 + j * 4] = f2b4(*(const float4*)(kb + ro + j * 4));
    }
  }
  __syncthreads();
  // P~[t][s] = (s<=t) e^{c_t-c_s} (q_t.k_s)
  for (int ni = 0; ni < 4; ++ni) {
    f32x4 acc = (f32x4){0.f, 0.f, 0.f, 0.f};
#pragma unroll
    for (int ks = 0; ks < 2; ++ks) {
      bf16x8 af = *(const bf16x8*)&Qb[(wave * 16 + l16) * BST + ks * 32 + quad * 8];
      bf16x8 bfr = *(const bf16x8*)&Kb3[(ni * 16 + l16) * BST + ks * 32 + quad * 8];
      acc = __builtin_amdgcn_mfma_f32_16x16x32_bf16(af, bfr, acc, 0, 0, 0);
    }
#pragma unroll
    for (int r = 0; r < 4; ++r) {
      const int t = wave * 16 + quad * 4 + r, s = ni * 16 + l16;
      const float p = (s <= t) ? expf(cc3[t] - cc3[s]) * acc[r] : 0.f;
      Pb[t * BST + s] = f2b(p);
    }
  }
  __syncthreads();
  // O = 0.125 * (e^{c_t} Q S0 + P~ U); B fragments direct from global
  for (int ni = 0; ni < 4; ++ni) {
    f32x4 a1 = (f32x4){0.f, 0.f, 0.f, 0.f};
    f32x4 a2 = (f32x4){0.f, 0.f, 0.f, 0.f};
#pragma unroll
    for (int ks = 0; ks < 2; ++ks) {
      const size_t boff = base + (size_t)(ni * 16 + l16) * 64 + ks * 32 + quad * 8;
      bf16x8 afq = *(const bf16x8*)&Qb[(wave * 16 + l16) * BST + ks * 32 + quad * 8];
      bf16x8 bfs = *(const bf16x8*)(Stg + boff);
      a1 = __builtin_amdgcn_mfma_f32_16x16x32_bf16(afq, bfs, a1, 0, 0, 0);
      bf16x8 afp = *(const bf16x8*)&Pb[(wave * 16 + l16) * BST + ks * 32 + quad * 8];
      bf16x8 bfu = *(const bf16x8*)(Utg + boff);
      a2 = __builtin_amdgcn_mfma_f32_16x16x32_bf16(afp, bfu, a2, 0, 0, 0);
    }
#pragma unroll
    for (int r = 0; r < 4; ++r) {
      const int t = wave * 16 + quad * 4 + r, dv = ni * 16 + l16;
      const int gt = b * SEQ + ch * 64 + t;
      const float wv = wbuf[gt * NEXP + e];
      if (wv > 0.f) {
        const float o = 0.125f * (expf(cc3[t]) * a1[r] + a2[r]);
        atomicAdd(&coreb[(size_t)gt * DMODEL + hh * 64 + dv], wv * o);
      }
    }
  }
}

// ---------------- fallback serial scan (R3-proven) ----------------
__global__ __launch_bounds__(64) void scan_kernel(
    const float* __restrict__ qb, const float* __restrict__ kb,
    const float* __restrict__ vb, const float* __restrict__ betab,
    const float* __restrict__ gbuf, const float* __restrict__ wbuf,
    const int* __restrict__ tidx, const int* __restrict__ tcnt,
    float* __restrict__ coreb) {
  const int vhalf = blockIdx.x & 1, e = blockIdx.x >> 1;
  const int b = blockIdx.y, hh = blockIdx.z;
  const int lane = threadIdx.x;
  const int kh = lane >> 5;
  const int vi = lane & 31;
  const int cv = vhalf * 32 + vi;
  const int* idx = tidx + (e * BATCH + b) * SEQ;
  const int n = tcnt[e * BATCH + b];
  if (n == 0) return;
  const int nm1 = n - 1;
  __shared__ __align__(16) float lk[4][64];
  __shared__ __align__(16) float lq[4][64];
  __shared__ int lidx[SEQ];
  for (int i = lane; i < SEQ; i += 64) lidx[i] = idx[i < n ? i : nm1];
  __syncthreads();
  v2f S2[16];
#pragma unroll
  for (int j = 0; j < 16; ++j) S2[j] = (v2f){0.f, 0.f};
  float kf[4], qf[4], vf[4], gf[4], bf[4], wf[4], egr[4];
  int tcur[4], tok4[4];
#define PREF(SLOT, TK)                                          \
  do {                                                          \
    const int tn_ = b * SEQ + (TK);                             \
    const size_t kq_ = (size_t)tn_ * DMODEL + hh * 64 + lane;   \
    kf[SLOT] = kb[kq_];                                         \
    qf[SLOT] = qb[kq_];                                         \
    vf[SLOT] = vb[(size_t)tn_ * DMODEL + hh * 64 + cv];         \
    gf[SLOT] = gbuf[tn_ * NHEADS + hh];                         \
    bf[SLOT] = betab[tn_ * NHEADS + hh];                        \
    wf[SLOT] = wbuf[tn_ * NEXP + e];                            \
    tcur[SLOT] = tn_;                                           \
  } while (0)
  tok4[0] = lidx[0];
  tok4[1] = lidx[1 < n ? 1 : nm1];
  tok4[2] = lidx[2 < n ? 2 : nm1];
  tok4[3] = lidx[3 < n ? 3 : nm1];
  PREF(0, tok4[0]); PREF(1, tok4[1]); PREF(2, tok4[2]);
  lk[0][lane] = kf[0]; lq[0][lane] = qf[0];
  egr[0] = expf(gf[0]);
  const int m = (n + 3) & ~3;
  for (int i = 0; i < m; i += 4) {
#pragma unroll
    for (int u = 0; u < 4; ++u) {
      const int s = i + u;
      const int sN = (u + 3) & 3;
      const int s1 = (u + 1) & 3;
      PREF(sN, tok4[sN]);
      int a4 = s + 4;
      a4 = a4 < nm1 ? a4 : nm1;
      tok4[u] = lidx[a4];
      __builtin_amdgcn_wave_barrier();
      lk[s1][lane] = kf[s1];
      lq[s1][lane] = qf[s1];
      __builtin_amdgcn_wave_barrier();
      egr[s1] = expf(gf[s1]);
      const v4f* lk4 = (const v4f*)&lk[u][kh * 32];
      const v4f* lq4 = (const v4f*)&lq[u][kh * 32];
      v2f myk[16];
      v2f c0 = (v2f){0.f, 0.f}, c1 = c0, c2 = c0, c3 = c0;
#pragma unroll
      for (int j = 0; j < 8; ++j) {
        const v4f k4 = lk4[j];
        const v2f klo = (v2f){k4.x, k4.y};
        const v2f khi = (v2f){k4.z, k4.w};
        myk[2 * j] = klo; myk[2 * j + 1] = khi;
        if (j & 1) {
          c2 = __builtin_elementwise_fma(klo, S2[2 * j], c2);
          c3 = __builtin_elementwise_fma(khi, S2[2 * j + 1], c3);
        } else {
          c0 = __builtin_elementwise_fma(klo, S2[2 * j], c0);
          c1 = __builtin_elementwise_fma(khi, S2[2 * j + 1], c1);
        }
      }
      const v2f cacc = (c0 + c1) + (c2 + c3);
      float cd = cacc.x + cacc.y;
      cd += __shfl_xor(cd, 32);
      const float egc = egr[u];
      const float delta = (vf[u] - egc * cd) * bf[u];
      const v2f d2 = (v2f){delta, delta};
      const v2f eg2 = (v2f){egc, egc};
      v2f o0 = (v2f){0.f, 0.f}, o1 = o0, o2 = o0, o3 = o0;
#pragma unroll
      for (int j = 0; j < 8; ++j) {
        const v4f q4 = lq4[j];
        const v2f qlo = (v2f){q4.x, q4.y};
        const v2f qhi = (v2f){q4.z, q4.w};
        const v2f s0 = __builtin_elementwise_fma(S2[2 * j], eg2, myk[2 * j] * d2);
        const v2f s1v = __builtin_elementwise_fma(S2[2 * j + 1], eg2, myk[2 * j + 1] * d2);
        S2[2 * j] = s0; S2[2 * j + 1] = s1v;
        if (j & 1) {
          o2 = __builtin_elementwise_fma(qlo, s0, o2);
          o3 = __builtin_elementwise_fma(qhi, s1v, o3);
        } else {
          o0 = __builtin_elementwise_fma(qlo, s0, o0);
          o1 = __builtin_elementwise_fma(qhi, s1v, o1);
        }
      }
      const v2f oacc = (o0 + o1) + (o2 + o3);
      float o = oacc.x + oacc.y;
      o += __shfl_xor(o, 32);
      if (kh == 0 && s < n)
        atomicAdd(&coreb[(size_t)tcur[u] * DMODEL + hh * 64 + cv],
                  o * 0.125f * wf[u]);
    }
  }
#undef PREF
}

// ---------------- fused gated RMSNorm -> bf16 ----------------
__global__ __launch_bounds__(512) void rmsnorm_kernel(
    const float* __restrict__ coreb, const float* __restrict__ gateb,
    const float* __restrict__ wn, u16* __restrict__ outb) {
  const int t = blockIdx.x;
  const int tid = threadIdx.x;
  const int v = tid & 63;
  const float x = coreb[(size_t)t * DMODEL + tid];
  float ss = x * x;
#pragma unroll
  for (int off = 1; off < 64; off <<= 1) ss += __shfl_xor(ss, off);
  const float r = rsqrtf(ss * (1.0f / 64.0f) + 1e-5f);
  const float gt = gateb[(size_t)t * DMODEL + tid];
  outb[(size_t)t * DMODEL + tid] = f2b(x * r * wn[v] * gt);
}

extern "C" void kernel_launch(void* const* d_in, const int* in_sizes, int n_in,
                              void* d_out, int out_size, void* d_ws, size_t ws_size,
                              hipStream_t stream) {
  const float* h       = (const float*)d_in[0];
  const float* Wq      = (const float*)d_in[1];
  const float* Wgate   = (const float*)d_in[2];
  const float* Wk      = (const float*)d_in[3];
  const float* Wv      = (const float*)d_in[4];
  const float* Wb      = (const float*)d_in[5];
  const float* Wa      = (const float*)d_in[6];
  const float* A_log   = (const float*)d_in[7];
  const float* dt_bias = (const float*)d_in[8];
  const float* Wg      = (const float*)d_in[9];
  const float* wn      = (const float*)d_in[10];
  const float* Wo      = (const float*)d_in[11];
  float* out = (float*)d_out;

  char* p = (char*)d_ws;
  const size_t big = (size_t)NTOK * DMODEL;  // 2M elements
  auto alloc = [&](size_t bytes) { char* r = p; p += (bytes + 255) & ~255ull; return r; };
  float* qb    = (float*)alloc(big * 4);
  float* kb    = (float*)alloc(big * 4);
  float* vb    = (float*)alloc(big * 4);
  float* gateb = (float*)alloc(big * 4);
  float* coreb = (float*)alloc(big * 4);
  float* betab = (float*)alloc((size_t)NTOK * NHEADS * 4);
  float* gbuf  = (float*)alloc((size_t)NTOK * NHEADS * 4);
  float* wbuf  = (float*)alloc((size_t)NTOK * NEXP * 4);
  int*   tidx  = (int*)alloc((size_t)NEXP * BATCH * SEQ * 4);
  int*   tcnt  = (int*)alloc(256);
  u16*   hb    = (u16*)alloc(big * 2);
  u16*   nb    = (u16*)alloc(big * 2);
  u16*   wtq   = (u16*)alloc((size_t)DMODEL * DMODEL * 2);
  u16*   wtk   = (u16*)alloc((size_t)DMODEL * DMODEL * 2);
  u16*   wtv   = (u16*)alloc((size_t)DMODEL * DMODEL * 2);
  u16*   wtg   = (u16*)alloc((size_t)DMODEL * DMODEL * 2);
  u16*   wto   = (u16*)alloc((size_t)DMODEL * DMODEL * 2);
  // chunked-path extras
  const size_t nchunks = (size_t)NEXP * BATCH * NHEADS * NCHUNK;  // 2048
  float* U0buf = (float*)alloc(nchunks * 4096 * 4);
  float* Wbuf_ = (float*)alloc(nchunks * 4096 * 4);
  u16*   Utg   = (u16*)alloc(nchunks * 4096 * 2);
  u16*   Stg   = (u16*)alloc(nchunks * 4096 * 2);
  float* cbuf  = (float*)alloc(nchunks * 64 * 4);
  u16*   ktg   = (u16*)alloc((size_t)BATCH * NHEADS * NCHUNK * 4096 * 2);
  const size_t need = (size_t)(p - (char*)d_ws);
  const bool use_chunked = (ws_size >= need);

  // fused prep: zero coreb + cast h + transpose-cast 5 weights + router
  prep_kernel<<<dim3(SEG_TOTAL), 256, 0, stream>>>(
      h, coreb, hb, Wq, Wk, Wv, Wg, Wo, wtq, wtk, wtv, wtg, wto,
      Wb, Wa, Wgate, A_log, dt_bias, betab, gbuf, wbuf);

  // batched projection GEMMs (z: Wq/Wk -> l2norm+silu, Wv/Wg -> silu)
  gemm4_kernel<<<dim3(NTOK / 128, DMODEL / 64, 4), 128, 0, stream>>>(
      hb, wtq, wtk, wtv, wtg, qb, kb, vb, gateb);

  if (use_chunked) {
    chunk_phase1<<<dim3(NCHUNK, NEXP * BATCH, NHEADS), 256, 0, stream>>>(
        kb, vb, betab, gbuf, wbuf, U0buf, Wbuf_, cbuf, ktg);
    chunk_phase2<<<dim3(NEXP * BATCH, NHEADS, 2), 256, 0, stream>>>(
        cbuf, U0buf, Wbuf_, ktg, Utg, Stg);
    chunk_phase3<<<dim3(NCHUNK, NEXP * BATCH, NHEADS), 256, 0, stream>>>(
        qb, kb, cbuf, Utg, Stg, wbuf, coreb);
  } else {
    compact_kernel<<<dim3(NEXP, BATCH), 64, 0, stream>>>(wbuf, tidx, tcnt);
    scan_kernel<<<dim3(NEXP * 2, BATCH, NHEADS), 64, 0, stream>>>(
        qb, kb, vb, betab, gbuf, wbuf, tidx, tcnt, coreb);
  }

  rmsnorm_kernel<<<dim3(NTOK), 512, 0, stream>>>(coreb, gateb, wn, nb);

  gemm_out_kernel<<<dim3(NTOK / 128, DMODEL / 64), 128, 0, stream>>>(nb, wto, out);
}